// Round 1
// baseline (9837.445 us; speedup 1.0000x reference)
//
#include <hip/hip_runtime.h>

// UniPhyBlock fp32 reference-faithful pipeline, round 0 (correctness-first).
// B=2 T=16 D=64 H=W=64, C=128, E=4 experts, M=256.
//
// Buffers:
//   d_out (16.7M f32): xn [K1->K2] -> u_t/u_out [K7->K9] -> final [K10]
//   ws slot0 (16.7M): X_re/X_im conv-output planes [n][d][p]
//   ws slot1 (16.7M): Wr (repacked conv weights) [K0->K2], then `on` [K9->K10]
//   ws smalls: Xm, xmix, fs, gate, src, op_decay, op_forcing  (per (n,d))
// ws requirement: (2*16777216 + 26624)*4 = 134,324,224 bytes.

#define DEV static __device__ __forceinline__

namespace {
constexpr int TT = 16;
constexpr int TN = 32;          // B*T
constexpr int TP = 4096;        // H*W
constexpr size_t PLANE = (size_t)TN * 64 * TP;   // 8,388,608
constexpr size_t BIGSZ = (size_t)TN * TP * 128;  // 16,777,216

DEV float sp_f(float x) { return x > 20.f ? x : log1pf(expf(x)); }
DEV float gelu_f(float x) {
  float x3 = x * x * x;
  return 0.5f * x * (1.f + tanhf(0.7978845608028654f * (x + 0.044715f * x3)));
}
} // namespace

// K0: repack conv_w (Co,Ci,3,3) -> Wr[k][co][ci], k=kh*3+kw
__global__ void k_repack(const float* __restrict__ cw, float* __restrict__ Wr) {
  int i = blockIdx.x * 256 + threadIdx.x;
  if (i >= 9 * 128 * 128) return;
  int ci = i & 127, co = (i >> 7) & 127, k = i >> 14;
  Wr[i] = cw[((size_t)co * 128 + ci) * 9 + k];
}

// K1: layernorm over channels [re(0..63), im(0..63)] -> xn [n][p][c]
__global__ __launch_bounds__(256) void k_ln_in(
    const float* __restrict__ xre, const float* __restrict__ xim,
    const float* __restrict__ gg, const float* __restrict__ bb,
    float* __restrict__ xn) {
  int n = blockIdx.x >> 6, h = blockIdx.x & 63;
  __shared__ float xl[64][129];
  __shared__ float ps[4][64], ps2[4][64];
  __shared__ float mu[64], rs[64];
  int tid = threadIdx.x;
  int w = tid & 63, q = tid >> 6;
  size_t base = ((size_t)n * 4096 + h) * 64 + w;  // n*262144 + h*64 + w
  for (int d = q; d < 64; d += 4) {
    size_t o = base + (size_t)d * 4096;
    xl[w][d] = xre[o];
    xl[w][64 + d] = xim[o];
  }
  __syncthreads();
  float s = 0.f, s2 = 0.f;
  for (int c = q * 32; c < q * 32 + 32; ++c) { float v = xl[w][c]; s += v; s2 += v * v; }
  ps[q][w] = s; ps2[q][w] = s2;
  __syncthreads();
  if (tid < 64) {
    float a = 0.f, b2 = 0.f;
#pragma unroll
    for (int i = 0; i < 4; ++i) { a += ps[i][tid]; b2 += ps2[i][tid]; }
    float m = a * (1.f / 128.f);
    mu[tid] = m;
    rs[tid] = rsqrtf(b2 * (1.f / 128.f) - m * m + 1e-5f);
  }
  __syncthreads();
  size_t obase = (((size_t)n * 64 + h) * 64) * 128;
  for (int idx = tid; idx < 64 * 128; idx += 256) {
    int c = idx & 127, p2 = idx >> 7;
    xn[obase + (size_t)p2 * 128 + c] = (xl[p2][c] - mu[p2]) * rs[p2] * gg[c] + bb[c];
  }
}

// K2: 3x3 SAME conv, 128->128 ch. One block per (n,h) row; 512 thr.
// thread: px=tid&63 (output w), wave-uniform co-group cg=tid>>6 (16 co each).
__global__ __launch_bounds__(512) void k_conv(
    const float* __restrict__ xn, const float* __restrict__ Wr,
    const float* __restrict__ cbias, float* __restrict__ Xre, float* __restrict__ Xim) {
  int n = blockIdx.x >> 6, h = blockIdx.x & 63;
  __shared__ __align__(16) float in_t[3][66][68];
  __shared__ float acc_l[128][65];
  int tid = threadIdx.x;
  int px = tid & 63;
  int cgu = __builtin_amdgcn_readfirstlane(tid >> 6);  // wave-uniform 0..7
  float acc[16];
#pragma unroll
  for (int j = 0; j < 16; ++j) acc[j] = 0.f;
  for (int chunk = 0; chunk < 2; ++chunk) {
    __syncthreads();
    for (int idx = tid; idx < 3 * 66 * 64; idx += 512) {
      int r = idx / (66 * 64);
      int rem = idx - r * (66 * 64);
      int p = rem >> 6, ci = rem & 63;
      int hh = h + r - 1, wg = p - 1;
      float v = 0.f;
      if ((unsigned)hh < 64u && (unsigned)wg < 64u)
        v = xn[(((size_t)n * 64 + hh) * 64 + wg) * 128 + chunk * 64 + ci];
      in_t[r][p][ci] = v;
    }
    __syncthreads();
#pragma unroll
    for (int kh = 0; kh < 3; ++kh) {
#pragma unroll
      for (int kw = 0; kw < 3; ++kw) {
        const float* wb = Wr + (((size_t)(kh * 3 + kw) * 128 + cgu * 16) * 128) + chunk * 64;
#pragma unroll 2
        for (int c4 = 0; c4 < 16; ++c4) {
          float4 inv = *(const float4*)&in_t[kh][px + kw][c4 * 4];
#pragma unroll
          for (int j = 0; j < 16; ++j) {
            float4 wv = *(const float4*)&wb[j * 128 + c4 * 4];
            acc[j] += inv.x * wv.x + inv.y * wv.y + inv.z * wv.z + inv.w * wv.w;
          }
        }
      }
    }
  }
  {
    int cg = tid >> 6;
#pragma unroll
    for (int j = 0; j < 16; ++j) acc_l[cg * 16 + j][px] = acc[j] + cbias[cg * 16 + j];
  }
  __syncthreads();
  for (int idx = tid; idx < 64 * 128; idx += 512) {
    int p2 = idx & 63, c = idx >> 6;
    float v = acc_l[c][p2];
    size_t off = ((size_t)n * 64 + (c & 63)) * 4096 + (size_t)h * 64 + p2;
    if (c < 64) Xre[off] = v; else Xim[off] = v;
  }
}

// K3: Xm[n][d] = mean_p (X + xf). One block per (n,d).
__global__ __launch_bounds__(256) void k_xmean(
    const float* __restrict__ Xre, const float* __restrict__ Xim,
    const float* __restrict__ xre, const float* __restrict__ xim,
    float2* __restrict__ Xm) {
  int nd = blockIdx.x;
  size_t base = (size_t)nd * 4096;
  int tid = threadIdx.x;
  float sr = 0.f, si = 0.f;
  for (int p = tid; p < 4096; p += 256) {
    sr += Xre[base + p] + xre[base + p];
    si += Xim[base + p] + xim[base + p];
  }
  __shared__ float r1[256], r2[256];
  r1[tid] = sr; r2[tid] = si;
  __syncthreads();
  for (int s = 128; s > 0; s >>= 1) {
    if (tid < s) { r1[tid] += r1[tid + s]; r2[tid] += r2[tid + s]; }
    __syncthreads();
  }
  if (tid == 0) Xm[nd] = make_float2(r1[0] * (1.f / 4096.f), r2[0] * (1.f / 4096.f));
}

// K4: per (b,t): xmean = Xm @ Ec; fcat = [re,im] @ mix_w + mix_b; xmix = complex
__global__ void k_chainA(const float2* __restrict__ Xm, const float* __restrict__ Ere,
                         const float* __restrict__ Eim, const float* __restrict__ mixw,
                         const float* __restrict__ mixb, float2* __restrict__ xmix) {
  int n = blockIdx.x;
  int tid = threadIdx.x;  // 128
  __shared__ float2 xm[64];
  __shared__ float cat[128];
  __shared__ float fc[128];
  if (tid < 64) xm[tid] = Xm[n * 64 + tid];
  __syncthreads();
  if (tid < 64) {
    float ar = 0.f, ai = 0.f;
    for (int d = 0; d < 64; ++d) {
      float2 x = xm[d];
      float er = Ere[d * 64 + tid], ei = Eim[d * 64 + tid];
      ar += x.x * er - x.y * ei;
      ai += x.x * ei + x.y * er;
    }
    cat[tid] = ar; cat[64 + tid] = ai;
  }
  __syncthreads();
  {
    float f = mixb[tid];
    for (int i = 0; i < 128; ++i) f += cat[i] * mixw[i * 128 + tid];
    fc[tid] = f;
  }
  __syncthreads();
  if (tid < 64) xmix[n * 64 + tid] = make_float2(fc[tid], fc[64 + tid]);
}

// K5: flux scan over t, + flux*decay^(t+1). 128 threads = (b,d).
__global__ void k_chainB(const float2* __restrict__ xmix, const float* __restrict__ nu,
                         const float* __restrict__ th, const float* __restrict__ fre,
                         const float* __restrict__ fim, float2* __restrict__ fs) {
  int tid = threadIdx.x;  // 128
  int b = tid >> 6, d = tid & 63;
  float r = expf(-sp_f(nu[d]));
  float dr = r * cosf(th[d]), di = r * sinf(th[d]);
  float yr = 0.f, yi = 0.f, cr = 1.f, ci = 0.f;
  float fr = fre[b * 64 + d], fi = fim[b * 64 + d];
  for (int t = 0; t < 16; ++t) {
    int n = b * 16 + t;
    float ncr = cr * dr - ci * di, nci = cr * di + ci * dr;
    cr = ncr; ci = nci;
    float2 xm = xmix[n * 64 + d];
    float nyr = dr * yr - di * yi + xm.x;
    float nyi = dr * yi + di * yr + xm.y;
    yr = nyr; yi = nyi;
    fs[n * 64 + d] = make_float2(yr + fr * cr - fi * ci, yi + fr * ci + fi * cr);
  }
}

// K6: per (b,t): source, gate, op_decay, op_forcing
__global__ void k_chainC(const float2* __restrict__ fs, const float* __restrict__ srcw,
                         const float* __restrict__ srcb, const float* __restrict__ gw,
                         const float* __restrict__ gbv, const float* __restrict__ la,
                         const float* __restrict__ lbv, const float* __restrict__ dt,
                         float* __restrict__ g, float2* __restrict__ src,
                         float2* __restrict__ opd, float2* __restrict__ opf) {
  int n = blockIdx.x;
  int t = n & 15;
  int tid = threadIdx.x;  // 128
  __shared__ float oc[128];
  __shared__ float sl[128];
  if (tid < 64) { float2 v = fs[n * 64 + tid]; oc[tid] = v.x; oc[64 + tid] = v.y; }
  __syncthreads();
  {
    float s = srcb[tid];
    for (int i = 0; i < 128; ++i) s += oc[i] * srcw[i * 128 + tid];
    sl[tid] = s;
  }
  if (tid < 64) {
    float gv = gbv[tid];
    for (int i = 0; i < 128; ++i) gv += oc[i] * gw[i * 64 + tid];
    g[n * 64 + tid] = 1.f / (1.f + expf(-gv));
    float lr = -sp_f(la[tid]), li = lbv[tid];
    float dtv = dt[t];
    float er = expf(lr * dtv);
    float2 od = make_float2(er * cosf(li * dtv), er * sinf(li * dtv));
    opd[n * 64 + tid] = od;
    float inv = 1.f / (lr * lr + li * li);
    float nx = od.x - 1.f, ny = od.y;
    opf[n * 64 + tid] = make_float2((nx * lr + ny * li) * inv, (ny * lr - nx * li) * inv);
  }
  __syncthreads();
  if (tid < 64) src[n * 64 + tid] = make_float2(sl[tid], sl[64 + tid]);
}

// K7: u_t = ((X+xf)@Ec * g + src*(1-g)) * opf  (+ h*opd at t=0) -> U [n][d][p]
__global__ __launch_bounds__(256) void k_ut(
    const float* __restrict__ Xre, const float* __restrict__ Xim,
    const float* __restrict__ xre, const float* __restrict__ xim,
    const float* __restrict__ Ere, const float* __restrict__ Eim,
    const float* __restrict__ g, const float2* __restrict__ src,
    const float2* __restrict__ opd, const float2* __restrict__ opf,
    const float* __restrict__ hre, const float* __restrict__ him,
    float* __restrict__ Ure, float* __restrict__ Uim) {
  int n = blockIdx.x >> 6, pt = blockIdx.x & 63;
  int p0 = pt * 64;
  int b = n >> 4, t = n & 15;
  __shared__ float2 Ec[64][64];
  __shared__ float gl[64];
  __shared__ float2 sl[64], ofl[64], odl[64];
  int tid = threadIdx.x;
  for (int idx = tid; idx < 4096; idx += 256)
    Ec[idx >> 6][idx & 63] = make_float2(Ere[idx], Eim[idx]);
  if (tid < 64) {
    gl[tid] = g[n * 64 + tid]; sl[tid] = src[n * 64 + tid];
    ofl[tid] = opf[n * 64 + tid]; odl[tid] = opd[n * 64 + tid];
  }
  __syncthreads();
  int px = tid & 63, grp = tid >> 6;
  float ar[16], ai[16];
#pragma unroll
  for (int j = 0; j < 16; ++j) { ar[j] = 0.f; ai[j] = 0.f; }
  size_t rowbase = (size_t)n * 64 * 4096 + p0 + px;
  for (int d = 0; d < 64; ++d) {
    size_t off = rowbase + (size_t)d * 4096;
    float xr = Xre[off] + xre[off];
    float xi = Xim[off] + xim[off];
#pragma unroll
    for (int j = 0; j < 16; ++j) {
      float2 e = Ec[d][grp * 16 + j];
      ar[j] += xr * e.x - xi * e.y;
      ai[j] += xr * e.y + xi * e.x;
    }
  }
#pragma unroll
  for (int j = 0; j < 16; ++j) {
    int ee = grp * 16 + j;
    float gv = gl[ee];
    float2 s = sl[ee];
    float fr = ar[j] * gv + s.x * (1.f - gv);
    float fi = ai[j] * gv + s.y * (1.f - gv);
    float2 of = ofl[ee];
    float ur = fr * of.x - fi * of.y;
    float ui = fr * of.y + fi * of.x;
    if (t == 0) {
      size_t hoff = ((size_t)b * 4096 + p0 + px) * 64 + ee;
      float hr = hre[hoff], hi = him[hoff];
      float2 od = odl[ee];
      ur += hr * od.x - hi * od.y;
      ui += hr * od.y + hi * od.x;
    }
    size_t off = ((size_t)n * 64 + ee) * 4096 + p0 + px;
    Ure[off] = ur; Uim[off] = ui;
  }
}

// K8: associative scan over t (in place on U)
__global__ __launch_bounds__(256) void k_scan(float* __restrict__ Ure, float* __restrict__ Uim,
                                              const float2* __restrict__ opd) {
  int gid = blockIdx.x * 256 + threadIdx.x;  // 524288
  int p = gid & 4095, d = (gid >> 12) & 63, b = gid >> 18;
  float yr = 0.f, yi = 0.f;
  for (int t = 0; t < 16; ++t) {
    int n = b * 16 + t;
    float2 od = opd[n * 64 + d];
    size_t off = ((size_t)n * 64 + d) * 4096 + p;
    float ur = Ure[off], ui = Uim[off];
    float nyr = od.x * yr - od.y * yi + ur;
    float nyi = od.x * yi + od.y * yr + ui;
    yr = nyr; yi = nyi;
    Ure[off] = yr; Uim[off] = yi;
  }
}

// K9: x_dec = u_out @ Fc, layernorm -> on [n][p][c]
__global__ __launch_bounds__(256) void k_xdec(
    const float* __restrict__ Ure, const float* __restrict__ Uim,
    const float* __restrict__ Fre, const float* __restrict__ Fim,
    const float* __restrict__ ntg, const float* __restrict__ ntb,
    float* __restrict__ on) {
  int n = blockIdx.x >> 6, pt = blockIdx.x & 63;
  int p0 = pt * 64;
  __shared__ float2 Fc[64][64];
  __shared__ float onl[64][129];
  __shared__ float ps[4][64], ps2[4][64];
  __shared__ float mu[64], rs[64];
  int tid = threadIdx.x;
  for (int idx = tid; idx < 4096; idx += 256)
    Fc[idx >> 6][idx & 63] = make_float2(Fre[idx], Fim[idx]);
  __syncthreads();
  int px = tid & 63, grp = tid >> 6;
  float ar[16], ai[16];
#pragma unroll
  for (int j = 0; j < 16; ++j) { ar[j] = 0.f; ai[j] = 0.f; }
  size_t rowbase = (size_t)n * 64 * 4096 + p0 + px;
  for (int d = 0; d < 64; ++d) {
    size_t off = rowbase + (size_t)d * 4096;
    float xr = Ure[off], xi = Uim[off];
#pragma unroll
    for (int j = 0; j < 16; ++j) {
      float2 e = Fc[d][grp * 16 + j];
      ar[j] += xr * e.x - xi * e.y;
      ai[j] += xr * e.y + xi * e.x;
    }
  }
#pragma unroll
  for (int j = 0; j < 16; ++j) {
    int ee = grp * 16 + j;
    onl[px][ee] = ar[j];
    onl[px][64 + ee] = ai[j];
  }
  __syncthreads();
  float s = 0.f, s2 = 0.f;
  for (int c = grp * 32; c < grp * 32 + 32; ++c) { float v = onl[px][c]; s += v; s2 += v * v; }
  ps[grp][px] = s; ps2[grp][px] = s2;
  __syncthreads();
  if (tid < 64) {
    float a = 0.f, b2 = 0.f;
#pragma unroll
    for (int i = 0; i < 4; ++i) { a += ps[i][tid]; b2 += ps2[i][tid]; }
    float m = a * (1.f / 128.f);
    mu[tid] = m;
    rs[tid] = rsqrtf(b2 * (1.f / 128.f) - m * m + 1e-5f);
  }
  __syncthreads();
  size_t obase = ((size_t)n * 4096 + p0) * 128;
  for (int idx = tid; idx < 64 * 128; idx += 256) {
    int c = idx & 127, q = idx >> 7;
    on[obase + (size_t)q * 128 + c] = (onl[q][c] - mu[q]) * rs[q] * ntg[c] + ntb[c];
  }
}

// K10: MoE (4 experts, gelu MLP 128->256->128, softmax-weighted) + final residual.
// Writes final output. Block: 32 px, 256 thr.
__global__ __launch_bounds__(256) void k_moe(
    const float* __restrict__ on, const float* __restrict__ rw, const float* __restrict__ rb,
    const float* __restrict__ w1, const float* __restrict__ b1,
    const float* __restrict__ w2, const float* __restrict__ b2,
    const float* __restrict__ Xre, const float* __restrict__ Xim,
    const float* __restrict__ xre, const float* __restrict__ xim,
    float* __restrict__ out) {
  int n = blockIdx.x >> 7, pt = blockIdx.x & 127;
  int p0 = pt * 32;
  __shared__ float onl[32][129];
  __shared__ __align__(16) float hid[32][68];
  __shared__ __align__(16) float moel[32][132];
  __shared__ float pr[32][4];
  int tid = threadIdx.x;
  size_t obase = ((size_t)n * 4096 + p0) * 128;
  for (int idx = tid; idx < 32 * 128; idx += 256) {
    int c = idx & 127, q = idx >> 7;
    onl[q][c] = on[obase + (size_t)q * 128 + c];
    moel[q][c] = 0.f;
  }
  __syncthreads();
  if (tid < 128) {
    int q = tid >> 2, e = tid & 3;
    float lg = rb[e];
    for (int c = 0; c < 128; ++c) lg += onl[q][c] * rw[c * 4 + e];
    pr[q][e] = lg;
  }
  __syncthreads();
  if (tid < 32) {
    float a0 = pr[tid][0], a1 = pr[tid][1], a2 = pr[tid][2], a3 = pr[tid][3];
    float m = fmaxf(fmaxf(a0, a1), fmaxf(a2, a3));
    float e0 = expf(a0 - m), e1 = expf(a1 - m), e2 = expf(a2 - m), e3 = expf(a3 - m);
    float inv = 1.f / (e0 + e1 + e2 + e3);
    pr[tid][0] = e0 * inv; pr[tid][1] = e1 * inv; pr[tid][2] = e2 * inv; pr[tid][3] = e3 * inv;
  }
  __syncthreads();
  for (int e = 0; e < 4; ++e) {
    for (int mc = 0; mc < 4; ++mc) {
      {  // hid chunk: 32px x 64m
        int m4 = (tid & 15) * 4, pxg = tid >> 4;
        const float* w1p = w1 + (size_t)e * 128 * 256 + mc * 64 + m4;
        const float4 bv = *(const float4*)&b1[e * 256 + mc * 64 + m4];
        for (int i = 0; i < 2; ++i) {
          int q = pxg + 16 * i;
          float a0 = bv.x, a1 = bv.y, a2 = bv.z, a3 = bv.w;
          for (int c = 0; c < 128; ++c) {
            float ov = onl[q][c];
            float4 wv = *(const float4*)&w1p[(size_t)c * 256];
            a0 += ov * wv.x; a1 += ov * wv.y; a2 += ov * wv.z; a3 += ov * wv.w;
          }
          hid[q][m4 + 0] = gelu_f(a0);
          hid[q][m4 + 1] = gelu_f(a1);
          hid[q][m4 + 2] = gelu_f(a2);
          hid[q][m4 + 3] = gelu_f(a3);
        }
      }
      __syncthreads();
      {  // eo chunk accumulate into moel (weighted by probs)
        int c4 = (tid & 31) * 4, pq = tid >> 5;
        const float* w2p = w2 + ((size_t)e * 256 + mc * 64) * 128 + c4;
        float4 bv = make_float4(0.f, 0.f, 0.f, 0.f);
        if (mc == 0) bv = *(const float4*)&b2[e * 128 + c4];
        for (int i = 0; i < 4; ++i) {
          int q = pq + 8 * i;
          float a0 = bv.x, a1 = bv.y, a2 = bv.z, a3 = bv.w;
          for (int m = 0; m < 64; ++m) {
            float hv = hid[q][m];
            const float4 wv = *(const float4*)&w2p[(size_t)m * 128];
            a0 += hv * wv.x; a1 += hv * wv.y; a2 += hv * wv.z; a3 += hv * wv.w;
          }
          float pe = pr[q][e];
          moel[q][c4 + 0] += pe * a0;
          moel[q][c4 + 1] += pe * a1;
          moel[q][c4 + 2] += pe * a2;
          moel[q][c4 + 3] += pe * a3;
        }
      }
      __syncthreads();
    }
  }
  // final: z = (xf + conv) + (xc + delta); out layout (b,t,c,h,w)
  for (int idx = tid; idx < 32 * 64; idx += 256) {
    int px = idx & 31, d = idx >> 5;
    size_t off = ((size_t)n * 64 + d) * 4096 + p0 + px;
    float zr = Xre[off] + xre[off] + onl[px][d] + moel[px][d];
    float zi = Xim[off] + xim[off] + onl[px][64 + d] + moel[px][64 + d];
    out[((size_t)n * 128 + d) * 4096 + p0 + px] = zr;
    out[((size_t)n * 128 + 64 + d) * 4096 + p0 + px] = zi;
  }
}

extern "C" void kernel_launch(void* const* d_in, const int* in_sizes, int n_in,
                              void* d_out, int out_size, void* d_ws, size_t ws_size,
                              hipStream_t stream) {
  const float* xre = (const float*)d_in[0];
  const float* xim = (const float*)d_in[1];
  const float* hre = (const float*)d_in[2];
  const float* him = (const float*)d_in[3];
  const float* dt = (const float*)d_in[4];
  const float* fre = (const float*)d_in[5];
  const float* fim = (const float*)d_in[6];
  const float* nsg = (const float*)d_in[7];
  const float* nsb = (const float*)d_in[8];
  const float* cw = (const float*)d_in[9];
  const float* cb = (const float*)d_in[10];
  const float* Ere = (const float*)d_in[11];
  const float* Eim = (const float*)d_in[12];
  const float* Fre = (const float*)d_in[13];
  const float* Fim = (const float*)d_in[14];
  const float* mixw = (const float*)d_in[15];
  const float* mixb = (const float*)d_in[16];
  const float* nu = (const float*)d_in[17];
  const float* th = (const float*)d_in[18];
  const float* srcw = (const float*)d_in[19];
  const float* srcb = (const float*)d_in[20];
  const float* gw = (const float*)d_in[21];
  const float* gbv = (const float*)d_in[22];
  const float* la = (const float*)d_in[23];
  const float* lb = (const float*)d_in[24];
  const float* ntg = (const float*)d_in[25];
  const float* ntb = (const float*)d_in[26];
  const float* rw = (const float*)d_in[27];
  const float* rb = (const float*)d_in[28];
  const float* w1 = (const float*)d_in[29];
  const float* b1 = (const float*)d_in[30];
  const float* w2 = (const float*)d_in[31];
  const float* b2 = (const float*)d_in[32];

  float* ws = (float*)d_ws;
  float* Xre_ = ws;                 // PLANE
  float* Xim_ = ws + PLANE;         // PLANE
  float* Wr = ws + 2 * PLANE;       // slot1: repacked conv weights (dead after conv)
  float* onb = ws + 2 * PLANE;      // slot1 reused: `on` buffer
  float* sm = ws + 2 * PLANE + BIGSZ;
  float2* Xm = (float2*)sm;                         // TN*64
  float2* xmix = Xm + TN * 64;
  float2* fsb = xmix + TN * 64;
  float* gbuf = (float*)(fsb + TN * 64);            // TN*64 floats
  float2* srcv = (float2*)(gbuf + TN * 64);
  float2* opdv = srcv + TN * 64;
  float2* opfv = opdv + TN * 64;

  float* out = (float*)d_out;
  float* xn = (float*)d_out;        // d_out reused as xn, then U, then final
  float* U_re = (float*)d_out;
  float* U_im = U_re + PLANE;

  hipLaunchKernelGGL(k_repack, dim3(576), dim3(256), 0, stream, cw, Wr);
  hipLaunchKernelGGL(k_ln_in, dim3(TN * 64), dim3(256), 0, stream, xre, xim, nsg, nsb, xn);
  hipLaunchKernelGGL(k_conv, dim3(TN * 64), dim3(512), 0, stream, xn, Wr, cb, Xre_, Xim_);
  hipLaunchKernelGGL(k_xmean, dim3(TN * 64), dim3(256), 0, stream, Xre_, Xim_, xre, xim, Xm);
  hipLaunchKernelGGL(k_chainA, dim3(TN), dim3(128), 0, stream, Xm, Ere, Eim, mixw, mixb, xmix);
  hipLaunchKernelGGL(k_chainB, dim3(1), dim3(128), 0, stream, xmix, nu, th, fre, fim, fsb);
  hipLaunchKernelGGL(k_chainC, dim3(TN), dim3(128), 0, stream, fsb, srcw, srcb, gw, gbv, la, lb,
                     dt, gbuf, srcv, opdv, opfv);
  hipLaunchKernelGGL(k_ut, dim3(TN * 64), dim3(256), 0, stream, Xre_, Xim_, xre, xim, Ere, Eim,
                     gbuf, srcv, opdv, opfv, hre, him, U_re, U_im);
  hipLaunchKernelGGL(k_scan, dim3(2048), dim3(256), 0, stream, U_re, U_im, opdv);
  hipLaunchKernelGGL(k_xdec, dim3(TN * 64), dim3(256), 0, stream, U_re, U_im, Fre, Fim, ntg, ntb,
                     onb);
  hipLaunchKernelGGL(k_moe, dim3(TN * 128), dim3(256), 0, stream, onb, rw, rb, w1, b1, w2, b2,
                     Xre_, Xim_, xre, xim, out);
  (void)in_sizes; (void)n_in; (void)out_size; (void)ws_size;
}

// Round 2
// 2924.044 us; speedup vs baseline: 3.3643x; 3.3643x over previous
//
#include <hip/hip_runtime.h>

// UniPhyBlock pipeline, round 1: MoE moved to bf16 MFMA.
// B=2 T=16 D=64 H=W=64, C=128, E=4 experts, M=256.

#define DEV static __device__ __forceinline__

typedef __attribute__((ext_vector_type(8))) short bf16x8;
typedef __attribute__((ext_vector_type(4))) float f32x4;

namespace {
constexpr int TN = 32;          // B*T
constexpr size_t PLANE = (size_t)TN * 64 * 4096;   // 8,388,608
constexpr size_t BIGSZ = (size_t)TN * 4096 * 128;  // 16,777,216

DEV float sp_f(float x) { return x > 20.f ? x : log1pf(expf(x)); }
DEV unsigned short f2bf(float f) {
  unsigned int u = __float_as_uint(f);
  unsigned int r = (u + 0x7FFFu + ((u >> 16) & 1u)) >> 16;
  return (unsigned short)r;
}
DEV float bf2f(unsigned short s) { return __uint_as_float(((unsigned int)s) << 16); }
DEV float gelu_f(float x) {
  float z = 0.7978845608028654f * (x + 0.044715f * x * x * x);
  float t = 1.f - 2.f / (__expf(2.f * z) + 1.f);   // tanh(z)
  return 0.5f * x * (1.f + t);
}
} // namespace

// K0: repack conv_w (Co,Ci,3,3) -> Wr[k][co][ci], k=kh*3+kw
__global__ void k_repack(const float* __restrict__ cw, float* __restrict__ Wr) {
  int i = blockIdx.x * 256 + threadIdx.x;
  if (i >= 9 * 128 * 128) return;
  int ci = i & 127, co = (i >> 7) & 127, k = i >> 14;
  Wr[i] = cw[((size_t)co * 128 + ci) * 9 + k];
}

// K0b: repack w1/w2 to bf16 MFMA B-fragment order.
// w1p[e][kt<4][ntG<16][l<64][j<8] = w1[e][kt*32+(l>>4)*8+j][ntG*16+(l&15)]
// w2p[e][kt<8][ct<8][l<64][j<8]   = w2[e][kt*32+(l>>4)*8+j][ct*16+(l&15)]
__global__ void k_repw(const float* __restrict__ w1, const float* __restrict__ w2,
                       unsigned short* __restrict__ w1p, unsigned short* __restrict__ w2p) {
  int i = blockIdx.x * 256 + threadIdx.x;  // 262144
  int half = i >> 17;
  int idx = i & 131071;
  int j = idx & 7, l = (idx >> 3) & 63;
  if (half == 0) {
    int nt = (idx >> 9) & 15, kt = (idx >> 13) & 3, e = idx >> 15;
    int c = kt * 32 + (l >> 4) * 8 + j, m = nt * 16 + (l & 15);
    w1p[idx] = f2bf(w1[((size_t)e * 128 + c) * 256 + m]);
  } else {
    int ct = (idx >> 9) & 7, kt = (idx >> 12) & 7, e = idx >> 15;
    int m = kt * 32 + (l >> 4) * 8 + j, c = ct * 16 + (l & 15);
    w2p[idx] = f2bf(w2[((size_t)e * 256 + m) * 128 + c]);
  }
}

// K1: layernorm over channels [re(0..63), im(0..63)] -> xn [n][p][c]
__global__ __launch_bounds__(256) void k_ln_in(
    const float* __restrict__ xre, const float* __restrict__ xim,
    const float* __restrict__ gg, const float* __restrict__ bb,
    float* __restrict__ xn) {
  int n = blockIdx.x >> 6, h = blockIdx.x & 63;
  __shared__ float xl[64][129];
  __shared__ float ps[4][64], ps2[4][64];
  __shared__ float mu[64], rs[64];
  int tid = threadIdx.x;
  int w = tid & 63, q = tid >> 6;
  size_t base = ((size_t)n * 4096 + h) * 64 + w;
  for (int d = q; d < 64; d += 4) {
    size_t o = base + (size_t)d * 4096;
    xl[w][d] = xre[o];
    xl[w][64 + d] = xim[o];
  }
  __syncthreads();
  float s = 0.f, s2 = 0.f;
  for (int c = q * 32; c < q * 32 + 32; ++c) { float v = xl[w][c]; s += v; s2 += v * v; }
  ps[q][w] = s; ps2[q][w] = s2;
  __syncthreads();
  if (tid < 64) {
    float a = 0.f, b2 = 0.f;
#pragma unroll
    for (int i = 0; i < 4; ++i) { a += ps[i][tid]; b2 += ps2[i][tid]; }
    float m = a * (1.f / 128.f);
    mu[tid] = m;
    rs[tid] = rsqrtf(b2 * (1.f / 128.f) - m * m + 1e-5f);
  }
  __syncthreads();
  size_t obase = (((size_t)n * 64 + h) * 64) * 128;
  for (int idx = tid; idx < 64 * 128; idx += 256) {
    int c = idx & 127, p2 = idx >> 7;
    xn[obase + (size_t)p2 * 128 + c] = (xl[p2][c] - mu[p2]) * rs[p2] * gg[c] + bb[c];
  }
}

// K2: 3x3 SAME conv, 128->128 ch.
__global__ __launch_bounds__(512) void k_conv(
    const float* __restrict__ xn, const float* __restrict__ Wr,
    const float* __restrict__ cbias, float* __restrict__ Xre, float* __restrict__ Xim) {
  int n = blockIdx.x >> 6, h = blockIdx.x & 63;
  __shared__ __align__(16) float in_t[3][66][68];
  __shared__ float acc_l[128][65];
  int tid = threadIdx.x;
  int px = tid & 63;
  int cgu = __builtin_amdgcn_readfirstlane(tid >> 6);
  float acc[16];
#pragma unroll
  for (int j = 0; j < 16; ++j) acc[j] = 0.f;
  for (int chunk = 0; chunk < 2; ++chunk) {
    __syncthreads();
    for (int idx = tid; idx < 3 * 66 * 64; idx += 512) {
      int r = idx / (66 * 64);
      int rem = idx - r * (66 * 64);
      int p = rem >> 6, ci = rem & 63;
      int hh = h + r - 1, wg = p - 1;
      float v = 0.f;
      if ((unsigned)hh < 64u && (unsigned)wg < 64u)
        v = xn[(((size_t)n * 64 + hh) * 64 + wg) * 128 + chunk * 64 + ci];
      in_t[r][p][ci] = v;
    }
    __syncthreads();
#pragma unroll
    for (int kh = 0; kh < 3; ++kh) {
#pragma unroll
      for (int kw = 0; kw < 3; ++kw) {
        const float* wb = Wr + (((size_t)(kh * 3 + kw) * 128 + cgu * 16) * 128) + chunk * 64;
#pragma unroll 2
        for (int c4 = 0; c4 < 16; ++c4) {
          float4 inv = *(const float4*)&in_t[kh][px + kw][c4 * 4];
#pragma unroll
          for (int j = 0; j < 16; ++j) {
            float4 wv = *(const float4*)&wb[j * 128 + c4 * 4];
            acc[j] += inv.x * wv.x + inv.y * wv.y + inv.z * wv.z + inv.w * wv.w;
          }
        }
      }
    }
  }
  {
    int cg = tid >> 6;
#pragma unroll
    for (int j = 0; j < 16; ++j) acc_l[cg * 16 + j][px] = acc[j] + cbias[cg * 16 + j];
  }
  __syncthreads();
  for (int idx = tid; idx < 64 * 128; idx += 512) {
    int p2 = idx & 63, c = idx >> 6;
    float v = acc_l[c][p2];
    size_t off = ((size_t)n * 64 + (c & 63)) * 4096 + (size_t)h * 64 + p2;
    if (c < 64) Xre[off] = v; else Xim[off] = v;
  }
}

// K3: Xm[n][d] = mean_p (X + xf).
__global__ __launch_bounds__(256) void k_xmean(
    const float* __restrict__ Xre, const float* __restrict__ Xim,
    const float* __restrict__ xre, const float* __restrict__ xim,
    float2* __restrict__ Xm) {
  int nd = blockIdx.x;
  size_t base = (size_t)nd * 4096;
  int tid = threadIdx.x;
  float sr = 0.f, si = 0.f;
  for (int p = tid; p < 4096; p += 256) {
    sr += Xre[base + p] + xre[base + p];
    si += Xim[base + p] + xim[base + p];
  }
  __shared__ float r1[256], r2[256];
  r1[tid] = sr; r2[tid] = si;
  __syncthreads();
  for (int s = 128; s > 0; s >>= 1) {
    if (tid < s) { r1[tid] += r1[tid + s]; r2[tid] += r2[tid + s]; }
    __syncthreads();
  }
  if (tid == 0) Xm[nd] = make_float2(r1[0] * (1.f / 4096.f), r2[0] * (1.f / 4096.f));
}

// K4: per (b,t): xmean = Xm @ Ec; fcat = [re,im] @ mix_w + mix_b
__global__ void k_chainA(const float2* __restrict__ Xm, const float* __restrict__ Ere,
                         const float* __restrict__ Eim, const float* __restrict__ mixw,
                         const float* __restrict__ mixb, float2* __restrict__ xmix) {
  int n = blockIdx.x;
  int tid = threadIdx.x;  // 128
  __shared__ float2 xm[64];
  __shared__ float cat[128];
  __shared__ float fc[128];
  if (tid < 64) xm[tid] = Xm[n * 64 + tid];
  __syncthreads();
  if (tid < 64) {
    float ar = 0.f, ai = 0.f;
    for (int d = 0; d < 64; ++d) {
      float2 x = xm[d];
      float er = Ere[d * 64 + tid], ei = Eim[d * 64 + tid];
      ar += x.x * er - x.y * ei;
      ai += x.x * ei + x.y * er;
    }
    cat[tid] = ar; cat[64 + tid] = ai;
  }
  __syncthreads();
  {
    float f = mixb[tid];
    for (int i = 0; i < 128; ++i) f += cat[i] * mixw[i * 128 + tid];
    fc[tid] = f;
  }
  __syncthreads();
  if (tid < 64) xmix[n * 64 + tid] = make_float2(fc[tid], fc[64 + tid]);
}

// K5: flux scan over t
__global__ void k_chainB(const float2* __restrict__ xmix, const float* __restrict__ nu,
                         const float* __restrict__ th, const float* __restrict__ fre,
                         const float* __restrict__ fim, float2* __restrict__ fs) {
  int tid = threadIdx.x;  // 128
  int b = tid >> 6, d = tid & 63;
  float r = expf(-sp_f(nu[d]));
  float dr = r * cosf(th[d]), di = r * sinf(th[d]);
  float yr = 0.f, yi = 0.f, cr = 1.f, ci = 0.f;
  float fr = fre[b * 64 + d], fi = fim[b * 64 + d];
  for (int t = 0; t < 16; ++t) {
    int n = b * 16 + t;
    float ncr = cr * dr - ci * di, nci = cr * di + ci * dr;
    cr = ncr; ci = nci;
    float2 xm = xmix[n * 64 + d];
    float nyr = dr * yr - di * yi + xm.x;
    float nyi = dr * yi + di * yr + xm.y;
    yr = nyr; yi = nyi;
    fs[n * 64 + d] = make_float2(yr + fr * cr - fi * ci, yi + fr * ci + fi * cr);
  }
}

// K6: per (b,t): source, gate, op_decay, op_forcing
__global__ void k_chainC(const float2* __restrict__ fs, const float* __restrict__ srcw,
                         const float* __restrict__ srcb, const float* __restrict__ gw,
                         const float* __restrict__ gbv, const float* __restrict__ la,
                         const float* __restrict__ lbv, const float* __restrict__ dt,
                         float* __restrict__ g, float2* __restrict__ src,
                         float2* __restrict__ opd, float2* __restrict__ opf) {
  int n = blockIdx.x;
  int t = n & 15;
  int tid = threadIdx.x;  // 128
  __shared__ float oc[128];
  __shared__ float sl[128];
  if (tid < 64) { float2 v = fs[n * 64 + tid]; oc[tid] = v.x; oc[64 + tid] = v.y; }
  __syncthreads();
  {
    float s = srcb[tid];
    for (int i = 0; i < 128; ++i) s += oc[i] * srcw[i * 128 + tid];
    sl[tid] = s;
  }
  if (tid < 64) {
    float gv = gbv[tid];
    for (int i = 0; i < 128; ++i) gv += oc[i] * gw[i * 64 + tid];
    g[n * 64 + tid] = 1.f / (1.f + expf(-gv));
    float lr = -sp_f(la[tid]), li = lbv[tid];
    float dtv = dt[t];
    float er = expf(lr * dtv);
    float2 od = make_float2(er * cosf(li * dtv), er * sinf(li * dtv));
    opd[n * 64 + tid] = od;
    float inv = 1.f / (lr * lr + li * li);
    float nx = od.x - 1.f, ny = od.y;
    opf[n * 64 + tid] = make_float2((nx * lr + ny * li) * inv, (ny * lr - nx * li) * inv);
  }
  __syncthreads();
  if (tid < 64) src[n * 64 + tid] = make_float2(sl[tid], sl[64 + tid]);
}

// K7: u_t
__global__ __launch_bounds__(256) void k_ut(
    const float* __restrict__ Xre, const float* __restrict__ Xim,
    const float* __restrict__ xre, const float* __restrict__ xim,
    const float* __restrict__ Ere, const float* __restrict__ Eim,
    const float* __restrict__ g, const float2* __restrict__ src,
    const float2* __restrict__ opd, const float2* __restrict__ opf,
    const float* __restrict__ hre, const float* __restrict__ him,
    float* __restrict__ Ure, float* __restrict__ Uim) {
  int n = blockIdx.x >> 6, pt = blockIdx.x & 63;
  int p0 = pt * 64;
  int b = n >> 4, t = n & 15;
  __shared__ float2 Ec[64][64];
  __shared__ float gl[64];
  __shared__ float2 sl[64], ofl[64], odl[64];
  int tid = threadIdx.x;
  for (int idx = tid; idx < 4096; idx += 256)
    Ec[idx >> 6][idx & 63] = make_float2(Ere[idx], Eim[idx]);
  if (tid < 64) {
    gl[tid] = g[n * 64 + tid]; sl[tid] = src[n * 64 + tid];
    ofl[tid] = opf[n * 64 + tid]; odl[tid] = opd[n * 64 + tid];
  }
  __syncthreads();
  int px = tid & 63, grp = tid >> 6;
  float ar[16], ai[16];
#pragma unroll
  for (int j = 0; j < 16; ++j) { ar[j] = 0.f; ai[j] = 0.f; }
  size_t rowbase = (size_t)n * 64 * 4096 + p0 + px;
  for (int d = 0; d < 64; ++d) {
    size_t off = rowbase + (size_t)d * 4096;
    float xr = Xre[off] + xre[off];
    float xi = Xim[off] + xim[off];
#pragma unroll
    for (int j = 0; j < 16; ++j) {
      float2 e = Ec[d][grp * 16 + j];
      ar[j] += xr * e.x - xi * e.y;
      ai[j] += xr * e.y + xi * e.x;
    }
  }
#pragma unroll
  for (int j = 0; j < 16; ++j) {
    int ee = grp * 16 + j;
    float gv = gl[ee];
    float2 s = sl[ee];
    float fr = ar[j] * gv + s.x * (1.f - gv);
    float fi = ai[j] * gv + s.y * (1.f - gv);
    float2 of = ofl[ee];
    float ur = fr * of.x - fi * of.y;
    float ui = fr * of.y + fi * of.x;
    if (t == 0) {
      size_t hoff = ((size_t)b * 4096 + p0 + px) * 64 + ee;
      float hr = hre[hoff], hi = him[hoff];
      float2 od = odl[ee];
      ur += hr * od.x - hi * od.y;
      ui += hr * od.y + hi * od.x;
    }
    size_t off = ((size_t)n * 64 + ee) * 4096 + p0 + px;
    Ure[off] = ur; Uim[off] = ui;
  }
}

// K8: associative scan over t (in place on U)
__global__ __launch_bounds__(256) void k_scan(float* __restrict__ Ure, float* __restrict__ Uim,
                                              const float2* __restrict__ opd) {
  int gid = blockIdx.x * 256 + threadIdx.x;  // 524288
  int p = gid & 4095, d = (gid >> 12) & 63, b = gid >> 18;
  float yr = 0.f, yi = 0.f;
  for (int t = 0; t < 16; ++t) {
    int n = b * 16 + t;
    float2 od = opd[n * 64 + d];
    size_t off = ((size_t)n * 64 + d) * 4096 + p;
    float ur = Ure[off], ui = Uim[off];
    float nyr = od.x * yr - od.y * yi + ur;
    float nyi = od.x * yi + od.y * yr + ui;
    yr = nyr; yi = nyi;
    Ure[off] = yr; Uim[off] = yi;
  }
}

// K9: x_dec = u_out @ Fc, layernorm -> on (bf16) [n][p][c]
__global__ __launch_bounds__(256) void k_xdec(
    const float* __restrict__ Ure, const float* __restrict__ Uim,
    const float* __restrict__ Fre, const float* __restrict__ Fim,
    const float* __restrict__ ntg, const float* __restrict__ ntb,
    unsigned short* __restrict__ onb) {
  int n = blockIdx.x >> 6, pt = blockIdx.x & 63;
  int p0 = pt * 64;
  __shared__ float2 Fc[64][64];
  __shared__ float onl[64][129];
  __shared__ float ps[4][64], ps2[4][64];
  __shared__ float mu[64], rs[64];
  int tid = threadIdx.x;
  for (int idx = tid; idx < 4096; idx += 256)
    Fc[idx >> 6][idx & 63] = make_float2(Fre[idx], Fim[idx]);
  __syncthreads();
  int px = tid & 63, grp = tid >> 6;
  float ar[16], ai[16];
#pragma unroll
  for (int j = 0; j < 16; ++j) { ar[j] = 0.f; ai[j] = 0.f; }
  size_t rowbase = (size_t)n * 64 * 4096 + p0 + px;
  for (int d = 0; d < 64; ++d) {
    size_t off = rowbase + (size_t)d * 4096;
    float xr = Ure[off], xi = Uim[off];
#pragma unroll
    for (int j = 0; j < 16; ++j) {
      float2 e = Fc[d][grp * 16 + j];
      ar[j] += xr * e.x - xi * e.y;
      ai[j] += xr * e.y + xi * e.x;
    }
  }
#pragma unroll
  for (int j = 0; j < 16; ++j) {
    int ee = grp * 16 + j;
    onl[px][ee] = ar[j];
    onl[px][64 + ee] = ai[j];
  }
  __syncthreads();
  float s = 0.f, s2 = 0.f;
  for (int c = grp * 32; c < grp * 32 + 32; ++c) { float v = onl[px][c]; s += v; s2 += v * v; }
  ps[grp][px] = s; ps2[grp][px] = s2;
  __syncthreads();
  if (tid < 64) {
    float a = 0.f, b2 = 0.f;
#pragma unroll
    for (int i = 0; i < 4; ++i) { a += ps[i][tid]; b2 += ps2[i][tid]; }
    float m = a * (1.f / 128.f);
    mu[tid] = m;
    rs[tid] = rsqrtf(b2 * (1.f / 128.f) - m * m + 1e-5f);
  }
  __syncthreads();
  size_t obase = ((size_t)n * 4096 + p0) * 128;
  for (int idx = tid; idx < 64 * 64; idx += 256) {
    int q = idx >> 6, c2 = (idx & 63) * 2;
    float v0 = (onl[q][c2] - mu[q]) * rs[q] * ntg[c2] + ntb[c2];
    float v1 = (onl[q][c2 + 1] - mu[q]) * rs[q] * ntg[c2 + 1] + ntb[c2 + 1];
    unsigned int pk = (unsigned int)f2bf(v0) | ((unsigned int)f2bf(v1) << 16);
    *(unsigned int*)&onb[obase + (size_t)q * 128 + c2] = pk;
  }
}

// K10: MFMA MoE + final residual. 64-px tile, 256 thr (4 waves).
// LDS: At (64x128 bf16, swizzled) + hidbuf (64x256 bf16 / 64x129 f32 union) + pr.
__global__ __launch_bounds__(256) void k_moe2(
    const unsigned short* __restrict__ onb, const unsigned short* __restrict__ w1p,
    const unsigned short* __restrict__ w2p, const float* __restrict__ rw,
    const float* __restrict__ rb, const float* __restrict__ b1, const float* __restrict__ b2,
    const float* __restrict__ Xre, const float* __restrict__ Xim,
    const float* __restrict__ xre, const float* __restrict__ xim,
    float* __restrict__ out) {
  int n = blockIdx.x >> 6, ptile = blockIdx.x & 63;
  int p0 = ptile * 64;
  __shared__ __align__(16) short At[64 * 128];        // 16KB, swizzled
  __shared__ __align__(16) char hidbuf[64 * 129 * 4]; // 33024B: hid bf16 / fin f32
  __shared__ float pr[64][4];
  short* hid = (short*)hidbuf;
  float* fin = (float*)hidbuf;
  int tid = threadIdx.x;
  int l = tid & 63;
  int w = __builtin_amdgcn_readfirstlane(tid >> 6);

  // stage A tile: on[n][p0..p0+64][0..128] bf16 -> LDS swizzled
  {
    const char* gsrc = (const char*)onb + ((size_t)n * 4096 + p0) * 256;
#pragma unroll
    for (int it = 0; it < 4; ++it) {
      int ch = tid + it * 256;           // 1024 chunks of 16B
      int row = ch >> 4, cb = (ch & 15) * 16;
      float4 v = *(const float4*)(gsrc + (size_t)row * 256 + cb);
      int off = (row * 256 + cb) ^ ((row & 7) << 4);
      *(float4*)((char*)At + off) = v;
    }
  }
  __syncthreads();

  // router: logits -> pr
  {
    int px = tid >> 2, e = tid & 3;
    float acc = rb[e];
    for (int c = 0; c < 128; ++c) {
      int off = (px * 256 + c * 2) ^ ((px & 7) << 4);
      acc += bf2f(((unsigned short*)At)[off >> 1]) * rw[c * 4 + e];
    }
    pr[px][e] = acc;
  }
  __syncthreads();
  if (tid < 64) {
    float a0 = pr[tid][0], a1 = pr[tid][1], a2 = pr[tid][2], a3 = pr[tid][3];
    float m = fmaxf(fmaxf(a0, a1), fmaxf(a2, a3));
    float e0 = __expf(a0 - m), e1 = __expf(a1 - m), e2 = __expf(a2 - m), e3 = __expf(a3 - m);
    float inv = 1.f / (e0 + e1 + e2 + e3);
    pr[tid][0] = e0 * inv; pr[tid][1] = e1 * inv; pr[tid][2] = e2 * inv; pr[tid][3] = e3 * inv;
  }
  __syncthreads();

  float macc[8][4];
#pragma unroll
  for (int ct = 0; ct < 8; ++ct)
#pragma unroll
    for (int r = 0; r < 4; ++r) macc[ct][r] = 0.f;

  for (int e = 0; e < 4; ++e) {
    // ---- GEMM1: hid[64px][m-range w*64..+64] = gelu(on @ w1 + b1)
#pragma unroll
    for (int nt = 0; nt < 4; ++nt) {
      int ntG = w * 4 + nt;
      bf16x8 bb[4];
#pragma unroll
      for (int kt = 0; kt < 4; ++kt)
        bb[kt] = *(const bf16x8*)(w1p + ((((size_t)(e * 4 + kt) * 16 + ntG) * 64 + l) * 8));
      float b1v = b1[e * 256 + ntG * 16 + (l & 15)];
#pragma unroll
      for (int pt = 0; pt < 4; ++pt) {
        f32x4 acc = {0.f, 0.f, 0.f, 0.f};
#pragma unroll
        for (int kt = 0; kt < 4; ++kt) {
          int row = pt * 16 + (l & 15);
          int off = (row * 256 + kt * 64 + (l >> 4) * 16) ^ ((row & 7) << 4);
          bf16x8 aa = *(const bf16x8*)((const char*)At + off);
          acc = __builtin_amdgcn_mfma_f32_16x16x32_bf16(aa, bb[kt], acc, 0, 0, 0);
        }
        int mcol = ntG * 16 + (l & 15);
#pragma unroll
        for (int r = 0; r < 4; ++r) {
          int row = pt * 16 + (l >> 4) * 4 + r;
          float v = gelu_f(acc[r] + b1v);
          int off = (row * 512 + mcol * 2) ^ ((row & 7) << 4);
          hid[off >> 1] = (short)f2bf(v);
        }
      }
    }
    __syncthreads();
    // ---- GEMM2: eo[px-range w*16..+16][128c] = hid @ w2 + b2; macc += pr_e * eo
    {
      bf16x8 a2f[8];
#pragma unroll
      for (int kt = 0; kt < 8; ++kt) {
        int row = w * 16 + (l & 15);
        int off = (row * 512 + kt * 64 + (l >> 4) * 16) ^ ((row & 7) << 4);
        a2f[kt] = *(const bf16x8*)((const char*)hid + off);
      }
      float pw[4];
#pragma unroll
      for (int r = 0; r < 4; ++r) pw[r] = pr[w * 16 + (l >> 4) * 4 + r][e];
#pragma unroll
      for (int ct = 0; ct < 8; ++ct) {
        f32x4 acc = {0.f, 0.f, 0.f, 0.f};
#pragma unroll
        for (int kt = 0; kt < 8; ++kt) {
          bf16x8 b2f = *(const bf16x8*)(w2p + ((((size_t)(e * 8 + kt) * 8 + ct) * 64 + l) * 8));
          acc = __builtin_amdgcn_mfma_f32_16x16x32_bf16(a2f[kt], b2f, acc, 0, 0, 0);
        }
        float b2v = b2[e * 128 + ct * 16 + (l & 15)];
#pragma unroll
        for (int r = 0; r < 4; ++r) macc[ct][r] += (acc[r] + b2v) * pw[r];
      }
    }
    __syncthreads();
  }

  // fin[px][c] = on + moe  (f32, stride 129 — conflict-free columns)
#pragma unroll
  for (int ct = 0; ct < 8; ++ct) {
#pragma unroll
    for (int r = 0; r < 4; ++r) {
      int row = w * 16 + (l >> 4) * 4 + r;
      int c = ct * 16 + (l & 15);
      int aoff = (row * 256 + c * 2) ^ ((row & 7) << 4);
      float onv = bf2f(((unsigned short*)At)[aoff >> 1]);
      fin[row * 129 + c] = macc[ct][r] + onv;
    }
  }
  __syncthreads();
  // final: out = (X + xf) + fin ; layout (n, ch, p)
  for (int idx = tid; idx < 64 * 128; idx += 256) {
    int px = idx & 63, ch = idx >> 6;
    size_t off = ((size_t)n * 64 + (ch & 63)) * 4096 + p0 + px;
    float resid = (ch < 64) ? (Xre[off] + xre[off]) : (Xim[off] + xim[off]);
    out[((size_t)n * 128 + ch) * 4096 + p0 + px] = resid + fin[px * 129 + ch];
  }
}

extern "C" void kernel_launch(void* const* d_in, const int* in_sizes, int n_in,
                              void* d_out, int out_size, void* d_ws, size_t ws_size,
                              hipStream_t stream) {
  const float* xre = (const float*)d_in[0];
  const float* xim = (const float*)d_in[1];
  const float* hre = (const float*)d_in[2];
  const float* him = (const float*)d_in[3];
  const float* dt = (const float*)d_in[4];
  const float* fre = (const float*)d_in[5];
  const float* fim = (const float*)d_in[6];
  const float* nsg = (const float*)d_in[7];
  const float* nsb = (const float*)d_in[8];
  const float* cw = (const float*)d_in[9];
  const float* cb = (const float*)d_in[10];
  const float* Ere = (const float*)d_in[11];
  const float* Eim = (const float*)d_in[12];
  const float* Fre = (const float*)d_in[13];
  const float* Fim = (const float*)d_in[14];
  const float* mixw = (const float*)d_in[15];
  const float* mixb = (const float*)d_in[16];
  const float* nu = (const float*)d_in[17];
  const float* th = (const float*)d_in[18];
  const float* srcw = (const float*)d_in[19];
  const float* srcb = (const float*)d_in[20];
  const float* gw = (const float*)d_in[21];
  const float* gbv = (const float*)d_in[22];
  const float* la = (const float*)d_in[23];
  const float* lb = (const float*)d_in[24];
  const float* ntg = (const float*)d_in[25];
  const float* ntb = (const float*)d_in[26];
  const float* rw = (const float*)d_in[27];
  const float* rb = (const float*)d_in[28];
  const float* w1 = (const float*)d_in[29];
  const float* b1 = (const float*)d_in[30];
  const float* w2 = (const float*)d_in[31];
  const float* b2 = (const float*)d_in[32];

  float* ws = (float*)d_ws;
  float* Xre_ = ws;
  float* Xim_ = ws + PLANE;
  unsigned short* onb16 = (unsigned short*)(ws + 2 * PLANE);  // BIGSZ bf16
  float* Wr = ws + 2 * PLANE + BIGSZ / 2;                     // 147456 f32
  unsigned short* w1p = (unsigned short*)(Wr + 147456);       // 131072 bf16
  unsigned short* w2p = w1p + 131072;                         // 131072 bf16
  float* sm = (float*)(w2p + 131072);
  float2* Xm = (float2*)sm;
  float2* xmix = Xm + TN * 64;
  float2* fsb = xmix + TN * 64;
  float* gbuf = (float*)(fsb + TN * 64);
  float2* srcv = (float2*)(gbuf + TN * 64);
  float2* opdv = srcv + TN * 64;
  float2* opfv = opdv + TN * 64;

  float* out = (float*)d_out;
  float* xn = (float*)d_out;
  float* U_re = (float*)d_out;
  float* U_im = U_re + PLANE;

  hipLaunchKernelGGL(k_repack, dim3(576), dim3(256), 0, stream, cw, Wr);
  hipLaunchKernelGGL(k_repw, dim3(1024), dim3(256), 0, stream, w1, w2, w1p, w2p);
  hipLaunchKernelGGL(k_ln_in, dim3(TN * 64), dim3(256), 0, stream, xre, xim, nsg, nsb, xn);
  hipLaunchKernelGGL(k_conv, dim3(TN * 64), dim3(512), 0, stream, xn, Wr, cb, Xre_, Xim_);
  hipLaunchKernelGGL(k_xmean, dim3(TN * 64), dim3(256), 0, stream, Xre_, Xim_, xre, xim, Xm);
  hipLaunchKernelGGL(k_chainA, dim3(TN), dim3(128), 0, stream, Xm, Ere, Eim, mixw, mixb, xmix);
  hipLaunchKernelGGL(k_chainB, dim3(1), dim3(128), 0, stream, xmix, nu, th, fre, fim, fsb);
  hipLaunchKernelGGL(k_chainC, dim3(TN), dim3(128), 0, stream, fsb, srcw, srcb, gw, gbv, la, lb,
                     dt, gbuf, srcv, opdv, opfv);
  hipLaunchKernelGGL(k_ut, dim3(TN * 64), dim3(256), 0, stream, Xre_, Xim_, xre, xim, Ere, Eim,
                     gbuf, srcv, opdv, opfv, hre, him, U_re, U_im);
  hipLaunchKernelGGL(k_scan, dim3(2048), dim3(256), 0, stream, U_re, U_im, opdv);
  hipLaunchKernelGGL(k_xdec, dim3(TN * 64), dim3(256), 0, stream, U_re, U_im, Fre, Fim, ntg, ntb,
                     onb16);
  hipLaunchKernelGGL(k_moe2, dim3(TN * 64), dim3(256), 0, stream, onb16, w1p, w2p, rw, rb, b1, b2,
                     Xre_, Xim_, xre, xim, out);
  (void)in_sizes; (void)n_in; (void)out_size; (void)ws_size;
}

// Round 3
// 821.278 us; speedup vs baseline: 11.9782x; 3.5604x over previous
//
#include <hip/hip_runtime.h>

// UniPhyBlock pipeline, round 2: conv moved to bf16 MFMA implicit GEMM.
// B=2 T=16 D=64 H=W=64, C=128, E=4 experts, M=256.

#define DEV static __device__ __forceinline__

typedef __attribute__((ext_vector_type(8))) short bf16x8;
typedef __attribute__((ext_vector_type(4))) float f32x4;

namespace {
constexpr int TN = 32;          // B*T
constexpr size_t PLANE = (size_t)TN * 64 * 4096;   // 8,388,608
constexpr size_t BIGSZ = (size_t)TN * 4096 * 128;  // 16,777,216

DEV float sp_f(float x) { return x > 20.f ? x : log1pf(expf(x)); }
DEV unsigned short f2bf(float f) {
  unsigned int u = __float_as_uint(f);
  unsigned int r = (u + 0x7FFFu + ((u >> 16) & 1u)) >> 16;
  return (unsigned short)r;
}
DEV float bf2f(unsigned short s) { return __uint_as_float(((unsigned int)s) << 16); }
DEV float gelu_f(float x) {
  float z = 0.7978845608028654f * (x + 0.044715f * x * x * x);
  float t = 1.f - 2.f / (__expf(2.f * z) + 1.f);   // tanh(z)
  return 0.5f * x * (1.f + t);
}
} // namespace

// K0c: repack conv_w (Co,Ci,3,3) fp32 -> bf16 MFMA B-fragments
// wcv[k][cb][ct][l][j] = cw[ct*16+(l&15)][cb*32+(l>>4)*8+j][k]
__global__ void k_repc(const float* __restrict__ cw, unsigned short* __restrict__ wcv) {
  int i = blockIdx.x * 256 + threadIdx.x;  // 147456
  if (i >= 9 * 4 * 8 * 64 * 8) return;
  int j = i & 7, l = (i >> 3) & 63, ct = (i >> 9) & 7, cb = (i >> 12) & 3, k = i >> 14;
  int co = ct * 16 + (l & 15);
  int ci = cb * 32 + (l >> 4) * 8 + j;
  wcv[i] = f2bf(cw[((size_t)co * 128 + ci) * 9 + k]);
}

// K0b: repack w1/w2 to bf16 MFMA B-fragment order.
__global__ void k_repw(const float* __restrict__ w1, const float* __restrict__ w2,
                       unsigned short* __restrict__ w1p, unsigned short* __restrict__ w2p) {
  int i = blockIdx.x * 256 + threadIdx.x;  // 262144
  int half = i >> 17;
  int idx = i & 131071;
  int j = idx & 7, l = (idx >> 3) & 63;
  if (half == 0) {
    int nt = (idx >> 9) & 15, kt = (idx >> 13) & 3, e = idx >> 15;
    int c = kt * 32 + (l >> 4) * 8 + j, m = nt * 16 + (l & 15);
    w1p[idx] = f2bf(w1[((size_t)e * 128 + c) * 256 + m]);
  } else {
    int ct = (idx >> 9) & 7, kt = (idx >> 12) & 7, e = idx >> 15;
    int m = kt * 32 + (l >> 4) * 8 + j, c = ct * 16 + (l & 15);
    w2p[idx] = f2bf(w2[((size_t)e * 256 + m) * 128 + c]);
  }
}

// K1: layernorm over channels -> xn bf16 [n][p][c]
__global__ __launch_bounds__(256) void k_ln_in(
    const float* __restrict__ xre, const float* __restrict__ xim,
    const float* __restrict__ gg, const float* __restrict__ bb,
    unsigned short* __restrict__ xnb) {
  int n = blockIdx.x >> 6, h = blockIdx.x & 63;
  __shared__ float xl[64][129];
  __shared__ float ps[4][64], ps2[4][64];
  __shared__ float mu[64], rs[64];
  int tid = threadIdx.x;
  int w = tid & 63, q = tid >> 6;
  size_t base = ((size_t)n * 4096 + h) * 64 + w;
  for (int d = q; d < 64; d += 4) {
    size_t o = base + (size_t)d * 4096;
    xl[w][d] = xre[o];
    xl[w][64 + d] = xim[o];
  }
  __syncthreads();
  float s = 0.f, s2 = 0.f;
  for (int c = q * 32; c < q * 32 + 32; ++c) { float v = xl[w][c]; s += v; s2 += v * v; }
  ps[q][w] = s; ps2[q][w] = s2;
  __syncthreads();
  if (tid < 64) {
    float a = 0.f, b2 = 0.f;
#pragma unroll
    for (int i = 0; i < 4; ++i) { a += ps[i][tid]; b2 += ps2[i][tid]; }
    float m = a * (1.f / 128.f);
    mu[tid] = m;
    rs[tid] = rsqrtf(b2 * (1.f / 128.f) - m * m + 1e-5f);
  }
  __syncthreads();
  size_t obase = ((size_t)n * 4096 + (size_t)h * 64) * 128;
  for (int idx = tid; idx < 64 * 64; idx += 256) {
    int q2 = idx >> 6, c2 = (idx & 63) * 2;
    float v0 = (xl[q2][c2] - mu[q2]) * rs[q2] * gg[c2] + bb[c2];
    float v1 = (xl[q2][c2 + 1] - mu[q2]) * rs[q2] * gg[c2 + 1] + bb[c2 + 1];
    unsigned int pk = (unsigned int)f2bf(v0) | ((unsigned int)f2bf(v1) << 16);
    *(unsigned int*)&xnb[obase + (size_t)q2 * 128 + c2] = pk;
  }
}

// K2: 3x3 SAME conv via MFMA. Block = (n,h): 64 px x 128 co, K=9*128.
// 256 thr (4 waves); wave w owns co tiles {2w, 2w+1} (32 co).
__global__ __launch_bounds__(256) void k_conv(
    const unsigned short* __restrict__ xnb, const unsigned short* __restrict__ wcv,
    const float* __restrict__ cbias, float* __restrict__ Xre, float* __restrict__ Xim) {
  int n = blockIdx.x >> 6, h = blockIdx.x & 63;
  __shared__ __align__(16) short in_t[3 * 66 * 128];  // 50688 B, XOR-swizzled rows
  __shared__ float tr[64][66];                        // 16896 B transpose staging
  int tid = threadIdx.x;
  int l = tid & 63;
  int w = __builtin_amdgcn_readfirstlane(tid >> 6);

  // stage 3 input rows (h-1..h+1), 66 w-positions (halo), 128 ci, bf16
  for (int it = 0; it < 13; ++it) {
    int ch = tid + it * 256;  // 3168 chunks of 16B
    if (ch < 3168) {
      int ri = ch >> 4, cb16 = ch & 15;
      int rr = ri >= 132 ? 2 : (ri >= 66 ? 1 : 0);
      int wp = ri - rr * 66 - 1;
      int hh = h + rr - 1;
      uint4 v = make_uint4(0, 0, 0, 0);
      if ((unsigned)hh < 64u && (unsigned)wp < 64u)
        v = *(const uint4*)(xnb + ((size_t)(n * 4096 + hh * 64 + wp) << 7) + cb16 * 8);
      int off = (ri * 256 + cb16 * 16) ^ ((ri & 7) << 4);
      *(uint4*)((char*)in_t + off) = v;
    }
  }
  __syncthreads();

  f32x4 acc[4][2];
#pragma unroll
  for (int pt = 0; pt < 4; ++pt) { acc[pt][0] = {0,0,0,0}; acc[pt][1] = {0,0,0,0}; }

#pragma unroll
  for (int kh = 0; kh < 3; ++kh) {
#pragma unroll
    for (int kw = 0; kw < 3; ++kw) {
      int k = kh * 3 + kw;
#pragma unroll
      for (int cb = 0; cb < 4; ++cb) {
        const unsigned short* wb = wcv + ((((size_t)(k * 4 + cb) * 8) + 2 * w) * 64 + l) * 8;
        bf16x8 b0 = *(const bf16x8*)wb;
        bf16x8 b1 = *(const bf16x8*)(wb + 64 * 8);
#pragma unroll
        for (int pt = 0; pt < 4; ++pt) {
          int ri = kh * 66 + pt * 16 + (l & 15) + kw;
          int off = (ri * 256 + cb * 64 + (l >> 4) * 16) ^ ((ri & 7) << 4);
          bf16x8 a = *(const bf16x8*)((const char*)in_t + off);
          acc[pt][0] = __builtin_amdgcn_mfma_f32_16x16x32_bf16(a, b0, acc[pt][0], 0, 0, 0);
          acc[pt][1] = __builtin_amdgcn_mfma_f32_16x16x32_bf16(a, b1, acc[pt][1], 0, 0, 0);
        }
      }
    }
  }

  // epilogue: 2 passes through tr (re: co 0..63 from waves 0,1; im: 64..127 from 2,3)
  for (int pass = 0; pass < 2; ++pass) {
    __syncthreads();
    if ((w >> 1) == pass) {
      int ctl = w & 1;
#pragma unroll
      for (int ct = 0; ct < 2; ++ct) {
        int col = ctl * 32 + ct * 16 + (l & 15);
        float bias = cbias[pass * 64 + col];
#pragma unroll
        for (int pt = 0; pt < 4; ++pt)
#pragma unroll
          for (int r = 0; r < 4; ++r)
            tr[col][pt * 16 + (l >> 4) * 4 + r] = acc[pt][ct][r] + bias;
      }
    }
    __syncthreads();
    float* Xo = pass ? Xim : Xre;
    for (int it = 0; it < 16; ++it) {
      int ch = tid + it * 256;  // 4096
      int co = ch >> 6, px = ch & 63;
      Xo[((size_t)n * 64 + co) * 4096 + h * 64 + px] = tr[co][px];
    }
  }
}

// K3: Xm[n][d] = mean_p (X + xf).
__global__ __launch_bounds__(256) void k_xmean(
    const float* __restrict__ Xre, const float* __restrict__ Xim,
    const float* __restrict__ xre, const float* __restrict__ xim,
    float2* __restrict__ Xm) {
  int nd = blockIdx.x;
  size_t base = (size_t)nd * 4096;
  int tid = threadIdx.x;
  float sr = 0.f, si = 0.f;
  for (int p = tid; p < 4096; p += 256) {
    sr += Xre[base + p] + xre[base + p];
    si += Xim[base + p] + xim[base + p];
  }
  __shared__ float r1[256], r2[256];
  r1[tid] = sr; r2[tid] = si;
  __syncthreads();
  for (int s = 128; s > 0; s >>= 1) {
    if (tid < s) { r1[tid] += r1[tid + s]; r2[tid] += r2[tid + s]; }
    __syncthreads();
  }
  if (tid == 0) Xm[nd] = make_float2(r1[0] * (1.f / 4096.f), r2[0] * (1.f / 4096.f));
}

// K4: per (b,t): xmean = Xm @ Ec; fcat = [re,im] @ mix_w + mix_b
__global__ void k_chainA(const float2* __restrict__ Xm, const float* __restrict__ Ere,
                         const float* __restrict__ Eim, const float* __restrict__ mixw,
                         const float* __restrict__ mixb, float2* __restrict__ xmix) {
  int n = blockIdx.x;
  int tid = threadIdx.x;  // 128
  __shared__ float2 xm[64];
  __shared__ float cat[128];
  __shared__ float fc[128];
  if (tid < 64) xm[tid] = Xm[n * 64 + tid];
  __syncthreads();
  if (tid < 64) {
    float ar = 0.f, ai = 0.f;
    for (int d = 0; d < 64; ++d) {
      float2 x = xm[d];
      float er = Ere[d * 64 + tid], ei = Eim[d * 64 + tid];
      ar += x.x * er - x.y * ei;
      ai += x.x * ei + x.y * er;
    }
    cat[tid] = ar; cat[64 + tid] = ai;
  }
  __syncthreads();
  {
    float f = mixb[tid];
    for (int i = 0; i < 128; ++i) f += cat[i] * mixw[i * 128 + tid];
    fc[tid] = f;
  }
  __syncthreads();
  if (tid < 64) xmix[n * 64 + tid] = make_float2(fc[tid], fc[64 + tid]);
}

// K5: flux scan over t
__global__ void k_chainB(const float2* __restrict__ xmix, const float* __restrict__ nu,
                         const float* __restrict__ th, const float* __restrict__ fre,
                         const float* __restrict__ fim, float2* __restrict__ fs) {
  int tid = threadIdx.x;  // 128
  int b = tid >> 6, d = tid & 63;
  float r = expf(-sp_f(nu[d]));
  float dr = r * cosf(th[d]), di = r * sinf(th[d]);
  float yr = 0.f, yi = 0.f, cr = 1.f, ci = 0.f;
  float fr = fre[b * 64 + d], fi = fim[b * 64 + d];
  for (int t = 0; t < 16; ++t) {
    int n = b * 16 + t;
    float ncr = cr * dr - ci * di, nci = cr * di + ci * dr;
    cr = ncr; ci = nci;
    float2 xm = xmix[n * 64 + d];
    float nyr = dr * yr - di * yi + xm.x;
    float nyi = dr * yi + di * yr + xm.y;
    yr = nyr; yi = nyi;
    fs[n * 64 + d] = make_float2(yr + fr * cr - fi * ci, yi + fr * ci + fi * cr);
  }
}

// K6: per (b,t): source, gate, op_decay, op_forcing
__global__ void k_chainC(const float2* __restrict__ fs, const float* __restrict__ srcw,
                         const float* __restrict__ srcb, const float* __restrict__ gw,
                         const float* __restrict__ gbv, const float* __restrict__ la,
                         const float* __restrict__ lbv, const float* __restrict__ dt,
                         float* __restrict__ g, float2* __restrict__ src,
                         float2* __restrict__ opd, float2* __restrict__ opf) {
  int n = blockIdx.x;
  int t = n & 15;
  int tid = threadIdx.x;  // 128
  __shared__ float oc[128];
  __shared__ float sl[128];
  if (tid < 64) { float2 v = fs[n * 64 + tid]; oc[tid] = v.x; oc[64 + tid] = v.y; }
  __syncthreads();
  {
    float s = srcb[tid];
    for (int i = 0; i < 128; ++i) s += oc[i] * srcw[i * 128 + tid];
    sl[tid] = s;
  }
  if (tid < 64) {
    float gv = gbv[tid];
    for (int i = 0; i < 128; ++i) gv += oc[i] * gw[i * 64 + tid];
    g[n * 64 + tid] = 1.f / (1.f + expf(-gv));
    float lr = -sp_f(la[tid]), li = lbv[tid];
    float dtv = dt[t];
    float er = expf(lr * dtv);
    float2 od = make_float2(er * cosf(li * dtv), er * sinf(li * dtv));
    opd[n * 64 + tid] = od;
    float inv = 1.f / (lr * lr + li * li);
    float nx = od.x - 1.f, ny = od.y;
    opf[n * 64 + tid] = make_float2((nx * lr + ny * li) * inv, (ny * lr - nx * li) * inv);
  }
  __syncthreads();
  if (tid < 64) src[n * 64 + tid] = make_float2(sl[tid], sl[64 + tid]);
}

// K7: u_t
__global__ __launch_bounds__(256) void k_ut(
    const float* __restrict__ Xre, const float* __restrict__ Xim,
    const float* __restrict__ xre, const float* __restrict__ xim,
    const float* __restrict__ Ere, const float* __restrict__ Eim,
    const float* __restrict__ g, const float2* __restrict__ src,
    const float2* __restrict__ opd, const float2* __restrict__ opf,
    const float* __restrict__ hre, const float* __restrict__ him,
    float* __restrict__ Ure, float* __restrict__ Uim) {
  int n = blockIdx.x >> 6, pt = blockIdx.x & 63;
  int p0 = pt * 64;
  int b = n >> 4, t = n & 15;
  __shared__ float2 Ec[64][64];
  __shared__ float gl[64];
  __shared__ float2 sl[64], ofl[64], odl[64];
  int tid = threadIdx.x;
  for (int idx = tid; idx < 4096; idx += 256)
    Ec[idx >> 6][idx & 63] = make_float2(Ere[idx], Eim[idx]);
  if (tid < 64) {
    gl[tid] = g[n * 64 + tid]; sl[tid] = src[n * 64 + tid];
    ofl[tid] = opf[n * 64 + tid]; odl[tid] = opd[n * 64 + tid];
  }
  __syncthreads();
  int px = tid & 63, grp = tid >> 6;
  float ar[16], ai[16];
#pragma unroll
  for (int j = 0; j < 16; ++j) { ar[j] = 0.f; ai[j] = 0.f; }
  size_t rowbase = (size_t)n * 64 * 4096 + p0 + px;
  for (int d = 0; d < 64; ++d) {
    size_t off = rowbase + (size_t)d * 4096;
    float xr = Xre[off] + xre[off];
    float xi = Xim[off] + xim[off];
#pragma unroll
    for (int j = 0; j < 16; ++j) {
      float2 e = Ec[d][grp * 16 + j];
      ar[j] += xr * e.x - xi * e.y;
      ai[j] += xr * e.y + xi * e.x;
    }
  }
#pragma unroll
  for (int j = 0; j < 16; ++j) {
    int ee = grp * 16 + j;
    float gv = gl[ee];
    float2 s = sl[ee];
    float fr = ar[j] * gv + s.x * (1.f - gv);
    float fi = ai[j] * gv + s.y * (1.f - gv);
    float2 of = ofl[ee];
    float ur = fr * of.x - fi * of.y;
    float ui = fr * of.y + fi * of.x;
    if (t == 0) {
      size_t hoff = ((size_t)b * 4096 + p0 + px) * 64 + ee;
      float hr = hre[hoff], hi = him[hoff];
      float2 od = odl[ee];
      ur += hr * od.x - hi * od.y;
      ui += hr * od.y + hi * od.x;
    }
    size_t off = ((size_t)n * 64 + ee) * 4096 + p0 + px;
    Ure[off] = ur; Uim[off] = ui;
  }
}

// K8: associative scan over t (in place on U)
__global__ __launch_bounds__(256) void k_scan(float* __restrict__ Ure, float* __restrict__ Uim,
                                              const float2* __restrict__ opd) {
  int gid = blockIdx.x * 256 + threadIdx.x;  // 524288
  int p = gid & 4095, d = (gid >> 12) & 63, b = gid >> 18;
  float yr = 0.f, yi = 0.f;
  for (int t = 0; t < 16; ++t) {
    int n = b * 16 + t;
    float2 od = opd[n * 64 + d];
    size_t off = ((size_t)n * 64 + d) * 4096 + p;
    float ur = Ure[off], ui = Uim[off];
    float nyr = od.x * yr - od.y * yi + ur;
    float nyi = od.x * yi + od.y * yr + ui;
    yr = nyr; yi = nyi;
    Ure[off] = yr; Uim[off] = yi;
  }
}

// K9: x_dec = u_out @ Fc, layernorm -> on (bf16) [n][p][c]
__global__ __launch_bounds__(256) void k_xdec(
    const float* __restrict__ Ure, const float* __restrict__ Uim,
    const float* __restrict__ Fre, const float* __restrict__ Fim,
    const float* __restrict__ ntg, const float* __restrict__ ntb,
    unsigned short* __restrict__ onb) {
  int n = blockIdx.x >> 6, pt = blockIdx.x & 63;
  int p0 = pt * 64;
  __shared__ float2 Fc[64][64];
  __shared__ float onl[64][129];
  __shared__ float ps[4][64], ps2[4][64];
  __shared__ float mu[64], rs[64];
  int tid = threadIdx.x;
  for (int idx = tid; idx < 4096; idx += 256)
    Fc[idx >> 6][idx & 63] = make_float2(Fre[idx], Fim[idx]);
  __syncthreads();
  int px = tid & 63, grp = tid >> 6;
  float ar[16], ai[16];
#pragma unroll
  for (int j = 0; j < 16; ++j) { ar[j] = 0.f; ai[j] = 0.f; }
  size_t rowbase = (size_t)n * 64 * 4096 + p0 + px;
  for (int d = 0; d < 64; ++d) {
    size_t off = rowbase + (size_t)d * 4096;
    float xr = Ure[off], xi = Uim[off];
#pragma unroll
    for (int j = 0; j < 16; ++j) {
      float2 e = Fc[d][grp * 16 + j];
      ar[j] += xr * e.x - xi * e.y;
      ai[j] += xr * e.y + xi * e.x;
    }
  }
#pragma unroll
  for (int j = 0; j < 16; ++j) {
    int ee = grp * 16 + j;
    onl[px][ee] = ar[j];
    onl[px][64 + ee] = ai[j];
  }
  __syncthreads();
  float s = 0.f, s2 = 0.f;
  for (int c = grp * 32; c < grp * 32 + 32; ++c) { float v = onl[px][c]; s += v; s2 += v * v; }
  ps[grp][px] = s; ps2[grp][px] = s2;
  __syncthreads();
  if (tid < 64) {
    float a = 0.f, b2 = 0.f;
#pragma unroll
    for (int i = 0; i < 4; ++i) { a += ps[i][tid]; b2 += ps2[i][tid]; }
    float m = a * (1.f / 128.f);
    mu[tid] = m;
    rs[tid] = rsqrtf(b2 * (1.f / 128.f) - m * m + 1e-5f);
  }
  __syncthreads();
  size_t obase = ((size_t)n * 4096 + p0) * 128;
  for (int idx = tid; idx < 64 * 64; idx += 256) {
    int q = idx >> 6, c2 = (idx & 63) * 2;
    float v0 = (onl[q][c2] - mu[q]) * rs[q] * ntg[c2] + ntb[c2];
    float v1 = (onl[q][c2 + 1] - mu[q]) * rs[q] * ntg[c2 + 1] + ntb[c2 + 1];
    unsigned int pk = (unsigned int)f2bf(v0) | ((unsigned int)f2bf(v1) << 16);
    *(unsigned int*)&onb[obase + (size_t)q * 128 + c2] = pk;
  }
}

// K10: MFMA MoE + final residual. 64-px tile, 256 thr (4 waves).
__global__ __launch_bounds__(256) void k_moe2(
    const unsigned short* __restrict__ onb, const unsigned short* __restrict__ w1p,
    const unsigned short* __restrict__ w2p, const float* __restrict__ rw,
    const float* __restrict__ rb, const float* __restrict__ b1, const float* __restrict__ b2,
    const float* __restrict__ Xre, const float* __restrict__ Xim,
    const float* __restrict__ xre, const float* __restrict__ xim,
    float* __restrict__ out) {
  int n = blockIdx.x >> 6, ptile = blockIdx.x & 63;
  int p0 = ptile * 64;
  __shared__ __align__(16) short At[64 * 128];        // 16KB, swizzled
  __shared__ __align__(16) char hidbuf[64 * 129 * 4]; // hid bf16 / fin f32
  __shared__ float pr[64][4];
  short* hid = (short*)hidbuf;
  float* fin = (float*)hidbuf;
  int tid = threadIdx.x;
  int l = tid & 63;
  int w = __builtin_amdgcn_readfirstlane(tid >> 6);

  {
    const char* gsrc = (const char*)onb + ((size_t)n * 4096 + p0) * 256;
#pragma unroll
    for (int it = 0; it < 4; ++it) {
      int ch = tid + it * 256;
      int row = ch >> 4, cb = (ch & 15) * 16;
      float4 v = *(const float4*)(gsrc + (size_t)row * 256 + cb);
      int off = (row * 256 + cb) ^ ((row & 7) << 4);
      *(float4*)((char*)At + off) = v;
    }
  }
  __syncthreads();

  {
    int px = tid >> 2, e = tid & 3;
    float acc = rb[e];
    for (int c = 0; c < 128; ++c) {
      int off = (px * 256 + c * 2) ^ ((px & 7) << 4);
      acc += bf2f(((unsigned short*)At)[off >> 1]) * rw[c * 4 + e];
    }
    pr[px][e] = acc;
  }
  __syncthreads();
  if (tid < 64) {
    float a0 = pr[tid][0], a1 = pr[tid][1], a2 = pr[tid][2], a3 = pr[tid][3];
    float m = fmaxf(fmaxf(a0, a1), fmaxf(a2, a3));
    float e0 = __expf(a0 - m), e1 = __expf(a1 - m), e2 = __expf(a2 - m), e3 = __expf(a3 - m);
    float inv = 1.f / (e0 + e1 + e2 + e3);
    pr[tid][0] = e0 * inv; pr[tid][1] = e1 * inv; pr[tid][2] = e2 * inv; pr[tid][3] = e3 * inv;
  }
  __syncthreads();

  float macc[8][4];
#pragma unroll
  for (int ct = 0; ct < 8; ++ct)
#pragma unroll
    for (int r = 0; r < 4; ++r) macc[ct][r] = 0.f;

  for (int e = 0; e < 4; ++e) {
#pragma unroll
    for (int nt = 0; nt < 4; ++nt) {
      int ntG = w * 4 + nt;
      bf16x8 bb[4];
#pragma unroll
      for (int kt = 0; kt < 4; ++kt)
        bb[kt] = *(const bf16x8*)(w1p + ((((size_t)(e * 4 + kt) * 16 + ntG) * 64 + l) * 8));
      float b1v = b1[e * 256 + ntG * 16 + (l & 15)];
#pragma unroll
      for (int pt = 0; pt < 4; ++pt) {
        f32x4 acc = {0.f, 0.f, 0.f, 0.f};
#pragma unroll
        for (int kt = 0; kt < 4; ++kt) {
          int row = pt * 16 + (l & 15);
          int off = (row * 256 + kt * 64 + (l >> 4) * 16) ^ ((row & 7) << 4);
          bf16x8 aa = *(const bf16x8*)((const char*)At + off);
          acc = __builtin_amdgcn_mfma_f32_16x16x32_bf16(aa, bb[kt], acc, 0, 0, 0);
        }
        int mcol = ntG * 16 + (l & 15);
#pragma unroll
        for (int r = 0; r < 4; ++r) {
          int row = pt * 16 + (l >> 4) * 4 + r;
          float v = gelu_f(acc[r] + b1v);
          int off = (row * 512 + mcol * 2) ^ ((row & 7) << 4);
          hid[off >> 1] = (short)f2bf(v);
        }
      }
    }
    __syncthreads();
    {
      bf16x8 a2f[8];
#pragma unroll
      for (int kt = 0; kt < 8; ++kt) {
        int row = w * 16 + (l & 15);
        int off = (row * 512 + kt * 64 + (l >> 4) * 16) ^ ((row & 7) << 4);
        a2f[kt] = *(const bf16x8*)((const char*)hid + off);
      }
      float pw[4];
#pragma unroll
      for (int r = 0; r < 4; ++r) pw[r] = pr[w * 16 + (l >> 4) * 4 + r][e];
#pragma unroll
      for (int ct = 0; ct < 8; ++ct) {
        f32x4 acc = {0.f, 0.f, 0.f, 0.f};
#pragma unroll
        for (int kt = 0; kt < 8; ++kt) {
          bf16x8 b2f = *(const bf16x8*)(w2p + ((((size_t)(e * 8 + kt) * 8 + ct) * 64 + l) * 8));
          acc = __builtin_amdgcn_mfma_f32_16x16x32_bf16(a2f[kt], b2f, acc, 0, 0, 0);
        }
        float b2v = b2[e * 128 + ct * 16 + (l & 15)];
#pragma unroll
        for (int r = 0; r < 4; ++r) macc[ct][r] += (acc[r] + b2v) * pw[r];
      }
    }
    __syncthreads();
  }

#pragma unroll
  for (int ct = 0; ct < 8; ++ct) {
#pragma unroll
    for (int r = 0; r < 4; ++r) {
      int row = w * 16 + (l >> 4) * 4 + r;
      int c = ct * 16 + (l & 15);
      int aoff = (row * 256 + c * 2) ^ ((row & 7) << 4);
      float onv = bf2f(((unsigned short*)At)[aoff >> 1]);
      fin[row * 129 + c] = macc[ct][r] + onv;
    }
  }
  __syncthreads();
  for (int idx = tid; idx < 64 * 128; idx += 256) {
    int px = idx & 63, ch = idx >> 6;
    size_t off = ((size_t)n * 64 + (ch & 63)) * 4096 + p0 + px;
    float resid = (ch < 64) ? (Xre[off] + xre[off]) : (Xim[off] + xim[off]);
    out[((size_t)n * 128 + ch) * 4096 + p0 + px] = resid + fin[px * 129 + ch];
  }
}

extern "C" void kernel_launch(void* const* d_in, const int* in_sizes, int n_in,
                              void* d_out, int out_size, void* d_ws, size_t ws_size,
                              hipStream_t stream) {
  const float* xre = (const float*)d_in[0];
  const float* xim = (const float*)d_in[1];
  const float* hre = (const float*)d_in[2];
  const float* him = (const float*)d_in[3];
  const float* dt = (const float*)d_in[4];
  const float* fre = (const float*)d_in[5];
  const float* fim = (const float*)d_in[6];
  const float* nsg = (const float*)d_in[7];
  const float* nsb = (const float*)d_in[8];
  const float* cw = (const float*)d_in[9];
  const float* cb = (const float*)d_in[10];
  const float* Ere = (const float*)d_in[11];
  const float* Eim = (const float*)d_in[12];
  const float* Fre = (const float*)d_in[13];
  const float* Fim = (const float*)d_in[14];
  const float* mixw = (const float*)d_in[15];
  const float* mixb = (const float*)d_in[16];
  const float* nu = (const float*)d_in[17];
  const float* th = (const float*)d_in[18];
  const float* srcw = (const float*)d_in[19];
  const float* srcb = (const float*)d_in[20];
  const float* gw = (const float*)d_in[21];
  const float* gbv = (const float*)d_in[22];
  const float* la = (const float*)d_in[23];
  const float* lb = (const float*)d_in[24];
  const float* ntg = (const float*)d_in[25];
  const float* ntb = (const float*)d_in[26];
  const float* rw = (const float*)d_in[27];
  const float* rb = (const float*)d_in[28];
  const float* w1 = (const float*)d_in[29];
  const float* b1 = (const float*)d_in[30];
  const float* w2 = (const float*)d_in[31];
  const float* b2 = (const float*)d_in[32];

  float* ws = (float*)d_ws;
  float* Xre_ = ws;
  float* Xim_ = ws + PLANE;
  unsigned short* onb16 = (unsigned short*)(ws + 2 * PLANE);  // BIGSZ bf16
  unsigned short* wcv = (unsigned short*)(ws + 2 * PLANE + BIGSZ / 2);  // 147456 bf16
  unsigned short* w1p = wcv + 147456;                          // 131072 bf16
  unsigned short* w2p = w1p + 131072;                          // 131072 bf16
  float* sm = (float*)(w2p + 131072);
  float2* Xm = (float2*)sm;
  float2* xmix = Xm + TN * 64;
  float2* fsb = xmix + TN * 64;
  float* gbuf = (float*)(fsb + TN * 64);
  float2* srcv = (float2*)(gbuf + TN * 64);
  float2* opdv = srcv + TN * 64;
  float2* opfv = opdv + TN * 64;

  float* out = (float*)d_out;
  unsigned short* xnb = (unsigned short*)d_out;  // bf16 xn; dead before U written
  float* U_re = (float*)d_out;
  float* U_im = U_re + PLANE;

  hipLaunchKernelGGL(k_repc, dim3(576), dim3(256), 0, stream, cw, wcv);
  hipLaunchKernelGGL(k_repw, dim3(1024), dim3(256), 0, stream, w1, w2, w1p, w2p);
  hipLaunchKernelGGL(k_ln_in, dim3(TN * 64), dim3(256), 0, stream, xre, xim, nsg, nsb, xnb);
  hipLaunchKernelGGL(k_conv, dim3(TN * 64), dim3(256), 0, stream, xnb, wcv, cb, Xre_, Xim_);
  hipLaunchKernelGGL(k_xmean, dim3(TN * 64), dim3(256), 0, stream, Xre_, Xim_, xre, xim, Xm);
  hipLaunchKernelGGL(k_chainA, dim3(TN), dim3(128), 0, stream, Xm, Ere, Eim, mixw, mixb, xmix);
  hipLaunchKernelGGL(k_chainB, dim3(1), dim3(128), 0, stream, xmix, nu, th, fre, fim, fsb);
  hipLaunchKernelGGL(k_chainC, dim3(TN), dim3(128), 0, stream, fsb, srcw, srcb, gw, gbv, la, lb,
                     dt, gbuf, srcv, opdv, opfv);
  hipLaunchKernelGGL(k_ut, dim3(TN * 64), dim3(256), 0, stream, Xre_, Xim_, xre, xim, Ere, Eim,
                     gbuf, srcv, opdv, opfv, hre, him, U_re, U_im);
  hipLaunchKernelGGL(k_scan, dim3(2048), dim3(256), 0, stream, U_re, U_im, opdv);
  hipLaunchKernelGGL(k_xdec, dim3(TN * 64), dim3(256), 0, stream, U_re, U_im, Fre, Fim, ntg, ntb,
                     onb16);
  hipLaunchKernelGGL(k_moe2, dim3(TN * 64), dim3(256), 0, stream, onb16, w1p, w2p, rw, rb, b1, b2,
                     Xre_, Xim_, xre, xim, out);
  (void)in_sizes; (void)n_in; (void)out_size; (void)ws_size;
}

// Round 4
// 772.012 us; speedup vs baseline: 12.7426x; 1.0638x over previous
//
#include <hip/hip_runtime.h>

// UniPhyBlock pipeline, round 3: k_moe2 VALU diet (rcp-gelu, cvt_pk bf16,
// MFMA router). B=2 T=16 D=64 H=W=64, C=128, E=4 experts, M=256.

#define DEV static __device__ __forceinline__

typedef __attribute__((ext_vector_type(8))) short bf16x8;
typedef __attribute__((ext_vector_type(4))) float f32x4;

namespace {
constexpr int TN = 32;          // B*T
constexpr size_t PLANE = (size_t)TN * 64 * 4096;   // 8,388,608
constexpr size_t BIGSZ = (size_t)TN * 4096 * 128;  // 16,777,216

DEV float sp_f(float x) { return x > 20.f ? x : log1pf(expf(x)); }
DEV unsigned short f2bf(float f) {
  unsigned int u = __float_as_uint(f);
  unsigned int r = (u + 0x7FFFu + ((u >> 16) & 1u)) >> 16;
  return (unsigned short)r;
}
DEV float bf2f(unsigned short s) { return __uint_as_float(((unsigned int)s) << 16); }
DEV unsigned int cvtpk(float lo, float hi) {
  unsigned int u;
  asm("v_cvt_pk_bf16_f32 %0, %1, %2" : "=v"(u) : "v"(lo), "v"(hi));
  return u;
}
// tanh-gelu == x * sigmoid(2*0.79788456*(x + 0.044715 x^3)); rcp-based sigmoid
DEV float gelu_f(float x) {
  float x2 = x * x;
  float z2 = 1.5957691216057308f * x * (1.f + 0.044715f * x2);
  float r = __builtin_amdgcn_rcpf(1.f + __expf(-z2));
  return x * r;
}
} // namespace

// K0c: repack conv_w (Co,Ci,3,3) fp32 -> bf16 MFMA B-fragments
__global__ void k_repc(const float* __restrict__ cw, unsigned short* __restrict__ wcv) {
  int i = blockIdx.x * 256 + threadIdx.x;  // 147456
  if (i >= 9 * 4 * 8 * 64 * 8) return;
  int j = i & 7, l = (i >> 3) & 63, ct = (i >> 9) & 7, cb = (i >> 12) & 3, k = i >> 14;
  int co = ct * 16 + (l & 15);
  int ci = cb * 32 + (l >> 4) * 8 + j;
  wcv[i] = f2bf(cw[((size_t)co * 128 + ci) * 9 + k]);
}

// K0b: repack w1/w2 (+ router rw) to bf16 MFMA B-fragment order.
__global__ void k_repw(const float* __restrict__ w1, const float* __restrict__ w2,
                       const float* __restrict__ rw,
                       unsigned short* __restrict__ w1p, unsigned short* __restrict__ w2p,
                       unsigned short* __restrict__ rwp) {
  int i = blockIdx.x * 256 + threadIdx.x;  // 264192 total
  if (i >= 262144 + 2048) return;
  if (i >= 262144) {  // rwp[kt<4][l<64][j<8], zero-padded cols 4..15
    int idx = i - 262144;
    int j = idx & 7, l = (idx >> 3) & 63, kt = idx >> 9;
    int col = l & 15;
    rwp[idx] = col < 4 ? f2bf(rw[(kt * 32 + (l >> 4) * 8 + j) * 4 + col]) : (unsigned short)0;
    return;
  }
  int half = i >> 17;
  int idx = i & 131071;
  int j = idx & 7, l = (idx >> 3) & 63;
  if (half == 0) {
    int nt = (idx >> 9) & 15, kt = (idx >> 13) & 3, e = idx >> 15;
    int c = kt * 32 + (l >> 4) * 8 + j, m = nt * 16 + (l & 15);
    w1p[idx] = f2bf(w1[((size_t)e * 128 + c) * 256 + m]);
  } else {
    int ct = (idx >> 9) & 7, kt = (idx >> 12) & 7, e = idx >> 15;
    int m = kt * 32 + (l >> 4) * 8 + j, c = ct * 16 + (l & 15);
    w2p[idx] = f2bf(w2[((size_t)e * 256 + m) * 128 + c]);
  }
}

// K1: layernorm over channels -> xn bf16 [n][p][c]
__global__ __launch_bounds__(256) void k_ln_in(
    const float* __restrict__ xre, const float* __restrict__ xim,
    const float* __restrict__ gg, const float* __restrict__ bb,
    unsigned short* __restrict__ xnb) {
  int n = blockIdx.x >> 6, h = blockIdx.x & 63;
  __shared__ float xl[64][129];
  __shared__ float ps[4][64], ps2[4][64];
  __shared__ float mu[64], rs[64];
  int tid = threadIdx.x;
  int w = tid & 63, q = tid >> 6;
  size_t base = ((size_t)n * 4096 + h) * 64 + w;
  for (int d = q; d < 64; d += 4) {
    size_t o = base + (size_t)d * 4096;
    xl[w][d] = xre[o];
    xl[w][64 + d] = xim[o];
  }
  __syncthreads();
  float s = 0.f, s2 = 0.f;
  for (int c = q * 32; c < q * 32 + 32; ++c) { float v = xl[w][c]; s += v; s2 += v * v; }
  ps[q][w] = s; ps2[q][w] = s2;
  __syncthreads();
  if (tid < 64) {
    float a = 0.f, b2 = 0.f;
#pragma unroll
    for (int i = 0; i < 4; ++i) { a += ps[i][tid]; b2 += ps2[i][tid]; }
    float m = a * (1.f / 128.f);
    mu[tid] = m;
    rs[tid] = rsqrtf(b2 * (1.f / 128.f) - m * m + 1e-5f);
  }
  __syncthreads();
  size_t obase = ((size_t)n * 4096 + (size_t)h * 64) * 128;
  for (int idx = tid; idx < 64 * 64; idx += 256) {
    int q2 = idx >> 6, c2 = (idx & 63) * 2;
    float v0 = (xl[q2][c2] - mu[q2]) * rs[q2] * gg[c2] + bb[c2];
    float v1 = (xl[q2][c2 + 1] - mu[q2]) * rs[q2] * gg[c2 + 1] + bb[c2 + 1];
    *(unsigned int*)&xnb[obase + (size_t)q2 * 128 + c2] = cvtpk(v0, v1);
  }
}

// K2: 3x3 SAME conv via MFMA. Block = (n,h): 64 px x 128 co, K=9*128.
__global__ __launch_bounds__(256) void k_conv(
    const unsigned short* __restrict__ xnb, const unsigned short* __restrict__ wcv,
    const float* __restrict__ cbias, float* __restrict__ Xre, float* __restrict__ Xim) {
  int n = blockIdx.x >> 6, h = blockIdx.x & 63;
  __shared__ __align__(16) short in_t[3 * 66 * 128];  // 50688 B, XOR-swizzled rows
  __shared__ float tr[64][66];
  int tid = threadIdx.x;
  int l = tid & 63;
  int w = __builtin_amdgcn_readfirstlane(tid >> 6);

  for (int it = 0; it < 13; ++it) {
    int ch = tid + it * 256;  // 3168 chunks of 16B
    if (ch < 3168) {
      int ri = ch >> 4, cb16 = ch & 15;
      int rr = ri >= 132 ? 2 : (ri >= 66 ? 1 : 0);
      int wp = ri - rr * 66 - 1;
      int hh = h + rr - 1;
      uint4 v = make_uint4(0, 0, 0, 0);
      if ((unsigned)hh < 64u && (unsigned)wp < 64u)
        v = *(const uint4*)(xnb + ((size_t)(n * 4096 + hh * 64 + wp) << 7) + cb16 * 8);
      int off = (ri * 256 + cb16 * 16) ^ ((ri & 7) << 4);
      *(uint4*)((char*)in_t + off) = v;
    }
  }
  __syncthreads();

  f32x4 acc[4][2];
#pragma unroll
  for (int pt = 0; pt < 4; ++pt) { acc[pt][0] = {0,0,0,0}; acc[pt][1] = {0,0,0,0}; }

#pragma unroll
  for (int kh = 0; kh < 3; ++kh) {
#pragma unroll
    for (int kw = 0; kw < 3; ++kw) {
      int k = kh * 3 + kw;
#pragma unroll
      for (int cb = 0; cb < 4; ++cb) {
        const unsigned short* wb = wcv + ((((size_t)(k * 4 + cb) * 8) + 2 * w) * 64 + l) * 8;
        bf16x8 b0 = *(const bf16x8*)wb;
        bf16x8 b1 = *(const bf16x8*)(wb + 64 * 8);
#pragma unroll
        for (int pt = 0; pt < 4; ++pt) {
          int ri = kh * 66 + pt * 16 + (l & 15) + kw;
          int off = (ri * 256 + cb * 64 + (l >> 4) * 16) ^ ((ri & 7) << 4);
          bf16x8 a = *(const bf16x8*)((const char*)in_t + off);
          acc[pt][0] = __builtin_amdgcn_mfma_f32_16x16x32_bf16(a, b0, acc[pt][0], 0, 0, 0);
          acc[pt][1] = __builtin_amdgcn_mfma_f32_16x16x32_bf16(a, b1, acc[pt][1], 0, 0, 0);
        }
      }
    }
  }

  for (int pass = 0; pass < 2; ++pass) {
    __syncthreads();
    if ((w >> 1) == pass) {
      int ctl = w & 1;
#pragma unroll
      for (int ct = 0; ct < 2; ++ct) {
        int col = ctl * 32 + ct * 16 + (l & 15);
        float bias = cbias[pass * 64 + col];
#pragma unroll
        for (int pt = 0; pt < 4; ++pt)
#pragma unroll
          for (int r = 0; r < 4; ++r)
            tr[col][pt * 16 + (l >> 4) * 4 + r] = acc[pt][ct][r] + bias;
      }
    }
    __syncthreads();
    float* Xo = pass ? Xim : Xre;
    for (int it = 0; it < 16; ++it) {
      int ch = tid + it * 256;  // 4096
      int co = ch >> 6, px = ch & 63;
      Xo[((size_t)n * 64 + co) * 4096 + h * 64 + px] = tr[co][px];
    }
  }
}

// K3: Xm[n][d] = mean_p (X + xf).
__global__ __launch_bounds__(256) void k_xmean(
    const float* __restrict__ Xre, const float* __restrict__ Xim,
    const float* __restrict__ xre, const float* __restrict__ xim,
    float2* __restrict__ Xm) {
  int nd = blockIdx.x;
  size_t base = (size_t)nd * 4096;
  int tid = threadIdx.x;
  float sr = 0.f, si = 0.f;
  for (int p = tid; p < 4096; p += 256) {
    sr += Xre[base + p] + xre[base + p];
    si += Xim[base + p] + xim[base + p];
  }
  __shared__ float r1[256], r2[256];
  r1[tid] = sr; r2[tid] = si;
  __syncthreads();
  for (int s = 128; s > 0; s >>= 1) {
    if (tid < s) { r1[tid] += r1[tid + s]; r2[tid] += r2[tid + s]; }
    __syncthreads();
  }
  if (tid == 0) Xm[nd] = make_float2(r1[0] * (1.f / 4096.f), r2[0] * (1.f / 4096.f));
}

// K4: per (b,t): xmean = Xm @ Ec; fcat = [re,im] @ mix_w + mix_b
__global__ void k_chainA(const float2* __restrict__ Xm, const float* __restrict__ Ere,
                         const float* __restrict__ Eim, const float* __restrict__ mixw,
                         const float* __restrict__ mixb, float2* __restrict__ xmix) {
  int n = blockIdx.x;
  int tid = threadIdx.x;  // 128
  __shared__ float2 xm[64];
  __shared__ float cat[128];
  __shared__ float fc[128];
  if (tid < 64) xm[tid] = Xm[n * 64 + tid];
  __syncthreads();
  if (tid < 64) {
    float ar = 0.f, ai = 0.f;
    for (int d = 0; d < 64; ++d) {
      float2 x = xm[d];
      float er = Ere[d * 64 + tid], ei = Eim[d * 64 + tid];
      ar += x.x * er - x.y * ei;
      ai += x.x * ei + x.y * er;
    }
    cat[tid] = ar; cat[64 + tid] = ai;
  }
  __syncthreads();
  {
    float f = mixb[tid];
    for (int i = 0; i < 128; ++i) f += cat[i] * mixw[i * 128 + tid];
    fc[tid] = f;
  }
  __syncthreads();
  if (tid < 64) xmix[n * 64 + tid] = make_float2(fc[tid], fc[64 + tid]);
}

// K5: flux scan over t
__global__ void k_chainB(const float2* __restrict__ xmix, const float* __restrict__ nu,
                         const float* __restrict__ th, const float* __restrict__ fre,
                         const float* __restrict__ fim, float2* __restrict__ fs) {
  int tid = threadIdx.x;  // 128
  int b = tid >> 6, d = tid & 63;
  float r = expf(-sp_f(nu[d]));
  float dr = r * cosf(th[d]), di = r * sinf(th[d]);
  float yr = 0.f, yi = 0.f, cr = 1.f, ci = 0.f;
  float fr = fre[b * 64 + d], fi = fim[b * 64 + d];
  for (int t = 0; t < 16; ++t) {
    int n = b * 16 + t;
    float ncr = cr * dr - ci * di, nci = cr * di + ci * dr;
    cr = ncr; ci = nci;
    float2 xm = xmix[n * 64 + d];
    float nyr = dr * yr - di * yi + xm.x;
    float nyi = dr * yi + di * yr + xm.y;
    yr = nyr; yi = nyi;
    fs[n * 64 + d] = make_float2(yr + fr * cr - fi * ci, yi + fr * ci + fi * cr);
  }
}

// K6: per (b,t): source, gate, op_decay, op_forcing
__global__ void k_chainC(const float2* __restrict__ fs, const float* __restrict__ srcw,
                         const float* __restrict__ srcb, const float* __restrict__ gw,
                         const float* __restrict__ gbv, const float* __restrict__ la,
                         const float* __restrict__ lbv, const float* __restrict__ dt,
                         float* __restrict__ g, float2* __restrict__ src,
                         float2* __restrict__ opd, float2* __restrict__ opf) {
  int n = blockIdx.x;
  int t = n & 15;
  int tid = threadIdx.x;  // 128
  __shared__ float oc[128];
  __shared__ float sl[128];
  if (tid < 64) { float2 v = fs[n * 64 + tid]; oc[tid] = v.x; oc[64 + tid] = v.y; }
  __syncthreads();
  {
    float s = srcb[tid];
    for (int i = 0; i < 128; ++i) s += oc[i] * srcw[i * 128 + tid];
    sl[tid] = s;
  }
  if (tid < 64) {
    float gv = gbv[tid];
    for (int i = 0; i < 128; ++i) gv += oc[i] * gw[i * 64 + tid];
    g[n * 64 + tid] = 1.f / (1.f + expf(-gv));
    float lr = -sp_f(la[tid]), li = lbv[tid];
    float dtv = dt[t];
    float er = expf(lr * dtv);
    float2 od = make_float2(er * cosf(li * dtv), er * sinf(li * dtv));
    opd[n * 64 + tid] = od;
    float inv = 1.f / (lr * lr + li * li);
    float nx = od.x - 1.f, ny = od.y;
    opf[n * 64 + tid] = make_float2((nx * lr + ny * li) * inv, (ny * lr - nx * li) * inv);
  }
  __syncthreads();
  if (tid < 64) src[n * 64 + tid] = make_float2(sl[tid], sl[64 + tid]);
}

// K7: u_t
__global__ __launch_bounds__(256) void k_ut(
    const float* __restrict__ Xre, const float* __restrict__ Xim,
    const float* __restrict__ xre, const float* __restrict__ xim,
    const float* __restrict__ Ere, const float* __restrict__ Eim,
    const float* __restrict__ g, const float2* __restrict__ src,
    const float2* __restrict__ opd, const float2* __restrict__ opf,
    const float* __restrict__ hre, const float* __restrict__ him,
    float* __restrict__ Ure, float* __restrict__ Uim) {
  int n = blockIdx.x >> 6, pt = blockIdx.x & 63;
  int p0 = pt * 64;
  int b = n >> 4, t = n & 15;
  __shared__ float2 Ec[64][64];
  __shared__ float gl[64];
  __shared__ float2 sl[64], ofl[64], odl[64];
  int tid = threadIdx.x;
  for (int idx = tid; idx < 4096; idx += 256)
    Ec[idx >> 6][idx & 63] = make_float2(Ere[idx], Eim[idx]);
  if (tid < 64) {
    gl[tid] = g[n * 64 + tid]; sl[tid] = src[n * 64 + tid];
    ofl[tid] = opf[n * 64 + tid]; odl[tid] = opd[n * 64 + tid];
  }
  __syncthreads();
  int px = tid & 63, grp = tid >> 6;
  float ar[16], ai[16];
#pragma unroll
  for (int j = 0; j < 16; ++j) { ar[j] = 0.f; ai[j] = 0.f; }
  size_t rowbase = (size_t)n * 64 * 4096 + p0 + px;
  for (int d = 0; d < 64; ++d) {
    size_t off = rowbase + (size_t)d * 4096;
    float xr = Xre[off] + xre[off];
    float xi = Xim[off] + xim[off];
#pragma unroll
    for (int j = 0; j < 16; ++j) {
      float2 e = Ec[d][grp * 16 + j];
      ar[j] += xr * e.x - xi * e.y;
      ai[j] += xr * e.y + xi * e.x;
    }
  }
#pragma unroll
  for (int j = 0; j < 16; ++j) {
    int ee = grp * 16 + j;
    float gv = gl[ee];
    float2 s = sl[ee];
    float fr = ar[j] * gv + s.x * (1.f - gv);
    float fi = ai[j] * gv + s.y * (1.f - gv);
    float2 of = ofl[ee];
    float ur = fr * of.x - fi * of.y;
    float ui = fr * of.y + fi * of.x;
    if (t == 0) {
      size_t hoff = ((size_t)b * 4096 + p0 + px) * 64 + ee;
      float hr = hre[hoff], hi = him[hoff];
      float2 od = odl[ee];
      ur += hr * od.x - hi * od.y;
      ui += hr * od.y + hi * od.x;
    }
    size_t off = ((size_t)n * 64 + ee) * 4096 + p0 + px;
    Ure[off] = ur; Uim[off] = ui;
  }
}

// K8: associative scan over t (in place on U)
__global__ __launch_bounds__(256) void k_scan(float* __restrict__ Ure, float* __restrict__ Uim,
                                              const float2* __restrict__ opd) {
  int gid = blockIdx.x * 256 + threadIdx.x;  // 524288
  int p = gid & 4095, d = (gid >> 12) & 63, b = gid >> 18;
  float yr = 0.f, yi = 0.f;
  for (int t = 0; t < 16; ++t) {
    int n = b * 16 + t;
    float2 od = opd[n * 64 + d];
    size_t off = ((size_t)n * 64 + d) * 4096 + p;
    float ur = Ure[off], ui = Uim[off];
    float nyr = od.x * yr - od.y * yi + ur;
    float nyi = od.x * yi + od.y * yr + ui;
    yr = nyr; yi = nyi;
    Ure[off] = yr; Uim[off] = yi;
  }
}

// K9: x_dec = u_out @ Fc, layernorm -> on (bf16) [n][p][c]
__global__ __launch_bounds__(256) void k_xdec(
    const float* __restrict__ Ure, const float* __restrict__ Uim,
    const float* __restrict__ Fre, const float* __restrict__ Fim,
    const float* __restrict__ ntg, const float* __restrict__ ntb,
    unsigned short* __restrict__ onb) {
  int n = blockIdx.x >> 6, pt = blockIdx.x & 63;
  int p0 = pt * 64;
  __shared__ float2 Fc[64][64];
  __shared__ float onl[64][129];
  __shared__ float ps[4][64], ps2[4][64];
  __shared__ float mu[64], rs[64];
  int tid = threadIdx.x;
  for (int idx = tid; idx < 4096; idx += 256)
    Fc[idx >> 6][idx & 63] = make_float2(Fre[idx], Fim[idx]);
  __syncthreads();
  int px = tid & 63, grp = tid >> 6;
  float ar[16], ai[16];
#pragma unroll
  for (int j = 0; j < 16; ++j) { ar[j] = 0.f; ai[j] = 0.f; }
  size_t rowbase = (size_t)n * 64 * 4096 + p0 + px;
  for (int d = 0; d < 64; ++d) {
    size_t off = rowbase + (size_t)d * 4096;
    float xr = Ure[off], xi = Uim[off];
#pragma unroll
    for (int j = 0; j < 16; ++j) {
      float2 e = Fc[d][grp * 16 + j];
      ar[j] += xr * e.x - xi * e.y;
      ai[j] += xr * e.y + xi * e.x;
    }
  }
#pragma unroll
  for (int j = 0; j < 16; ++j) {
    int ee = grp * 16 + j;
    onl[px][ee] = ar[j];
    onl[px][64 + ee] = ai[j];
  }
  __syncthreads();
  float s = 0.f, s2 = 0.f;
  for (int c = grp * 32; c < grp * 32 + 32; ++c) { float v = onl[px][c]; s += v; s2 += v * v; }
  ps[grp][px] = s; ps2[grp][px] = s2;
  __syncthreads();
  if (tid < 64) {
    float a = 0.f, b2 = 0.f;
#pragma unroll
    for (int i = 0; i < 4; ++i) { a += ps[i][tid]; b2 += ps2[i][tid]; }
    float m = a * (1.f / 128.f);
    mu[tid] = m;
    rs[tid] = rsqrtf(b2 * (1.f / 128.f) - m * m + 1e-5f);
  }
  __syncthreads();
  size_t obase = ((size_t)n * 4096 + p0) * 128;
  for (int idx = tid; idx < 64 * 64; idx += 256) {
    int q = idx >> 6, c2 = (idx & 63) * 2;
    float v0 = (onl[q][c2] - mu[q]) * rs[q] * ntg[c2] + ntb[c2];
    float v1 = (onl[q][c2 + 1] - mu[q]) * rs[q] * ntg[c2 + 1] + ntb[c2 + 1];
    *(unsigned int*)&onb[obase + (size_t)q * 128 + c2] = cvtpk(v0, v1);
  }
}

// K10: MFMA MoE + final residual. 64-px tile, 256 thr (4 waves).
__global__ __launch_bounds__(256) void k_moe2(
    const unsigned short* __restrict__ onb, const unsigned short* __restrict__ w1p,
    const unsigned short* __restrict__ w2p, const unsigned short* __restrict__ rwp,
    const float* __restrict__ rb, const float* __restrict__ b1, const float* __restrict__ b2,
    const float* __restrict__ Xre, const float* __restrict__ Xim,
    const float* __restrict__ xre, const float* __restrict__ xim,
    float* __restrict__ out) {
  int n = blockIdx.x >> 6, ptile = blockIdx.x & 63;
  int p0 = ptile * 64;
  __shared__ __align__(16) short At[64 * 128];        // 16KB, swizzled
  __shared__ __align__(16) char hidbuf[64 * 130 * 4]; // hid bf16 / fin f32 (stride 130)
  __shared__ float pr[64][4];
  short* hid = (short*)hidbuf;
  float* fin = (float*)hidbuf;
  int tid = threadIdx.x;
  int l = tid & 63;
  int w = __builtin_amdgcn_readfirstlane(tid >> 6);

  // stage A tile (on, bf16) -> LDS swizzled
  {
    const char* gsrc = (const char*)onb + ((size_t)n * 4096 + p0) * 256;
#pragma unroll
    for (int it = 0; it < 4; ++it) {
      int ch = tid + it * 256;
      int row = ch >> 4, cb = (ch & 15) * 16;
      float4 v = *(const float4*)(gsrc + (size_t)row * 256 + cb);
      int off = (row * 256 + cb) ^ ((row & 7) << 4);
      *(float4*)((char*)At + off) = v;
    }
  }
  __syncthreads();

  // MFMA router: logits[16px x 4e] per wave (px-range w*16..+16), K=128
  {
    f32x4 acc = {0.f, 0.f, 0.f, 0.f};
#pragma unroll
    for (int kt = 0; kt < 4; ++kt) {
      int row = w * 16 + (l & 15);
      int off = (row * 256 + kt * 64 + (l >> 4) * 16) ^ ((row & 7) << 4);
      bf16x8 aa = *(const bf16x8*)((const char*)At + off);
      bf16x8 bb = *(const bf16x8*)(rwp + ((size_t)kt * 64 + l) * 8);
      acc = __builtin_amdgcn_mfma_f32_16x16x32_bf16(aa, bb, acc, 0, 0, 0);
    }
    int e = l & 15;
    float rbv = e < 4 ? rb[e] : 0.f;
    float p[4];
#pragma unroll
    for (int r = 0; r < 4; ++r) {
      float lg = acc[r] + rbv;
      float m = fmaxf(lg, __shfl_xor(lg, 1));
      m = fmaxf(m, __shfl_xor(m, 2));
      float ex = __expf(lg - m);
      float s = ex + __shfl_xor(ex, 1);
      s += __shfl_xor(s, 2);
      p[r] = ex * __builtin_amdgcn_rcpf(s);
    }
    if (e < 4) {
#pragma unroll
      for (int r = 0; r < 4; ++r) pr[w * 16 + (l >> 4) * 4 + r][e] = p[r];
    }
  }
  __syncthreads();

  float macc[8][4];
#pragma unroll
  for (int ct = 0; ct < 8; ++ct)
#pragma unroll
    for (int r = 0; r < 4; ++r) macc[ct][r] = 0.f;

  for (int e = 0; e < 4; ++e) {
    // ---- GEMM1: hid[64px][m-range w*64..+64] = gelu(on @ w1 + b1)
#pragma unroll
    for (int nt = 0; nt < 4; ++nt) {
      int ntG = w * 4 + nt;
      bf16x8 bb[4];
#pragma unroll
      for (int kt = 0; kt < 4; ++kt)
        bb[kt] = *(const bf16x8*)(w1p + ((((size_t)(e * 4 + kt) * 16 + ntG) * 64 + l) * 8));
      float b1v = b1[e * 256 + ntG * 16 + (l & 15)];
#pragma unroll
      for (int pt = 0; pt < 4; ++pt) {
        f32x4 acc = {0.f, 0.f, 0.f, 0.f};
#pragma unroll
        for (int kt = 0; kt < 4; ++kt) {
          int row = pt * 16 + (l & 15);
          int off = (row * 256 + kt * 64 + (l >> 4) * 16) ^ ((row & 7) << 4);
          bf16x8 aa = *(const bf16x8*)((const char*)At + off);
          acc = __builtin_amdgcn_mfma_f32_16x16x32_bf16(aa, bb[kt], acc, 0, 0, 0);
        }
        int mcol = ntG * 16 + (l & 15);
        float g0 = gelu_f(acc[0] + b1v), g1 = gelu_f(acc[1] + b1v);
        float g2 = gelu_f(acc[2] + b1v), g3 = gelu_f(acc[3] + b1v);
        unsigned int pk01 = cvtpk(g0, g1), pk23 = cvtpk(g2, g3);
        int rbase = pt * 16 + (l >> 4) * 4;
        int o0 = ((rbase + 0) * 512 + mcol * 2) ^ (((rbase + 0) & 7) << 4);
        int o1 = ((rbase + 1) * 512 + mcol * 2) ^ (((rbase + 1) & 7) << 4);
        int o2 = ((rbase + 2) * 512 + mcol * 2) ^ (((rbase + 2) & 7) << 4);
        int o3 = ((rbase + 3) * 512 + mcol * 2) ^ (((rbase + 3) & 7) << 4);
        hid[o0 >> 1] = (short)pk01;
        hid[o1 >> 1] = (short)(pk01 >> 16);
        hid[o2 >> 1] = (short)pk23;
        hid[o3 >> 1] = (short)(pk23 >> 16);
      }
    }
    __syncthreads();
    // ---- GEMM2: eo[px-range w*16..+16][128c]; macc += pr_e * (eo + b2)
    {
      bf16x8 a2f[8];
#pragma unroll
      for (int kt = 0; kt < 8; ++kt) {
        int row = w * 16 + (l & 15);
        int off = (row * 512 + kt * 64 + (l >> 4) * 16) ^ ((row & 7) << 4);
        a2f[kt] = *(const bf16x8*)((const char*)hid + off);
      }
      float pw[4];
#pragma unroll
      for (int r = 0; r < 4; ++r) pw[r] = pr[w * 16 + (l >> 4) * 4 + r][e];
#pragma unroll
      for (int ct = 0; ct < 8; ++ct) {
        f32x4 acc = {0.f, 0.f, 0.f, 0.f};
#pragma unroll
        for (int kt = 0; kt < 8; ++kt) {
          bf16x8 b2f = *(const bf16x8*)(w2p + ((((size_t)(e * 8 + kt) * 8 + ct) * 64 + l) * 8));
          acc = __builtin_amdgcn_mfma_f32_16x16x32_bf16(a2f[kt], b2f, acc, 0, 0, 0);
        }
        float b2v = b2[e * 128 + ct * 16 + (l & 15)];
#pragma unroll
        for (int r = 0; r < 4; ++r) macc[ct][r] += (acc[r] + b2v) * pw[r];
      }
    }
    __syncthreads();
  }

  // fin[px][c] = on + moe  (f32, stride 130)
#pragma unroll
  for (int ct = 0; ct < 8; ++ct) {
#pragma unroll
    for (int r = 0; r < 4; ++r) {
      int row = w * 16 + (l >> 4) * 4 + r;
      int c = ct * 16 + (l & 15);
      int aoff = (row * 256 + c * 2) ^ ((row & 7) << 4);
      float onv = bf2f(((unsigned short*)At)[aoff >> 1]);
      fin[row * 130 + c] = macc[ct][r] + onv;
    }
  }
  __syncthreads();
  for (int idx = tid; idx < 64 * 128; idx += 256) {
    int px = idx & 63, ch = idx >> 6;
    size_t off = ((size_t)n * 64 + (ch & 63)) * 4096 + p0 + px;
    float resid = (ch < 64) ? (Xre[off] + xre[off]) : (Xim[off] + xim[off]);
    out[((size_t)n * 128 + ch) * 4096 + p0 + px] = resid + fin[px * 130 + ch];
  }
}

extern "C" void kernel_launch(void* const* d_in, const int* in_sizes, int n_in,
                              void* d_out, int out_size, void* d_ws, size_t ws_size,
                              hipStream_t stream) {
  const float* xre = (const float*)d_in[0];
  const float* xim = (const float*)d_in[1];
  const float* hre = (const float*)d_in[2];
  const float* him = (const float*)d_in[3];
  const float* dt = (const float*)d_in[4];
  const float* fre = (const float*)d_in[5];
  const float* fim = (const float*)d_in[6];
  const float* nsg = (const float*)d_in[7];
  const float* nsb = (const float*)d_in[8];
  const float* cw = (const float*)d_in[9];
  const float* cb = (const float*)d_in[10];
  const float* Ere = (const float*)d_in[11];
  const float* Eim = (const float*)d_in[12];
  const float* Fre = (const float*)d_in[13];
  const float* Fim = (const float*)d_in[14];
  const float* mixw = (const float*)d_in[15];
  const float* mixb = (const float*)d_in[16];
  const float* nu = (const float*)d_in[17];
  const float* th = (const float*)d_in[18];
  const float* srcw = (const float*)d_in[19];
  const float* srcb = (const float*)d_in[20];
  const float* gw = (const float*)d_in[21];
  const float* gbv = (const float*)d_in[22];
  const float* la = (const float*)d_in[23];
  const float* lb = (const float*)d_in[24];
  const float* ntg = (const float*)d_in[25];
  const float* ntb = (const float*)d_in[26];
  const float* rw = (const float*)d_in[27];
  const float* rb = (const float*)d_in[28];
  const float* w1 = (const float*)d_in[29];
  const float* b1 = (const float*)d_in[30];
  const float* w2 = (const float*)d_in[31];
  const float* b2 = (const float*)d_in[32];

  float* ws = (float*)d_ws;
  float* Xre_ = ws;
  float* Xim_ = ws + PLANE;
  unsigned short* onb16 = (unsigned short*)(ws + 2 * PLANE);  // BIGSZ bf16
  unsigned short* wcv = (unsigned short*)(ws + 2 * PLANE + BIGSZ / 2);  // 147456 bf16
  unsigned short* w1p = wcv + 147456;                          // 131072 bf16
  unsigned short* w2p = w1p + 131072;                          // 131072 bf16
  unsigned short* rwp = w2p + 131072;                          // 2048 bf16
  float* sm = (float*)(rwp + 2048);
  float2* Xm = (float2*)sm;
  float2* xmix = Xm + TN * 64;
  float2* fsb = xmix + TN * 64;
  float* gbuf = (float*)(fsb + TN * 64);
  float2* srcv = (float2*)(gbuf + TN * 64);
  float2* opdv = srcv + TN * 64;
  float2* opfv = opdv + TN * 64;

  float* out = (float*)d_out;
  unsigned short* xnb = (unsigned short*)d_out;  // bf16 xn; dead before U written
  float* U_re = (float*)d_out;
  float* U_im = U_re + PLANE;

  hipLaunchKernelGGL(k_repc, dim3(576), dim3(256), 0, stream, cw, wcv);
  hipLaunchKernelGGL(k_repw, dim3(1033), dim3(256), 0, stream, w1, w2, rw, w1p, w2p, rwp);
  hipLaunchKernelGGL(k_ln_in, dim3(TN * 64), dim3(256), 0, stream, xre, xim, nsg, nsb, xnb);
  hipLaunchKernelGGL(k_conv, dim3(TN * 64), dim3(256), 0, stream, xnb, wcv, cb, Xre_, Xim_);
  hipLaunchKernelGGL(k_xmean, dim3(TN * 64), dim3(256), 0, stream, Xre_, Xim_, xre, xim, Xm);
  hipLaunchKernelGGL(k_chainA, dim3(TN), dim3(128), 0, stream, Xm, Ere, Eim, mixw, mixb, xmix);
  hipLaunchKernelGGL(k_chainB, dim3(1), dim3(128), 0, stream, xmix, nu, th, fre, fim, fsb);
  hipLaunchKernelGGL(k_chainC, dim3(TN), dim3(128), 0, stream, fsb, srcw, srcb, gw, gbv, la, lb,
                     dt, gbuf, srcv, opdv, opfv);
  hipLaunchKernelGGL(k_ut, dim3(TN * 64), dim3(256), 0, stream, Xre_, Xim_, xre, xim, Ere, Eim,
                     gbuf, srcv, opdv, opfv, hre, him, U_re, U_im);
  hipLaunchKernelGGL(k_scan, dim3(2048), dim3(256), 0, stream, U_re, U_im, opdv);
  hipLaunchKernelGGL(k_xdec, dim3(TN * 64), dim3(256), 0, stream, U_re, U_im, Fre, Fim, ntg, ntb,
                     onb16);
  hipLaunchKernelGGL(k_moe2, dim3(TN * 64), dim3(256), 0, stream, onb16, w1p, w2p, rwp, rb, b1, b2,
                     Xre_, Xim_, xre, xim, out);
  (void)in_sizes; (void)n_in; (void)out_size; (void)ws_size;
}

// Round 5
// 626.532 us; speedup vs baseline: 15.7014x; 1.2322x over previous
//
#include <hip/hip_runtime.h>

// UniPhyBlock pipeline, round 4: k_moe2 rebuilt around swapped-operand 32x32
// MFMA (hid^T kept in registers, no LDS round-trip, no e-loop barriers).
// B=2 T=16 D=64 H=W=64, C=128, E=4 experts, M=256.

#define DEV static __device__ __forceinline__

typedef __attribute__((ext_vector_type(8))) short bf16x8;
typedef __attribute__((ext_vector_type(4))) float f32x4;
typedef __attribute__((ext_vector_type(16))) float f32x16;
typedef __attribute__((ext_vector_type(4))) unsigned int u32x4;

namespace {
constexpr int TN = 32;          // B*T
constexpr size_t PLANE = (size_t)TN * 64 * 4096;   // 8,388,608
constexpr size_t BIGSZ = (size_t)TN * 4096 * 128;  // 16,777,216

DEV float sp_f(float x) { return x > 20.f ? x : log1pf(expf(x)); }
DEV unsigned short f2bf(float f) {
  unsigned int u = __float_as_uint(f);
  unsigned int r = (u + 0x7FFFu + ((u >> 16) & 1u)) >> 16;
  return (unsigned short)r;
}
DEV float bf2f(unsigned short s) { return __uint_as_float(((unsigned int)s) << 16); }
DEV unsigned int cvtpk(float lo, float hi) {
  unsigned int u;
  asm("v_cvt_pk_bf16_f32 %0, %1, %2" : "=v"(u) : "v"(lo), "v"(hi));
  return u;
}
// tanh-gelu == x * sigmoid(2*0.79788456*(x + 0.044715 x^3)); rcp-based sigmoid
DEV float gelu_f(float x) {
  float x2 = x * x;
  float z2 = 1.5957691216057308f * x * (1.f + 0.044715f * x2);
  float r = __builtin_amdgcn_rcpf(1.f + __expf(-z2));
  return x * r;
}
} // namespace

// K0c: repack conv_w (Co,Ci,3,3) fp32 -> bf16 MFMA B-fragments
__global__ void k_repc(const float* __restrict__ cw, unsigned short* __restrict__ wcv) {
  int i = blockIdx.x * 256 + threadIdx.x;  // 147456
  if (i >= 9 * 4 * 8 * 64 * 8) return;
  int j = i & 7, l = (i >> 3) & 63, ct = (i >> 9) & 7, cb = (i >> 12) & 3, k = i >> 14;
  int co = ct * 16 + (l & 15);
  int ci = cb * 32 + (l >> 4) * 8 + j;
  wcv[i] = f2bf(cw[((size_t)co * 128 + ci) * 9 + k]);
}

// K0b: repack w1 -> 32x32x16 A-fragments (w1^T), w2 -> 32x32x16 B-fragments,
// router rw -> 16x16x32 B-fragments (zero-padded).
// w1tp[e][mtG8][kt8][l64][j8]  = w1[e][c=kt*16+(l>>5)*8+j][m=mtG*32+(l&31)]
// w2p32[e][ktG16][ct4][l64][j8]= w2[e][m=ktG*16+(l>>5)*8+j][c=ct*32+(l&31)]
__global__ void k_repw(const float* __restrict__ w1, const float* __restrict__ w2,
                       const float* __restrict__ rw,
                       unsigned short* __restrict__ w1tp, unsigned short* __restrict__ w2p32,
                       unsigned short* __restrict__ rwp) {
  int i = blockIdx.x * 256 + threadIdx.x;  // 264192 total
  if (i >= 262144 + 2048) return;
  if (i >= 262144) {  // rwp[kt<4][l<64][j<8], zero-padded cols 4..15
    int idx = i - 262144;
    int j = idx & 7, l = (idx >> 3) & 63, kt = idx >> 9;
    int col = l & 15;
    rwp[idx] = col < 4 ? f2bf(rw[(kt * 32 + (l >> 4) * 8 + j) * 4 + col]) : (unsigned short)0;
    return;
  }
  int half = i >> 17;
  int idx = i & 131071;
  int j = idx & 7, l = (idx >> 3) & 63;
  if (half == 0) {
    int kt = (idx >> 9) & 7, mtG = (idx >> 12) & 7, e = idx >> 15;
    int c = kt * 16 + (l >> 5) * 8 + j, m = mtG * 32 + (l & 31);
    w1tp[idx] = f2bf(w1[((size_t)e * 128 + c) * 256 + m]);
  } else {
    int ct = (idx >> 9) & 3, ktG = (idx >> 11) & 15, e = idx >> 15;
    int m = ktG * 16 + (l >> 5) * 8 + j, c = ct * 32 + (l & 31);
    w2p32[idx] = f2bf(w2[((size_t)e * 256 + m) * 128 + c]);
  }
}

// K1: layernorm over channels -> xn bf16 [n][p][c]
__global__ __launch_bounds__(256) void k_ln_in(
    const float* __restrict__ xre, const float* __restrict__ xim,
    const float* __restrict__ gg, const float* __restrict__ bb,
    unsigned short* __restrict__ xnb) {
  int n = blockIdx.x >> 6, h = blockIdx.x & 63;
  __shared__ float xl[64][129];
  __shared__ float ps[4][64], ps2[4][64];
  __shared__ float mu[64], rs[64];
  int tid = threadIdx.x;
  int w = tid & 63, q = tid >> 6;
  size_t base = ((size_t)n * 4096 + h) * 64 + w;
  for (int d = q; d < 64; d += 4) {
    size_t o = base + (size_t)d * 4096;
    xl[w][d] = xre[o];
    xl[w][64 + d] = xim[o];
  }
  __syncthreads();
  float s = 0.f, s2 = 0.f;
  for (int c = q * 32; c < q * 32 + 32; ++c) { float v = xl[w][c]; s += v; s2 += v * v; }
  ps[q][w] = s; ps2[q][w] = s2;
  __syncthreads();
  if (tid < 64) {
    float a = 0.f, b2 = 0.f;
#pragma unroll
    for (int i = 0; i < 4; ++i) { a += ps[i][tid]; b2 += ps2[i][tid]; }
    float m = a * (1.f / 128.f);
    mu[tid] = m;
    rs[tid] = rsqrtf(b2 * (1.f / 128.f) - m * m + 1e-5f);
  }
  __syncthreads();
  size_t obase = ((size_t)n * 4096 + (size_t)h * 64) * 128;
  for (int idx = tid; idx < 64 * 64; idx += 256) {
    int q2 = idx >> 6, c2 = (idx & 63) * 2;
    float v0 = (xl[q2][c2] - mu[q2]) * rs[q2] * gg[c2] + bb[c2];
    float v1 = (xl[q2][c2 + 1] - mu[q2]) * rs[q2] * gg[c2 + 1] + bb[c2 + 1];
    *(unsigned int*)&xnb[obase + (size_t)q2 * 128 + c2] = cvtpk(v0, v1);
  }
}

// K2: 3x3 SAME conv via MFMA. Block = (n,h): 64 px x 128 co, K=9*128.
__global__ __launch_bounds__(256) void k_conv(
    const unsigned short* __restrict__ xnb, const unsigned short* __restrict__ wcv,
    const float* __restrict__ cbias, float* __restrict__ Xre, float* __restrict__ Xim) {
  int n = blockIdx.x >> 6, h = blockIdx.x & 63;
  __shared__ __align__(16) short in_t[3 * 66 * 128];  // 50688 B, XOR-swizzled rows
  __shared__ float tr[64][66];
  int tid = threadIdx.x;
  int l = tid & 63;
  int w = __builtin_amdgcn_readfirstlane(tid >> 6);

  for (int it = 0; it < 13; ++it) {
    int ch = tid + it * 256;  // 3168 chunks of 16B
    if (ch < 3168) {
      int ri = ch >> 4, cb16 = ch & 15;
      int rr = ri >= 132 ? 2 : (ri >= 66 ? 1 : 0);
      int wp = ri - rr * 66 - 1;
      int hh = h + rr - 1;
      uint4 v = make_uint4(0, 0, 0, 0);
      if ((unsigned)hh < 64u && (unsigned)wp < 64u)
        v = *(const uint4*)(xnb + ((size_t)(n * 4096 + hh * 64 + wp) << 7) + cb16 * 8);
      int off = (ri * 256 + cb16 * 16) ^ ((ri & 7) << 4);
      *(uint4*)((char*)in_t + off) = v;
    }
  }
  __syncthreads();

  f32x4 acc[4][2];
#pragma unroll
  for (int pt = 0; pt < 4; ++pt) { acc[pt][0] = {0,0,0,0}; acc[pt][1] = {0,0,0,0}; }

#pragma unroll
  for (int kh = 0; kh < 3; ++kh) {
#pragma unroll
    for (int kw = 0; kw < 3; ++kw) {
      int k = kh * 3 + kw;
#pragma unroll
      for (int cb = 0; cb < 4; ++cb) {
        const unsigned short* wb = wcv + ((((size_t)(k * 4 + cb) * 8) + 2 * w) * 64 + l) * 8;
        bf16x8 b0 = *(const bf16x8*)wb;
        bf16x8 b1 = *(const bf16x8*)(wb + 64 * 8);
#pragma unroll
        for (int pt = 0; pt < 4; ++pt) {
          int ri = kh * 66 + pt * 16 + (l & 15) + kw;
          int off = (ri * 256 + cb * 64 + (l >> 4) * 16) ^ ((ri & 7) << 4);
          bf16x8 a = *(const bf16x8*)((const char*)in_t + off);
          acc[pt][0] = __builtin_amdgcn_mfma_f32_16x16x32_bf16(a, b0, acc[pt][0], 0, 0, 0);
          acc[pt][1] = __builtin_amdgcn_mfma_f32_16x16x32_bf16(a, b1, acc[pt][1], 0, 0, 0);
        }
      }
    }
  }

  for (int pass = 0; pass < 2; ++pass) {
    __syncthreads();
    if ((w >> 1) == pass) {
      int ctl = w & 1;
#pragma unroll
      for (int ct = 0; ct < 2; ++ct) {
        int col = ctl * 32 + ct * 16 + (l & 15);
        float bias = cbias[pass * 64 + col];
#pragma unroll
        for (int pt = 0; pt < 4; ++pt)
#pragma unroll
          for (int r = 0; r < 4; ++r)
            tr[col][pt * 16 + (l >> 4) * 4 + r] = acc[pt][ct][r] + bias;
      }
    }
    __syncthreads();
    float* Xo = pass ? Xim : Xre;
    for (int it = 0; it < 16; ++it) {
      int ch = tid + it * 256;  // 4096
      int co = ch >> 6, px = ch & 63;
      Xo[((size_t)n * 64 + co) * 4096 + h * 64 + px] = tr[co][px];
    }
  }
}

// K3: Xm[n][d] = mean_p (X + xf).
__global__ __launch_bounds__(256) void k_xmean(
    const float* __restrict__ Xre, const float* __restrict__ Xim,
    const float* __restrict__ xre, const float* __restrict__ xim,
    float2* __restrict__ Xm) {
  int nd = blockIdx.x;
  size_t base = (size_t)nd * 4096;
  int tid = threadIdx.x;
  float sr = 0.f, si = 0.f;
  for (int p = tid; p < 4096; p += 256) {
    sr += Xre[base + p] + xre[base + p];
    si += Xim[base + p] + xim[base + p];
  }
  __shared__ float r1[256], r2[256];
  r1[tid] = sr; r2[tid] = si;
  __syncthreads();
  for (int s = 128; s > 0; s >>= 1) {
    if (tid < s) { r1[tid] += r1[tid + s]; r2[tid] += r2[tid + s]; }
    __syncthreads();
  }
  if (tid == 0) Xm[nd] = make_float2(r1[0] * (1.f / 4096.f), r2[0] * (1.f / 4096.f));
}

// K4: per (b,t): xmean = Xm @ Ec; fcat = [re,im] @ mix_w + mix_b
__global__ void k_chainA(const float2* __restrict__ Xm, const float* __restrict__ Ere,
                         const float* __restrict__ Eim, const float* __restrict__ mixw,
                         const float* __restrict__ mixb, float2* __restrict__ xmix) {
  int n = blockIdx.x;
  int tid = threadIdx.x;  // 128
  __shared__ float2 xm[64];
  __shared__ float cat[128];
  __shared__ float fc[128];
  if (tid < 64) xm[tid] = Xm[n * 64 + tid];
  __syncthreads();
  if (tid < 64) {
    float ar = 0.f, ai = 0.f;
    for (int d = 0; d < 64; ++d) {
      float2 x = xm[d];
      float er = Ere[d * 64 + tid], ei = Eim[d * 64 + tid];
      ar += x.x * er - x.y * ei;
      ai += x.x * ei + x.y * er;
    }
    cat[tid] = ar; cat[64 + tid] = ai;
  }
  __syncthreads();
  {
    float f = mixb[tid];
    for (int i = 0; i < 128; ++i) f += cat[i] * mixw[i * 128 + tid];
    fc[tid] = f;
  }
  __syncthreads();
  if (tid < 64) xmix[n * 64 + tid] = make_float2(fc[tid], fc[64 + tid]);
}

// K5: flux scan over t
__global__ void k_chainB(const float2* __restrict__ xmix, const float* __restrict__ nu,
                         const float* __restrict__ th, const float* __restrict__ fre,
                         const float* __restrict__ fim, float2* __restrict__ fs) {
  int tid = threadIdx.x;  // 128
  int b = tid >> 6, d = tid & 63;
  float r = expf(-sp_f(nu[d]));
  float dr = r * cosf(th[d]), di = r * sinf(th[d]);
  float yr = 0.f, yi = 0.f, cr = 1.f, ci = 0.f;
  float fr = fre[b * 64 + d], fi = fim[b * 64 + d];
  for (int t = 0; t < 16; ++t) {
    int n = b * 16 + t;
    float ncr = cr * dr - ci * di, nci = cr * di + ci * dr;
    cr = ncr; ci = nci;
    float2 xm = xmix[n * 64 + d];
    float nyr = dr * yr - di * yi + xm.x;
    float nyi = dr * yi + di * yr + xm.y;
    yr = nyr; yi = nyi;
    fs[n * 64 + d] = make_float2(yr + fr * cr - fi * ci, yi + fr * ci + fi * cr);
  }
}

// K6: per (b,t): source, gate, op_decay, op_forcing
__global__ void k_chainC(const float2* __restrict__ fs, const float* __restrict__ srcw,
                         const float* __restrict__ srcb, const float* __restrict__ gw,
                         const float* __restrict__ gbv, const float* __restrict__ la,
                         const float* __restrict__ lbv, const float* __restrict__ dt,
                         float* __restrict__ g, float2* __restrict__ src,
                         float2* __restrict__ opd, float2* __restrict__ opf) {
  int n = blockIdx.x;
  int t = n & 15;
  int tid = threadIdx.x;  // 128
  __shared__ float oc[128];
  __shared__ float sl[128];
  if (tid < 64) { float2 v = fs[n * 64 + tid]; oc[tid] = v.x; oc[64 + tid] = v.y; }
  __syncthreads();
  {
    float s = srcb[tid];
    for (int i = 0; i < 128; ++i) s += oc[i] * srcw[i * 128 + tid];
    sl[tid] = s;
  }
  if (tid < 64) {
    float gv = gbv[tid];
    for (int i = 0; i < 128; ++i) gv += oc[i] * gw[i * 64 + tid];
    g[n * 64 + tid] = 1.f / (1.f + expf(-gv));
    float lr = -sp_f(la[tid]), li = lbv[tid];
    float dtv = dt[t];
    float er = expf(lr * dtv);
    float2 od = make_float2(er * cosf(li * dtv), er * sinf(li * dtv));
    opd[n * 64 + tid] = od;
    float inv = 1.f / (lr * lr + li * li);
    float nx = od.x - 1.f, ny = od.y;
    opf[n * 64 + tid] = make_float2((nx * lr + ny * li) * inv, (ny * lr - nx * li) * inv);
  }
  __syncthreads();
  if (tid < 64) src[n * 64 + tid] = make_float2(sl[tid], sl[64 + tid]);
}

// K7: u_t
__global__ __launch_bounds__(256) void k_ut(
    const float* __restrict__ Xre, const float* __restrict__ Xim,
    const float* __restrict__ xre, const float* __restrict__ xim,
    const float* __restrict__ Ere, const float* __restrict__ Eim,
    const float* __restrict__ g, const float2* __restrict__ src,
    const float2* __restrict__ opd, const float2* __restrict__ opf,
    const float* __restrict__ hre, const float* __restrict__ him,
    float* __restrict__ Ure, float* __restrict__ Uim) {
  int n = blockIdx.x >> 6, pt = blockIdx.x & 63;
  int p0 = pt * 64;
  int b = n >> 4, t = n & 15;
  __shared__ float2 Ec[64][64];
  __shared__ float gl[64];
  __shared__ float2 sl[64], ofl[64], odl[64];
  int tid = threadIdx.x;
  for (int idx = tid; idx < 4096; idx += 256)
    Ec[idx >> 6][idx & 63] = make_float2(Ere[idx], Eim[idx]);
  if (tid < 64) {
    gl[tid] = g[n * 64 + tid]; sl[tid] = src[n * 64 + tid];
    ofl[tid] = opf[n * 64 + tid]; odl[tid] = opd[n * 64 + tid];
  }
  __syncthreads();
  int px = tid & 63, grp = tid >> 6;
  float ar[16], ai[16];
#pragma unroll
  for (int j = 0; j < 16; ++j) { ar[j] = 0.f; ai[j] = 0.f; }
  size_t rowbase = (size_t)n * 64 * 4096 + p0 + px;
  for (int d = 0; d < 64; ++d) {
    size_t off = rowbase + (size_t)d * 4096;
    float xr = Xre[off] + xre[off];
    float xi = Xim[off] + xim[off];
#pragma unroll
    for (int j = 0; j < 16; ++j) {
      float2 e = Ec[d][grp * 16 + j];
      ar[j] += xr * e.x - xi * e.y;
      ai[j] += xr * e.y + xi * e.x;
    }
  }
#pragma unroll
  for (int j = 0; j < 16; ++j) {
    int ee = grp * 16 + j;
    float gv = gl[ee];
    float2 s = sl[ee];
    float fr = ar[j] * gv + s.x * (1.f - gv);
    float fi = ai[j] * gv + s.y * (1.f - gv);
    float2 of = ofl[ee];
    float ur = fr * of.x - fi * of.y;
    float ui = fr * of.y + fi * of.x;
    if (t == 0) {
      size_t hoff = ((size_t)b * 4096 + p0 + px) * 64 + ee;
      float hr = hre[hoff], hi = him[hoff];
      float2 od = odl[ee];
      ur += hr * od.x - hi * od.y;
      ui += hr * od.y + hi * od.x;
    }
    size_t off = ((size_t)n * 64 + ee) * 4096 + p0 + px;
    Ure[off] = ur; Uim[off] = ui;
  }
}

// K8: associative scan over t (in place on U)
__global__ __launch_bounds__(256) void k_scan(float* __restrict__ Ure, float* __restrict__ Uim,
                                              const float2* __restrict__ opd) {
  int gid = blockIdx.x * 256 + threadIdx.x;  // 524288
  int p = gid & 4095, d = (gid >> 12) & 63, b = gid >> 18;
  float yr = 0.f, yi = 0.f;
  for (int t = 0; t < 16; ++t) {
    int n = b * 16 + t;
    float2 od = opd[n * 64 + d];
    size_t off = ((size_t)n * 64 + d) * 4096 + p;
    float ur = Ure[off], ui = Uim[off];
    float nyr = od.x * yr - od.y * yi + ur;
    float nyi = od.x * yi + od.y * yr + ui;
    yr = nyr; yi = nyi;
    Ure[off] = yr; Uim[off] = yi;
  }
}

// K9: x_dec = u_out @ Fc, layernorm -> on (bf16) [n][p][c]
__global__ __launch_bounds__(256) void k_xdec(
    const float* __restrict__ Ure, const float* __restrict__ Uim,
    const float* __restrict__ Fre, const float* __restrict__ Fim,
    const float* __restrict__ ntg, const float* __restrict__ ntb,
    unsigned short* __restrict__ onb) {
  int n = blockIdx.x >> 6, pt = blockIdx.x & 63;
  int p0 = pt * 64;
  __shared__ float2 Fc[64][64];
  __shared__ float onl[64][129];
  __shared__ float ps[4][64], ps2[4][64];
  __shared__ float mu[64], rs[64];
  int tid = threadIdx.x;
  for (int idx = tid; idx < 4096; idx += 256)
    Fc[idx >> 6][idx & 63] = make_float2(Fre[idx], Fim[idx]);
  __syncthreads();
  int px = tid & 63, grp = tid >> 6;
  float ar[16], ai[16];
#pragma unroll
  for (int j = 0; j < 16; ++j) { ar[j] = 0.f; ai[j] = 0.f; }
  size_t rowbase = (size_t)n * 64 * 4096 + p0 + px;
  for (int d = 0; d < 64; ++d) {
    size_t off = rowbase + (size_t)d * 4096;
    float xr = Ure[off], xi = Uim[off];
#pragma unroll
    for (int j = 0; j < 16; ++j) {
      float2 e = Fc[d][grp * 16 + j];
      ar[j] += xr * e.x - xi * e.y;
      ai[j] += xr * e.y + xi * e.x;
    }
  }
#pragma unroll
  for (int j = 0; j < 16; ++j) {
    int ee = grp * 16 + j;
    onl[px][ee] = ar[j];
    onl[px][64 + ee] = ai[j];
  }
  __syncthreads();
  float s = 0.f, s2 = 0.f;
  for (int c = grp * 32; c < grp * 32 + 32; ++c) { float v = onl[px][c]; s += v; s2 += v * v; }
  ps[grp][px] = s; ps2[grp][px] = s2;
  __syncthreads();
  if (tid < 64) {
    float a = 0.f, b2 = 0.f;
#pragma unroll
    for (int i = 0; i < 4; ++i) { a += ps[i][tid]; b2 += ps2[i][tid]; }
    float m = a * (1.f / 128.f);
    mu[tid] = m;
    rs[tid] = rsqrtf(b2 * (1.f / 128.f) - m * m + 1e-5f);
  }
  __syncthreads();
  size_t obase = ((size_t)n * 4096 + p0) * 128;
  for (int idx = tid; idx < 64 * 64; idx += 256) {
    int q = idx >> 6, c2 = (idx & 63) * 2;
    float v0 = (onl[q][c2] - mu[q]) * rs[q] * ntg[c2] + ntb[c2];
    float v1 = (onl[q][c2 + 1] - mu[q]) * rs[q] * ntg[c2 + 1] + ntb[c2 + 1];
    *(unsigned int*)&onb[obase + (size_t)q * 128 + c2] = cvtpk(v0, v1);
  }
}

// K10: MoE via swapped-operand 32x32 MFMA; hid^T lives in registers.
// 4 waves: pw = w&1 (px half), mh = w>>1 (m half). End: cross-pair reduction.
__global__ __launch_bounds__(256) void k_moe2(
    const unsigned short* __restrict__ onb, const unsigned short* __restrict__ w1tp,
    const unsigned short* __restrict__ w2p32, const unsigned short* __restrict__ rwp,
    const float* __restrict__ rb, const float* __restrict__ b1, const float* __restrict__ b2,
    const float* __restrict__ Xre, const float* __restrict__ Xim,
    const float* __restrict__ xre, const float* __restrict__ xim,
    float* __restrict__ out) {
  int n = blockIdx.x >> 6, ptile = blockIdx.x & 63;
  int p0 = ptile * 64;
  __shared__ __align__(16) short At[64 * 128];  // 16KB swizzled
  __shared__ __align__(16) float buf[8320];     // 33280B: b1l/b2l -> red -> fin
  __shared__ float pr[64][4];
  int tid = threadIdx.x;
  int l = tid & 63;
  int w = __builtin_amdgcn_readfirstlane(tid >> 6);
  int h = l >> 5, s = l & 31;
  float* b1l = buf;         // 1024 f32
  float* b2l = buf + 1024;  // 512 f32

  for (int i = tid; i < 1024; i += 256) b1l[i] = b1[i];
  for (int i = tid; i < 512; i += 256) b2l[i] = b2[i];

  {  // stage At (on, bf16) -> LDS swizzled
    const char* gsrc = (const char*)onb + ((size_t)n * 4096 + p0) * 256;
#pragma unroll
    for (int it = 0; it < 4; ++it) {
      int ch = tid + it * 256;
      int row = ch >> 4, cb = (ch & 15) * 16;
      float4 v = *(const float4*)(gsrc + (size_t)row * 256 + cb);
      int off = (row * 256 + cb) ^ ((row & 7) << 4);
      *(float4*)((char*)At + off) = v;
    }
  }
  __syncthreads();

  {  // MFMA router (16x16): logits[16px x 4e] per wave
    f32x4 acc = {0.f, 0.f, 0.f, 0.f};
#pragma unroll
    for (int kt = 0; kt < 4; ++kt) {
      int row = w * 16 + (l & 15);
      int off = (row * 256 + kt * 64 + (l >> 4) * 16) ^ ((row & 7) << 4);
      bf16x8 aa = *(const bf16x8*)((const char*)At + off);
      bf16x8 bb = *(const bf16x8*)(rwp + ((size_t)kt * 64 + l) * 8);
      acc = __builtin_amdgcn_mfma_f32_16x16x32_bf16(aa, bb, acc, 0, 0, 0);
    }
    int e = l & 15;
    float rbv = e < 4 ? rb[e] : 0.f;
#pragma unroll
    for (int r = 0; r < 4; ++r) {
      float lg = acc[r] + rbv;
      float m = fmaxf(lg, __shfl_xor(lg, 1));
      m = fmaxf(m, __shfl_xor(m, 2));
      float ex = __expf(lg - m);
      float sm = ex + __shfl_xor(ex, 1);
      sm += __shfl_xor(sm, 2);
      float p = ex * __builtin_amdgcn_rcpf(sm);
      if (e < 4) pr[w * 16 + (l >> 4) * 4 + r][e] = p;
    }
  }
  __syncthreads();

  int pw = w & 1, mh = w >> 1;
  int rowb = pw * 32 + s;
  int swz = (rowb & 7) << 4;

  float macc[4][16];
#pragma unroll
  for (int ct = 0; ct < 4; ++ct)
#pragma unroll
    for (int r = 0; r < 16; ++r) macc[ct][r] = 0.f;

  const f32x16 Z16 = {0.f, 0.f, 0.f, 0.f, 0.f, 0.f, 0.f, 0.f,
                      0.f, 0.f, 0.f, 0.f, 0.f, 0.f, 0.f, 0.f};

  for (int e = 0; e < 4; ++e) {
    // ---- GEMM1 (swapped): hid^T[m 128 (wave half)][px 32 (wave half)]
    u32x4 af[8];  // GEMM2 A-fragments, built per mt
#pragma unroll
    for (int mt = 0; mt < 4; ++mt) {
      f32x16 acc = Z16;
#pragma unroll
      for (int kt = 0; kt < 8; ++kt) {
        bf16x8 a = *(const bf16x8*)(
            w1tp + ((((size_t)e * 8 + (mh * 4 + mt)) * 8 + kt) * 64 + l) * 8);
        int off = (rowb * 256 + kt * 32 + h * 16) ^ swz;
        bf16x8 b = *(const bf16x8*)((const char*)At + off);
        acc = __builtin_amdgcn_mfma_f32_32x32x16_bf16(a, b, acc, 0, 0, 0);
      }
      // bias + gelu + pack: hpk[i] = bf16(pos 2i, 2i+1); pos=(r&3)+8*(r>>2)+4h
      unsigned int hpk[8];
#pragma unroll
      for (int i2 = 0; i2 < 8; ++i2) {
        int r0 = 2 * i2;
        int m0 = mh * 128 + mt * 32 + (r0 & 3) + 8 * (r0 >> 2) + 4 * h;
        float2 bv = *(const float2*)&b1l[e * 256 + m0];
        hpk[i2] = cvtpk(gelu_f(acc[r0] + bv.x), gelu_f(acc[r0 + 1] + bv.y));
      }
      // assemble A-frags for kt = 2mt, 2mt+1 via half-wave exchange
#pragma unroll
      for (int hf = 0; hf < 2; ++hf) {
        unsigned int pA = hpk[4 * hf + 0], pB = hpk[4 * hf + 1];
        unsigned int pC = hpk[4 * hf + 2], pD = hpk[4 * hf + 3];
        unsigned int Z0 = h ? pC : pA, Z1 = h ? pD : pB;   // own needed
        unsigned int S0 = h ? pA : pC, S1 = h ? pB : pD;   // partner needs
        unsigned int Ss0 = (unsigned int)__shfl_xor((int)S0, 32);
        unsigned int Ss1 = (unsigned int)__shfl_xor((int)S1, 32);
        u32x4 fr;
        fr.x = h ? Ss0 : Z0;
        fr.y = h ? Ss1 : Z1;
        fr.z = h ? Z0 : Ss0;
        fr.w = h ? Z1 : Ss1;
        af[mt * 2 + hf] = fr;
      }
    }
    // per-px router probs for this expert
    float prv[16];
#pragma unroll
    for (int r = 0; r < 16; ++r) {
      int px = pw * 32 + (r & 3) + 8 * (r >> 2) + 4 * h;
      prv[r] = pr[px][e];
    }
    // ---- GEMM2: eo[px 32][c 128] partial over wave's 128 m
#pragma unroll
    for (int ct = 0; ct < 4; ++ct) {
      f32x16 acc = Z16;
#pragma unroll
      for (int kt = 0; kt < 8; ++kt) {
        bf16x8 bf = *(const bf16x8*)(
            w2p32 + ((((size_t)e * 16 + (mh * 8 + kt)) * 4 + ct) * 64 + l) * 8);
        bf16x8 a = __builtin_bit_cast(bf16x8, af[kt]);
        acc = __builtin_amdgcn_mfma_f32_32x32x16_bf16(a, bf, acc, 0, 0, 0);
      }
      float b2v = mh ? 0.f : b2l[e * 128 + ct * 32 + s];
#pragma unroll
      for (int r = 0; r < 16; ++r) macc[ct][r] += (acc[r] + b2v) * prv[r];
    }
  }

  // ---- cross-pair (m-half) reduction, then fin = macc + on, then out
  __syncthreads();
  if (mh == 1) {
#pragma unroll
    for (int g = 0; g < 16; ++g) {
      int ct = g >> 2, q = (g & 3) * 4;
      float4 v = make_float4(macc[ct][q], macc[ct][q + 1], macc[ct][q + 2], macc[ct][q + 3]);
      *(float4*)&buf[((g * 2 + pw) * 64 + l) * 4] = v;
    }
  }
  __syncthreads();
  if (mh == 0) {
#pragma unroll
    for (int g = 0; g < 16; ++g) {
      float4 v = *(const float4*)&buf[((g * 2 + pw) * 64 + l) * 4];
      int ct = g >> 2, q = (g & 3) * 4;
      macc[ct][q] += v.x; macc[ct][q + 1] += v.y;
      macc[ct][q + 2] += v.z; macc[ct][q + 3] += v.w;
    }
  }
  __syncthreads();
  if (mh == 0) {
#pragma unroll
    for (int ct = 0; ct < 4; ++ct) {
      int c = ct * 32 + s;
#pragma unroll
      for (int r = 0; r < 16; ++r) {
        int px = pw * 32 + (r & 3) + 8 * (r >> 2) + 4 * h;
        int aoff = (px * 256 + c * 2) ^ ((px & 7) << 4);
        float onv = bf2f(((unsigned short*)At)[aoff >> 1]);
        buf[px * 130 + c] = macc[ct][r] + onv;
      }
    }
  }
  __syncthreads();
  for (int idx = tid; idx < 64 * 128; idx += 256) {
    int px = idx & 63, ch = idx >> 6;
    size_t off = ((size_t)n * 64 + (ch & 63)) * 4096 + p0 + px;
    float resid = (ch < 64) ? (Xre[off] + xre[off]) : (Xim[off] + xim[off]);
    out[((size_t)n * 128 + ch) * 4096 + p0 + px] = resid + buf[px * 130 + ch];
  }
}

extern "C" void kernel_launch(void* const* d_in, const int* in_sizes, int n_in,
                              void* d_out, int out_size, void* d_ws, size_t ws_size,
                              hipStream_t stream) {
  const float* xre = (const float*)d_in[0];
  const float* xim = (const float*)d_in[1];
  const float* hre = (const float*)d_in[2];
  const float* him = (const float*)d_in[3];
  const float* dt = (const float*)d_in[4];
  const float* fre = (const float*)d_in[5];
  const float* fim = (const float*)d_in[6];
  const float* nsg = (const float*)d_in[7];
  const float* nsb = (const float*)d_in[8];
  const float* cw = (const float*)d_in[9];
  const float* cb = (const float*)d_in[10];
  const float* Ere = (const float*)d_in[11];
  const float* Eim = (const float*)d_in[12];
  const float* Fre = (const float*)d_in[13];
  const float* Fim = (const float*)d_in[14];
  const float* mixw = (const float*)d_in[15];
  const float* mixb = (const float*)d_in[16];
  const float* nu = (const float*)d_in[17];
  const float* th = (const float*)d_in[18];
  const float* srcw = (const float*)d_in[19];
  const float* srcb = (const float*)d_in[20];
  const float* gw = (const float*)d_in[21];
  const float* gbv = (const float*)d_in[22];
  const float* la = (const float*)d_in[23];
  const float* lb = (const float*)d_in[24];
  const float* ntg = (const float*)d_in[25];
  const float* ntb = (const float*)d_in[26];
  const float* rw = (const float*)d_in[27];
  const float* rb = (const float*)d_in[28];
  const float* w1 = (const float*)d_in[29];
  const float* b1 = (const float*)d_in[30];
  const float* w2 = (const float*)d_in[31];
  const float* b2 = (const float*)d_in[32];

  float* ws = (float*)d_ws;
  float* Xre_ = ws;
  float* Xim_ = ws + PLANE;
  unsigned short* onb16 = (unsigned short*)(ws + 2 * PLANE);  // BIGSZ bf16
  unsigned short* wcv = (unsigned short*)(ws + 2 * PLANE + BIGSZ / 2);  // 147456 bf16
  unsigned short* w1tp = wcv + 147456;                         // 131072 bf16
  unsigned short* w2p32 = w1tp + 131072;                       // 131072 bf16
  unsigned short* rwp = w2p32 + 131072;                        // 2048 bf16
  float* sm = (float*)(rwp + 2048);
  float2* Xm = (float2*)sm;
  float2* xmix = Xm + TN * 64;
  float2* fsb = xmix + TN * 64;
  float* gbuf = (float*)(fsb + TN * 64);
  float2* srcv = (float2*)(gbuf + TN * 64);
  float2* opdv = srcv + TN * 64;
  float2* opfv = opdv + TN * 64;

  float* out = (float*)d_out;
  unsigned short* xnb = (unsigned short*)d_out;  // bf16 xn; dead before U written
  float* U_re = (float*)d_out;
  float* U_im = U_re + PLANE;

  hipLaunchKernelGGL(k_repc, dim3(576), dim3(256), 0, stream, cw, wcv);
  hipLaunchKernelGGL(k_repw, dim3(1033), dim3(256), 0, stream, w1, w2, rw, w1tp, w2p32, rwp);
  hipLaunchKernelGGL(k_ln_in, dim3(TN * 64), dim3(256), 0, stream, xre, xim, nsg, nsb, xnb);
  hipLaunchKernelGGL(k_conv, dim3(TN * 64), dim3(256), 0, stream, xnb, wcv, cb, Xre_, Xim_);
  hipLaunchKernelGGL(k_xmean, dim3(TN * 64), dim3(256), 0, stream, Xre_, Xim_, xre, xim, Xm);
  hipLaunchKernelGGL(k_chainA, dim3(TN), dim3(128), 0, stream, Xm, Ere, Eim, mixw, mixb, xmix);
  hipLaunchKernelGGL(k_chainB, dim3(1), dim3(128), 0, stream, xmix, nu, th, fre, fim, fsb);
  hipLaunchKernelGGL(k_chainC, dim3(TN), dim3(128), 0, stream, fsb, srcw, srcb, gw, gbv, la, lb,
                     dt, gbuf, srcv, opdv, opfv);
  hipLaunchKernelGGL(k_ut, dim3(TN * 64), dim3(256), 0, stream, Xre_, Xim_, xre, xim, Ere, Eim,
                     gbuf, srcv, opdv, opfv, hre, him, U_re, U_im);
  hipLaunchKernelGGL(k_scan, dim3(2048), dim3(256), 0, stream, U_re, U_im, opdv);
  hipLaunchKernelGGL(k_xdec, dim3(TN * 64), dim3(256), 0, stream, U_re, U_im, Fre, Fim, ntg, ntb,
                     onb16);
  hipLaunchKernelGGL(k_moe2, dim3(TN * 64), dim3(256), 0, stream, onb16, w1tp, w2p32, rwp, rb,
                     b1, b2, Xre_, Xim_, xre, xim, out);
  (void)in_sizes; (void)n_in; (void)out_size; (void)ws_size;
}

// Round 8
// 498.516 us; speedup vs baseline: 19.7335x; 1.2568x over previous
//
#include <hip/hip_runtime.h>

// UniPhyBlock pipeline, round 7: k_state ysc-LDS transpose replaced with
// __shfl register transpose (fixes cross-lane LDS ordering hazard).
// Split-bf16 (hi+lo) precision on XS, E, F, y. B=2 T=16 D=64 H=W=64.

#define DEV static __device__ __forceinline__

typedef __attribute__((ext_vector_type(8))) short bf16x8;
typedef __attribute__((ext_vector_type(4))) float f32x4;
typedef __attribute__((ext_vector_type(16))) float f32x16;
typedef __attribute__((ext_vector_type(4))) unsigned int u32x4;

namespace {
constexpr int TN = 32;          // B*T

DEV float sp_f(float x) { return x > 20.f ? x : log1pf(expf(x)); }
DEV unsigned short f2bf(float f) {
  unsigned int u = __float_as_uint(f);
  unsigned int r = (u + 0x7FFFu + ((u >> 16) & 1u)) >> 16;
  return (unsigned short)r;
}
DEV float bf2f(unsigned short s) { return __uint_as_float(((unsigned int)s) << 16); }
DEV unsigned int cvtpk(float lo, float hi) {
  unsigned int u;
  asm("v_cvt_pk_bf16_f32 %0, %1, %2" : "=v"(u) : "v"(lo), "v"(hi));
  return u;
}
// split pair (a,b) into packed bf16 hi word + packed bf16 lo word
DEV void split2(float a, float b, unsigned int& hi, unsigned int& lo) {
  unsigned short ha = f2bf(a), hb = f2bf(b);
  hi = (unsigned int)ha | ((unsigned int)hb << 16);
  float la = a - bf2f(ha), lb = b - bf2f(hb);
  lo = (unsigned int)f2bf(la) | ((unsigned int)f2bf(lb) << 16);
}
DEV float gelu_f(float x) {
  float x2 = x * x;
  float z2 = 1.5957691216057308f * x * (1.f + 0.044715f * x2);
  float r = __builtin_amdgcn_rcpf(1.f + __expf(-z2));
  return x * r;
}
} // namespace

// K0c: repack conv_w (Co,Ci,3,3) fp32 -> bf16 MFMA B-fragments
__global__ void k_repc(const float* __restrict__ cw, unsigned short* __restrict__ wcv) {
  int i = blockIdx.x * 256 + threadIdx.x;  // 147456
  if (i >= 9 * 4 * 8 * 64 * 8) return;
  int j = i & 7, l = (i >> 3) & 63, ct = (i >> 9) & 7, cb = (i >> 12) & 3, k = i >> 14;
  int co = ct * 16 + (l & 15);
  int ci = cb * 32 + (l >> 4) * 8 + j;
  wcv[i] = f2bf(cw[((size_t)co * 128 + ci) * 9 + k]);
}

// K0b: repack w1 -> 32x32x16 A-frags, w2 -> 32x32x16 B-frags, rw -> 16x16x32 B-frags
__global__ void k_repw(const float* __restrict__ w1, const float* __restrict__ w2,
                       const float* __restrict__ rw,
                       unsigned short* __restrict__ w1tp, unsigned short* __restrict__ w2p32,
                       unsigned short* __restrict__ rwp) {
  int i = blockIdx.x * 256 + threadIdx.x;
  if (i >= 262144 + 2048) return;
  if (i >= 262144) {
    int idx = i - 262144;
    int j = idx & 7, l = (idx >> 3) & 63, kt = idx >> 9;
    int col = l & 15;
    rwp[idx] = col < 4 ? f2bf(rw[(kt * 32 + (l >> 4) * 8 + j) * 4 + col]) : (unsigned short)0;
    return;
  }
  int half = i >> 17;
  int idx = i & 131071;
  int j = idx & 7, l = (idx >> 3) & 63;
  if (half == 0) {
    int kt = (idx >> 9) & 7, mtG = (idx >> 12) & 7, e = idx >> 15;
    int c = kt * 16 + (l >> 5) * 8 + j, m = mtG * 32 + (l & 31);
    w1tp[idx] = f2bf(w1[((size_t)e * 128 + c) * 256 + m]);
  } else {
    int ct = (idx >> 9) & 3, ktG = (idx >> 11) & 15, e = idx >> 15;
    int m = ktG * 16 + (l >> 5) * 8 + j, c = ct * 32 + (l & 31);
    w2p32[idx] = f2bf(w2[((size_t)e * 256 + m) * 128 + c]);
  }
}

// K0e: prepack E^T, F^T -> 16x16x32 A-fragments, hi then lo halves.
__global__ void k_repEF(const float* __restrict__ Ere, const float* __restrict__ Eim,
                        const float* __restrict__ Fre, const float* __restrict__ Fim,
                        unsigned short* __restrict__ efb) {
  int i = blockIdx.x * 256 + threadIdx.x;
  if (i >= 32768) return;
  int sel = i >> 14;         // 0 = hi, 1 = lo
  int f = i & 16383;
  float val;
  if (f < 8192) {
    int j = f & 7, l = (f >> 3) & 63, kt = (f >> 9) & 1, es = (f >> 10) & 1;
    int v = (f >> 11) & 1, eh = f >> 12;
    int d = kt * 32 + (l >> 4) * 8 + j;
    int e = eh * 32 + es * 16 + (l & 15);
    val = (v ? Eim : Ere)[d * 64 + e];
  } else {
    int g = f - 8192;
    int j = g & 7, l = (g >> 3) & 63, ds = (g >> 9) & 3;
    int v = (g >> 11) & 1, eh = g >> 12;
    int e = eh * 32 + (l >> 4) * 8 + j;
    int d = ds * 16 + (l & 15);
    val = (v ? Fim : Fre)[e * 64 + d];
  }
  unsigned short hv = f2bf(val);
  efb[i] = sel ? f2bf(val - bf2f(hv)) : hv;
}

// K1: layernorm -> xn bf16 [n][p][c]; also raw x -> xfb bf16 [n][p][c]
__global__ __launch_bounds__(256) void k_ln_in(
    const float* __restrict__ xre, const float* __restrict__ xim,
    const float* __restrict__ gg, const float* __restrict__ bb,
    unsigned short* __restrict__ xnb, unsigned short* __restrict__ xfb) {
  int n = blockIdx.x >> 6, h = blockIdx.x & 63;
  __shared__ float xl[64][129];
  __shared__ float ps[4][64], ps2[4][64];
  __shared__ float mu[64], rs[64];
  int tid = threadIdx.x;
  int w = tid & 63, q = tid >> 6;
  size_t base = ((size_t)n * 4096 + h) * 64 + w;
  for (int d = q; d < 64; d += 4) {
    size_t o = base + (size_t)d * 4096;
    xl[w][d] = xre[o];
    xl[w][64 + d] = xim[o];
  }
  __syncthreads();
  float s = 0.f, s2 = 0.f;
  for (int c = q * 32; c < q * 32 + 32; ++c) { float v = xl[w][c]; s += v; s2 += v * v; }
  ps[q][w] = s; ps2[q][w] = s2;
  __syncthreads();
  if (tid < 64) {
    float a = 0.f, b2 = 0.f;
#pragma unroll
    for (int i = 0; i < 4; ++i) { a += ps[i][tid]; b2 += ps2[i][tid]; }
    float m = a * (1.f / 128.f);
    mu[tid] = m;
    rs[tid] = rsqrtf(b2 * (1.f / 128.f) - m * m + 1e-5f);
  }
  __syncthreads();
  size_t obase = ((size_t)n * 4096 + (size_t)h * 64) * 128;
  for (int idx = tid; idx < 64 * 64; idx += 256) {
    int q2 = idx >> 6, c2 = (idx & 63) * 2;
    float r0 = xl[q2][c2], r1 = xl[q2][c2 + 1];
    float v0 = (r0 - mu[q2]) * rs[q2] * gg[c2] + bb[c2];
    float v1 = (r1 - mu[q2]) * rs[q2] * gg[c2 + 1] + bb[c2 + 1];
    *(unsigned int*)&xnb[obase + (size_t)q2 * 128 + c2] = cvtpk(v0, v1);
    *(unsigned int*)&xfb[obase + (size_t)q2 * 128 + c2] = cvtpk(r0, r1);
  }
}

// K2: 3x3 conv via MFMA; epilogue adds xf and emits XS hi/lo B-fragment buffers.
__global__ __launch_bounds__(256) void k_conv(
    const unsigned short* __restrict__ xnb, const unsigned short* __restrict__ wcv,
    const float* __restrict__ cbias, const unsigned short* __restrict__ xfb,
    unsigned short* __restrict__ XSf, unsigned short* __restrict__ XSl) {
  int n = blockIdx.x >> 6, h = blockIdx.x & 63;
  __shared__ __align__(16) short in_t[3 * 66 * 128];
  __shared__ float tr[64][66];
  int tid = threadIdx.x;
  int l = tid & 63;
  int w = __builtin_amdgcn_readfirstlane(tid >> 6);

  for (int it = 0; it < 13; ++it) {
    int ch = tid + it * 256;
    if (ch < 3168) {
      int ri = ch >> 4, cb16 = ch & 15;
      int rr = ri >= 132 ? 2 : (ri >= 66 ? 1 : 0);
      int wp = ri - rr * 66 - 1;
      int hh = h + rr - 1;
      uint4 v = make_uint4(0, 0, 0, 0);
      if ((unsigned)hh < 64u && (unsigned)wp < 64u)
        v = *(const uint4*)(xnb + ((size_t)(n * 4096 + hh * 64 + wp) << 7) + cb16 * 8);
      int off = (ri * 256 + cb16 * 16) ^ ((ri & 7) << 4);
      *(uint4*)((char*)in_t + off) = v;
    }
  }
  __syncthreads();

  f32x4 acc[4][2];
#pragma unroll
  for (int pt = 0; pt < 4; ++pt) { acc[pt][0] = {0,0,0,0}; acc[pt][1] = {0,0,0,0}; }

#pragma unroll
  for (int kh = 0; kh < 3; ++kh) {
#pragma unroll
    for (int kw = 0; kw < 3; ++kw) {
      int k = kh * 3 + kw;
#pragma unroll
      for (int cb = 0; cb < 4; ++cb) {
        const unsigned short* wb = wcv + ((((size_t)(k * 4 + cb) * 8) + 2 * w) * 64 + l) * 8;
        bf16x8 b0 = *(const bf16x8*)wb;
        bf16x8 b1 = *(const bf16x8*)(wb + 64 * 8);
#pragma unroll
        for (int pt = 0; pt < 4; ++pt) {
          int ri = kh * 66 + pt * 16 + (l & 15) + kw;
          int off = (ri * 256 + cb * 64 + (l >> 4) * 16) ^ ((ri & 7) << 4);
          bf16x8 a = *(const bf16x8*)((const char*)in_t + off);
          acc[pt][0] = __builtin_amdgcn_mfma_f32_16x16x32_bf16(a, b0, acc[pt][0], 0, 0, 0);
          acc[pt][1] = __builtin_amdgcn_mfma_f32_16x16x32_bf16(a, b1, acc[pt][1], 0, 0, 0);
        }
      }
    }
  }

  for (int pass = 0; pass < 2; ++pass) {
    __syncthreads();
    if ((w >> 1) == pass) {
      int ctl = w & 1;
#pragma unroll
      for (int ct = 0; ct < 2; ++ct) {
        int col = ctl * 32 + ct * 16 + (l & 15);
        float bias = cbias[pass * 64 + col];
#pragma unroll
        for (int pt = 0; pt < 4; ++pt) {
          int pxb = pt * 16 + (l >> 4) * 4;
          size_t xfo = ((size_t)(n * 4096 + h * 64 + pxb)) * 128 + pass * 64 + col;
#pragma unroll
          for (int r = 0; r < 4; ++r)
            tr[col][pxb + r] = acc[pt][ct][r] + bias + bf2f(xfb[xfo + (size_t)r * 128]);
        }
      }
    }
    __syncthreads();
#pragma unroll
    for (int q = 0; q < 2; ++q) {
      int it = tid + q * 256;
      int ptl = it >> 7, kt = (it >> 6) & 1, lf = it & 63;
      int dbase = kt * 32 + (lf >> 4) * 8;
      int px = ptl * 16 + (lf & 15);
      unsigned int hw[4], lw[4];
#pragma unroll
      for (int u = 0; u < 4; ++u)
        split2(tr[dbase + 2 * u][px], tr[dbase + 2 * u + 1][px], hw[u], lw[u]);
      size_t base = ((((size_t)n * 256 + h * 4 + ptl) * 2 + pass) * 2 + kt) * 512 + lf * 8;
      *(uint4*)(XSf + base) = make_uint4(hw[0], hw[1], hw[2], hw[3]);
      *(uint4*)(XSl + base) = make_uint4(lw[0], lw[1], lw[2], lw[3]);
    }
    __syncthreads();
  }
}

// K3: Xm[n][d] = mean_p XS (hi+lo)
__global__ __launch_bounds__(256) void k_xmean(const unsigned short* __restrict__ XSf,
                                               const unsigned short* __restrict__ XSl,
                                               float2* __restrict__ Xm) {
  int nd = blockIdx.x;
  int n = nd >> 6, d = nd & 63;
  int kt = d >> 5, hs = (d >> 3) & 3, j = d & 7;
  int tid = threadIdx.x;
  float sr = 0.f, si = 0.f;
  for (int p = tid; p < 4096; p += 256) {
    int ptg = p >> 4, c = p & 15;
    size_t b0 = ((((size_t)n * 256 + ptg) * 2 + 0) * 2 + kt) * 512 + (hs * 16 + c) * 8 + j;
    size_t b1 = ((((size_t)n * 256 + ptg) * 2 + 1) * 2 + kt) * 512 + (hs * 16 + c) * 8 + j;
    sr += bf2f(XSf[b0]) + bf2f(XSl[b0]);
    si += bf2f(XSf[b1]) + bf2f(XSl[b1]);
  }
  __shared__ float r1[256], r2[256];
  r1[tid] = sr; r2[tid] = si;
  __syncthreads();
  for (int s = 128; s > 0; s >>= 1) {
    if (tid < s) { r1[tid] += r1[tid + s]; r2[tid] += r2[tid + s]; }
    __syncthreads();
  }
  if (tid == 0) Xm[nd] = make_float2(r1[0] * (1.f / 4096.f), r2[0] * (1.f / 4096.f));
}

// K4: per (b,t): xmean = Xm @ Ec; fcat = [re,im] @ mix_w + mix_b
__global__ void k_chainA(const float2* __restrict__ Xm, const float* __restrict__ Ere,
                         const float* __restrict__ Eim, const float* __restrict__ mixw,
                         const float* __restrict__ mixb, float2* __restrict__ xmix) {
  int n = blockIdx.x;
  int tid = threadIdx.x;  // 128
  __shared__ float2 xm[64];
  __shared__ float cat[128];
  __shared__ float fc[128];
  if (tid < 64) xm[tid] = Xm[n * 64 + tid];
  __syncthreads();
  if (tid < 64) {
    float ar = 0.f, ai = 0.f;
    for (int d = 0; d < 64; ++d) {
      float2 x = xm[d];
      float er = Ere[d * 64 + tid], ei = Eim[d * 64 + tid];
      ar += x.x * er - x.y * ei;
      ai += x.x * ei + x.y * er;
    }
    cat[tid] = ar; cat[64 + tid] = ai;
  }
  __syncthreads();
  {
    float f = mixb[tid];
    for (int i = 0; i < 128; ++i) f += cat[i] * mixw[i * 128 + tid];
    fc[tid] = f;
  }
  __syncthreads();
  if (tid < 64) xmix[n * 64 + tid] = make_float2(fc[tid], fc[64 + tid]);
}

// K5: flux scan over t
__global__ void k_chainB(const float2* __restrict__ xmix, const float* __restrict__ nu,
                         const float* __restrict__ th, const float* __restrict__ fre,
                         const float* __restrict__ fim, float2* __restrict__ fs) {
  int tid = threadIdx.x;  // 128
  int b = tid >> 6, d = tid & 63;
  float r = expf(-sp_f(nu[d]));
  float dr = r * cosf(th[d]), di = r * sinf(th[d]);
  float yr = 0.f, yi = 0.f, cr = 1.f, ci = 0.f;
  float fr = fre[b * 64 + d], fi = fim[b * 64 + d];
  for (int t = 0; t < 16; ++t) {
    int n = b * 16 + t;
    float ncr = cr * dr - ci * di, nci = cr * di + ci * dr;
    cr = ncr; ci = nci;
    float2 xm = xmix[n * 64 + d];
    float nyr = dr * yr - di * yi + xm.x;
    float nyi = dr * yi + di * yr + xm.y;
    yr = nyr; yi = nyi;
    fs[n * 64 + d] = make_float2(yr + fr * cr - fi * ci, yi + fr * ci + fi * cr);
  }
}

// K6: per (b,t): abo[n][e][8] = {a_r, a_i, bb_r, bb_i, od_r, od_i, 0, 0}
__global__ void k_chainC(const float2* __restrict__ fs, const float* __restrict__ srcw,
                         const float* __restrict__ srcb, const float* __restrict__ gw,
                         const float* __restrict__ gbv, const float* __restrict__ la,
                         const float* __restrict__ lbv, const float* __restrict__ dt,
                         float* __restrict__ abo) {
  int n = blockIdx.x;
  int t = n & 15;
  int tid = threadIdx.x;  // 128
  __shared__ float oc[128];
  __shared__ float sl[128];
  if (tid < 64) { float2 v = fs[n * 64 + tid]; oc[tid] = v.x; oc[64 + tid] = v.y; }
  __syncthreads();
  {
    float s = srcb[tid];
    for (int i = 0; i < 128; ++i) s += oc[i] * srcw[i * 128 + tid];
    sl[tid] = s;
  }
  __syncthreads();
  if (tid < 64) {
    float gv = gbv[tid];
    for (int i = 0; i < 128; ++i) gv += oc[i] * gw[i * 64 + tid];
    float g = 1.f / (1.f + expf(-gv));
    float lr = -sp_f(la[tid]), li = lbv[tid];
    float dtv = dt[t];
    float er = expf(lr * dtv);
    float odr = er * cosf(li * dtv), odi = er * sinf(li * dtv);
    float inv = 1.f / (lr * lr + li * li);
    float nx = odr - 1.f, ny = odi;
    float ofr = (nx * lr + ny * li) * inv, ofi = (ny * lr - nx * li) * inv;
    float s1r = sl[tid] * (1.f - g), s1i = sl[64 + tid] * (1.f - g);
    float* ap = abo + ((size_t)n * 64 + tid) * 8;
    ap[0] = g * ofr;
    ap[1] = g * ofi;
    ap[2] = s1r * ofr - s1i * ofi;
    ap[3] = s1r * ofi + s1i * ofr;
    ap[4] = odr;
    ap[5] = odi;
    ap[6] = 0.f; ap[7] = 0.f;
  }
}

// K7 (fused): encode -> forcing -> scan -> decode -> LN -> on. Split-bf16 precision.
// y C-layout -> B-fragment transpose done fully in registers via __shfl.
__global__ __launch_bounds__(128) void k_state(
    const unsigned short* __restrict__ XSf, const unsigned short* __restrict__ XSl,
    const unsigned short* __restrict__ efb,
    const float* __restrict__ abo, const float* __restrict__ hre,
    const float* __restrict__ him, const float* __restrict__ ntg,
    const float* __restrict__ ntb, unsigned short* __restrict__ onb) {
  int bq = blockIdx.x;
  int b = bq >> 8, pt = bq & 255;
  int p0 = pt * 16;
  int tid = threadIdx.x;
  int l = tid & 63;
  int eh = __builtin_amdgcn_readfirstlane(tid >> 6);
  int c = l & 15, h4 = l >> 4;

  __shared__ float xpart[2 * 64 * 17];
  __shared__ float ntgl[128], ntbl[128];
  ntgl[tid] = ntg[tid]; ntbl[tid] = ntb[tid];

  const unsigned short* Ehi = efb;
  const unsigned short* Fhi = efb + 8192;
  const unsigned short* Elo = efb + 16384;
  const unsigned short* Flo = efb + 24576;

  bf16x8 erh[2][2], eihh[2][2], erl[2][2], eil[2][2];
#pragma unroll
  for (int es = 0; es < 2; ++es)
#pragma unroll
    for (int kt = 0; kt < 2; ++kt) {
      size_t o = (size_t)(eh * 4096 + es * 1024 + kt * 512 + l * 8);
      erh[es][kt] = *(const bf16x8*)(Ehi + o);
      eihh[es][kt] = *(const bf16x8*)(Ehi + o + 2048);
      erl[es][kt] = *(const bf16x8*)(Elo + o);
      eil[es][kt] = *(const bf16x8*)(Elo + o + 2048);
    }
  bf16x8 frh[4], fih[4], frl[4], fil[4];
#pragma unroll
  for (int ds = 0; ds < 4; ++ds) {
    size_t o = (size_t)(eh * 4096 + ds * 512 + l * 8);
    frh[ds] = *(const bf16x8*)(Fhi + o);
    fih[ds] = *(const bf16x8*)(Fhi + o + 2048);
    frl[ds] = *(const bf16x8*)(Flo + o);
    fil[ds] = *(const bf16x8*)(Flo + o + 2048);
  }

  float yre[2][4], yim[2][4];
#pragma unroll
  for (int es = 0; es < 2; ++es)
#pragma unroll
    for (int r = 0; r < 4; ++r) { yre[es][r] = 0.f; yim[es][r] = 0.f; }

  __syncthreads();

  const f32x4 Z = {0.f, 0.f, 0.f, 0.f};
  for (int t = 0; t < 16; ++t) {
    int n = b * 16 + t;
    bf16x8 xh0[2], xh1[2], xq0[2], xq1[2];
#pragma unroll
    for (int kt = 0; kt < 2; ++kt) {
      size_t b0 = ((((size_t)n * 256 + pt) * 2 + 0) * 2 + kt) * 512 + l * 8;
      size_t b1 = ((((size_t)n * 256 + pt) * 2 + 1) * 2 + kt) * 512 + l * 8;
      xh0[kt] = *(const bf16x8*)(XSf + b0);
      xh1[kt] = *(const bf16x8*)(XSf + b1);
      xq0[kt] = *(const bf16x8*)(XSl + b0);
      xq1[kt] = *(const bf16x8*)(XSl + b1);
    }
    // ---- encode (triple product) + forcing + scan
#pragma unroll
    for (int es = 0; es < 2; ++es) {
      f32x4 a1 = Z, a2 = Z, a3 = Z, a4 = Z;
#pragma unroll
      for (int kt = 0; kt < 2; ++kt) {
        a1 = __builtin_amdgcn_mfma_f32_16x16x32_bf16(erh[es][kt], xh0[kt], a1, 0, 0, 0);
        a1 = __builtin_amdgcn_mfma_f32_16x16x32_bf16(erh[es][kt], xq0[kt], a1, 0, 0, 0);
        a1 = __builtin_amdgcn_mfma_f32_16x16x32_bf16(erl[es][kt], xh0[kt], a1, 0, 0, 0);
        a2 = __builtin_amdgcn_mfma_f32_16x16x32_bf16(eihh[es][kt], xh1[kt], a2, 0, 0, 0);
        a2 = __builtin_amdgcn_mfma_f32_16x16x32_bf16(eihh[es][kt], xq1[kt], a2, 0, 0, 0);
        a2 = __builtin_amdgcn_mfma_f32_16x16x32_bf16(eil[es][kt], xh1[kt], a2, 0, 0, 0);
        a3 = __builtin_amdgcn_mfma_f32_16x16x32_bf16(eihh[es][kt], xh0[kt], a3, 0, 0, 0);
        a3 = __builtin_amdgcn_mfma_f32_16x16x32_bf16(eihh[es][kt], xq0[kt], a3, 0, 0, 0);
        a3 = __builtin_amdgcn_mfma_f32_16x16x32_bf16(eil[es][kt], xh0[kt], a3, 0, 0, 0);
        a4 = __builtin_amdgcn_mfma_f32_16x16x32_bf16(erh[es][kt], xh1[kt], a4, 0, 0, 0);
        a4 = __builtin_amdgcn_mfma_f32_16x16x32_bf16(erh[es][kt], xq1[kt], a4, 0, 0, 0);
        a4 = __builtin_amdgcn_mfma_f32_16x16x32_bf16(erl[es][kt], xh1[kt], a4, 0, 0, 0);
      }
#pragma unroll
      for (int r = 0; r < 4; ++r) {
        int e = eh * 32 + es * 16 + 4 * h4 + r;
        const float* ap = abo + ((size_t)n * 64 + e) * 8;
        float4 cv = *(const float4*)ap;
        float2 ov = *(const float2*)(ap + 4);
        float xr_ = a1[r] - a2[r], xi_ = a3[r] + a4[r];
        float ur = xr_ * cv.x - xi_ * cv.y + cv.z;
        float ui = xr_ * cv.y + xi_ * cv.x + cv.w;
        if (t == 0) {
          size_t ho = ((size_t)(b * 4096 + p0 + c)) * 64 + e;
          float hr = hre[ho], hi = him[ho];
          ur += hr * ov.x - hi * ov.y;
          ui += hr * ov.y + hi * ov.x;
        }
        float nyr = ov.x * yre[es][r] - ov.y * yim[es][r] + ur;
        float nyi = ov.x * yim[es][r] + ov.y * yre[es][r] + ui;
        yre[es][r] = nyr; yim[es][r] = nyi;
      }
    }
    // ---- y -> split bf16 hi/lo B-fragments, in-register shfl transpose.
    // Source lane (h4s,c) reg [es][b] = pair at e_local = es*16 + 4*h4s + 2*b.
    // Target lane (h4,c) word jj = pair at e_local = 8*h4 + 2*jj
    //   => es = h4>>1, h4s = 2*(h4&1) + (jj>>1), b = jj&1.
    unsigned int hr_[2][2], lr_[2][2], hi_[2][2], li_[2][2];
#pragma unroll
    for (int es = 0; es < 2; ++es) {
      split2(yre[es][0], yre[es][1], hr_[es][0], lr_[es][0]);
      split2(yre[es][2], yre[es][3], hr_[es][1], lr_[es][1]);
      split2(yim[es][0], yim[es][1], hi_[es][0], li_[es][0]);
      split2(yim[es][2], yim[es][3], hi_[es][1], li_[es][1]);
    }
    int base_src = c + 16 * (2 * (h4 & 1));
    int hsel = h4 >> 1;
    u32x4 urh, uih, url, uil;
#pragma unroll
    for (int jj = 0; jj < 4; ++jj) {
      int src = base_src + 16 * (jj >> 1);
      unsigned int t0, t1;
      t0 = (unsigned int)__shfl((int)hr_[0][jj & 1], src);
      t1 = (unsigned int)__shfl((int)hr_[1][jj & 1], src);
      urh[jj] = hsel ? t1 : t0;
      t0 = (unsigned int)__shfl((int)hi_[0][jj & 1], src);
      t1 = (unsigned int)__shfl((int)hi_[1][jj & 1], src);
      uih[jj] = hsel ? t1 : t0;
      t0 = (unsigned int)__shfl((int)lr_[0][jj & 1], src);
      t1 = (unsigned int)__shfl((int)lr_[1][jj & 1], src);
      url[jj] = hsel ? t1 : t0;
      t0 = (unsigned int)__shfl((int)li_[0][jj & 1], src);
      t1 = (unsigned int)__shfl((int)li_[1][jj & 1], src);
      uil[jj] = hsel ? t1 : t0;
    }
    bf16x8 ybrh = __builtin_bit_cast(bf16x8, urh);
    bf16x8 ybih = __builtin_bit_cast(bf16x8, uih);
    bf16x8 ybrl = __builtin_bit_cast(bf16x8, url);
    bf16x8 ybil = __builtin_bit_cast(bf16x8, uil);
    // ---- decode (triple product, partial over this wave's e-half)
    float v[2][4][4];
#pragma unroll
    for (int ds = 0; ds < 4; ++ds) {
      f32x4 d1 = Z, d2 = Z, d3 = Z, d4 = Z;
      d1 = __builtin_amdgcn_mfma_f32_16x16x32_bf16(frh[ds], ybrh, d1, 0, 0, 0);
      d1 = __builtin_amdgcn_mfma_f32_16x16x32_bf16(frh[ds], ybrl, d1, 0, 0, 0);
      d1 = __builtin_amdgcn_mfma_f32_16x16x32_bf16(frl[ds], ybrh, d1, 0, 0, 0);
      d2 = __builtin_amdgcn_mfma_f32_16x16x32_bf16(fih[ds], ybih, d2, 0, 0, 0);
      d2 = __builtin_amdgcn_mfma_f32_16x16x32_bf16(fih[ds], ybil, d2, 0, 0, 0);
      d2 = __builtin_amdgcn_mfma_f32_16x16x32_bf16(fil[ds], ybih, d2, 0, 0, 0);
      d3 = __builtin_amdgcn_mfma_f32_16x16x32_bf16(fih[ds], ybrh, d3, 0, 0, 0);
      d3 = __builtin_amdgcn_mfma_f32_16x16x32_bf16(fih[ds], ybrl, d3, 0, 0, 0);
      d3 = __builtin_amdgcn_mfma_f32_16x16x32_bf16(fil[ds], ybrh, d3, 0, 0, 0);
      d4 = __builtin_amdgcn_mfma_f32_16x16x32_bf16(frh[ds], ybih, d4, 0, 0, 0);
      d4 = __builtin_amdgcn_mfma_f32_16x16x32_bf16(frh[ds], ybil, d4, 0, 0, 0);
      d4 = __builtin_amdgcn_mfma_f32_16x16x32_bf16(frl[ds], ybih, d4, 0, 0, 0);
#pragma unroll
      for (int r = 0; r < 4; ++r) {
        v[0][ds][r] = d1[r] - d2[r];
        v[1][ds][r] = d3[r] + d4[r];
      }
    }
    bool own = (eh == (t & 1));
    if (!own) {
#pragma unroll
      for (int p = 0; p < 2; ++p)
#pragma unroll
        for (int ds = 0; ds < 4; ++ds)
#pragma unroll
          for (int r = 0; r < 4; ++r)
            xpart[(p * 64 + ds * 16 + 4 * h4 + r) * 17 + c] = v[p][ds][r];
    }
    __syncthreads();
    if (own) {
      float s = 0.f, s2 = 0.f;
#pragma unroll
      for (int p = 0; p < 2; ++p)
#pragma unroll
        for (int ds = 0; ds < 4; ++ds)
#pragma unroll
          for (int r = 0; r < 4; ++r) {
            float q2 = v[p][ds][r] + xpart[(p * 64 + ds * 16 + 4 * h4 + r) * 17 + c];
            v[p][ds][r] = q2;
            s += q2; s2 += q2 * q2;
          }
      s += __shfl_xor(s, 16); s += __shfl_xor(s, 32);
      s2 += __shfl_xor(s2, 16); s2 += __shfl_xor(s2, 32);
      float mu = s * (1.f / 128.f);
      float rsv = rsqrtf(s2 * (1.f / 128.f) - mu * mu + 1e-5f);
      size_t ob = ((size_t)(n * 4096 + p0 + c)) * 128;
#pragma unroll
      for (int p = 0; p < 2; ++p)
#pragma unroll
        for (int ds = 0; ds < 4; ++ds) {
          int ch = p * 64 + ds * 16 + 4 * h4;
          float l0 = (v[p][ds][0] - mu) * rsv * ntgl[ch + 0] + ntbl[ch + 0];
          float l1 = (v[p][ds][1] - mu) * rsv * ntgl[ch + 1] + ntbl[ch + 1];
          float l2 = (v[p][ds][2] - mu) * rsv * ntgl[ch + 2] + ntbl[ch + 2];
          float l3 = (v[p][ds][3] - mu) * rsv * ntgl[ch + 3] + ntbl[ch + 3];
          *(unsigned int*)&onb[ob + ch] = cvtpk(l0, l1);
          *(unsigned int*)&onb[ob + ch + 2] = cvtpk(l2, l3);
        }
    }
    __syncthreads();
  }
}

// K10: MoE via swapped-operand 32x32 MFMA; residual from XS hi+lo.
__global__ __launch_bounds__(256) void k_moe2(
    const unsigned short* __restrict__ onb, const unsigned short* __restrict__ w1tp,
    const unsigned short* __restrict__ w2p32, const unsigned short* __restrict__ rwp,
    const float* __restrict__ rb, const float* __restrict__ b1, const float* __restrict__ b2,
    const unsigned short* __restrict__ XSf, const unsigned short* __restrict__ XSl,
    float* __restrict__ out) {
  int n = blockIdx.x >> 6, ptile = blockIdx.x & 63;
  int p0 = ptile * 64;
  __shared__ __align__(16) short At[64 * 128];
  __shared__ __align__(16) float buf[8320];
  __shared__ float pr[64][4];
  int tid = threadIdx.x;
  int l = tid & 63;
  int w = __builtin_amdgcn_readfirstlane(tid >> 6);
  int h = l >> 5, s = l & 31;
  float* b1l = buf;
  float* b2l = buf + 1024;

  for (int i = tid; i < 1024; i += 256) b1l[i] = b1[i];
  for (int i = tid; i < 512; i += 256) b2l[i] = b2[i];

  {
    const char* gsrc = (const char*)onb + ((size_t)n * 4096 + p0) * 256;
#pragma unroll
    for (int it = 0; it < 4; ++it) {
      int ch = tid + it * 256;
      int row = ch >> 4, cb = (ch & 15) * 16;
      float4 v = *(const float4*)(gsrc + (size_t)row * 256 + cb);
      int off = (row * 256 + cb) ^ ((row & 7) << 4);
      *(float4*)((char*)At + off) = v;
    }
  }
  __syncthreads();

  {
    f32x4 acc = {0.f, 0.f, 0.f, 0.f};
#pragma unroll
    for (int kt = 0; kt < 4; ++kt) {
      int row = w * 16 + (l & 15);
      int off = (row * 256 + kt * 64 + (l >> 4) * 16) ^ ((row & 7) << 4);
      bf16x8 aa = *(const bf16x8*)((const char*)At + off);
      bf16x8 bb = *(const bf16x8*)(rwp + ((size_t)kt * 64 + l) * 8);
      acc = __builtin_amdgcn_mfma_f32_16x16x32_bf16(aa, bb, acc, 0, 0, 0);
    }
    int e = l & 15;
    float rbv = e < 4 ? rb[e] : 0.f;
#pragma unroll
    for (int r = 0; r < 4; ++r) {
      float lg = acc[r] + rbv;
      float m = fmaxf(lg, __shfl_xor(lg, 1));
      m = fmaxf(m, __shfl_xor(m, 2));
      float ex = __expf(lg - m);
      float sm = ex + __shfl_xor(ex, 1);
      sm += __shfl_xor(sm, 2);
      float p = ex * __builtin_amdgcn_rcpf(sm);
      if (e < 4) pr[w * 16 + (l >> 4) * 4 + r][e] = p;
    }
  }
  __syncthreads();

  int pw = w & 1, mh = w >> 1;
  int rowb = pw * 32 + s;
  int swz = (rowb & 7) << 4;

  float macc[4][16];
#pragma unroll
  for (int ct = 0; ct < 4; ++ct)
#pragma unroll
    for (int r = 0; r < 16; ++r) macc[ct][r] = 0.f;

  const f32x16 Z16 = {0.f, 0.f, 0.f, 0.f, 0.f, 0.f, 0.f, 0.f,
                      0.f, 0.f, 0.f, 0.f, 0.f, 0.f, 0.f, 0.f};

  for (int e = 0; e < 4; ++e) {
    u32x4 af[8];
#pragma unroll
    for (int mt = 0; mt < 4; ++mt) {
      f32x16 acc = Z16;
#pragma unroll
      for (int kt = 0; kt < 8; ++kt) {
        bf16x8 a = *(const bf16x8*)(
            w1tp + ((((size_t)e * 8 + (mh * 4 + mt)) * 8 + kt) * 64 + l) * 8);
        int off = (rowb * 256 + kt * 32 + h * 16) ^ swz;
        bf16x8 b = *(const bf16x8*)((const char*)At + off);
        acc = __builtin_amdgcn_mfma_f32_32x32x16_bf16(a, b, acc, 0, 0, 0);
      }
      unsigned int hpk[8];
#pragma unroll
      for (int i2 = 0; i2 < 8; ++i2) {
        int r0 = 2 * i2;
        int m0 = mh * 128 + mt * 32 + (r0 & 3) + 8 * (r0 >> 2) + 4 * h;
        float2 bv = *(const float2*)&b1l[e * 256 + m0];
        hpk[i2] = cvtpk(gelu_f(acc[r0] + bv.x), gelu_f(acc[r0 + 1] + bv.y));
      }
#pragma unroll
      for (int hf = 0; hf < 2; ++hf) {
        unsigned int pA = hpk[4 * hf + 0], pB = hpk[4 * hf + 1];
        unsigned int pC = hpk[4 * hf + 2], pD = hpk[4 * hf + 3];
        unsigned int Z0 = h ? pC : pA, Z1 = h ? pD : pB;
        unsigned int S0 = h ? pA : pC, S1 = h ? pB : pD;
        unsigned int Ss0 = (unsigned int)__shfl_xor((int)S0, 32);
        unsigned int Ss1 = (unsigned int)__shfl_xor((int)S1, 32);
        u32x4 fr2;
        fr2.x = h ? Ss0 : Z0;
        fr2.y = h ? Ss1 : Z1;
        fr2.z = h ? Z0 : Ss0;
        fr2.w = h ? Z1 : Ss1;
        af[mt * 2 + hf] = fr2;
      }
    }
    float prv[16];
#pragma unroll
    for (int r = 0; r < 16; ++r) {
      int px = pw * 32 + (r & 3) + 8 * (r >> 2) + 4 * h;
      prv[r] = pr[px][e];
    }
#pragma unroll
    for (int ct = 0; ct < 4; ++ct) {
      f32x16 acc = Z16;
#pragma unroll
      for (int kt = 0; kt < 8; ++kt) {
        bf16x8 bf = *(const bf16x8*)(
            w2p32 + ((((size_t)e * 16 + (mh * 8 + kt)) * 4 + ct) * 64 + l) * 8);
        bf16x8 a = __builtin_bit_cast(bf16x8, af[kt]);
        acc = __builtin_amdgcn_mfma_f32_32x32x16_bf16(a, bf, acc, 0, 0, 0);
      }
      float b2v = mh ? 0.f : b2l[e * 128 + ct * 32 + s];
#pragma unroll
      for (int r = 0; r < 16; ++r) macc[ct][r] += (acc[r] + b2v) * prv[r];
    }
  }

  __syncthreads();
  if (mh == 1) {
#pragma unroll
    for (int g = 0; g < 16; ++g) {
      int ct = g >> 2, q = (g & 3) * 4;
      float4 v = make_float4(macc[ct][q], macc[ct][q + 1], macc[ct][q + 2], macc[ct][q + 3]);
      *(float4*)&buf[((g * 2 + pw) * 64 + l) * 4] = v;
    }
  }
  __syncthreads();
  if (mh == 0) {
#pragma unroll
    for (int g = 0; g < 16; ++g) {
      float4 v = *(const float4*)&buf[((g * 2 + pw) * 64 + l) * 4];
      int ct = g >> 2, q = (g & 3) * 4;
      macc[ct][q] += v.x; macc[ct][q + 1] += v.y;
      macc[ct][q + 2] += v.z; macc[ct][q + 3] += v.w;
    }
  }
  __syncthreads();
  if (mh == 0) {
#pragma unroll
    for (int ct = 0; ct < 4; ++ct) {
      int cc = ct * 32 + s;
#pragma unroll
      for (int r = 0; r < 16; ++r) {
        int px = pw * 32 + (r & 3) + 8 * (r >> 2) + 4 * h;
        int aoff = (px * 256 + cc * 2) ^ ((px & 7) << 4);
        float onv = bf2f(((unsigned short*)At)[aoff >> 1]);
        buf[px * 130 + cc] = macc[ct][r] + onv;
      }
    }
  }
  __syncthreads();
  for (int idx = tid; idx < 64 * 128; idx += 256) {
    int px = idx & 63, ch = idx >> 6;
    int p = p0 + px;
    int part = ch >> 6, d = ch & 63;
    size_t el = ((((size_t)n * 256 + (p >> 4)) * 2 + part) * 2 + (d >> 5)) * 512
              + (((d >> 3) & 3) * 16 + (p & 15)) * 8 + (d & 7);
    float resid = bf2f(XSf[el]) + bf2f(XSl[el]);
    out[((size_t)n * 128 + ch) * 4096 + p0 + px] = resid + buf[px * 130 + ch];
  }
}

extern "C" void kernel_launch(void* const* d_in, const int* in_sizes, int n_in,
                              void* d_out, int out_size, void* d_ws, size_t ws_size,
                              hipStream_t stream) {
  const float* xre = (const float*)d_in[0];
  const float* xim = (const float*)d_in[1];
  const float* hre = (const float*)d_in[2];
  const float* him = (const float*)d_in[3];
  const float* dt = (const float*)d_in[4];
  const float* fre = (const float*)d_in[5];
  const float* fim = (const float*)d_in[6];
  const float* nsg = (const float*)d_in[7];
  const float* nsb = (const float*)d_in[8];
  const float* cw = (const float*)d_in[9];
  const float* cb = (const float*)d_in[10];
  const float* Ere = (const float*)d_in[11];
  const float* Eim = (const float*)d_in[12];
  const float* Fre = (const float*)d_in[13];
  const float* Fim = (const float*)d_in[14];
  const float* mixw = (const float*)d_in[15];
  const float* mixb = (const float*)d_in[16];
  const float* nu = (const float*)d_in[17];
  const float* th = (const float*)d_in[18];
  const float* srcw = (const float*)d_in[19];
  const float* srcb = (const float*)d_in[20];
  const float* gw = (const float*)d_in[21];
  const float* gbv = (const float*)d_in[22];
  const float* la = (const float*)d_in[23];
  const float* lb = (const float*)d_in[24];
  const float* ntg = (const float*)d_in[25];
  const float* ntb = (const float*)d_in[26];
  const float* rw = (const float*)d_in[27];
  const float* rb = (const float*)d_in[28];
  const float* w1 = (const float*)d_in[29];
  const float* b1 = (const float*)d_in[30];
  const float* w2 = (const float*)d_in[31];
  const float* b2 = (const float*)d_in[32];

  unsigned short* XSf = (unsigned short*)d_ws;
  unsigned short* XSl = XSf + 16777216;
  unsigned short* onb16 = XSl + 16777216;
  unsigned short* wcv = onb16 + 16777216;        // 147456
  unsigned short* w1tp = wcv + 147456;           // 131072
  unsigned short* w2p32 = w1tp + 131072;         // 131072
  unsigned short* rwp = w2p32 + 131072;          // 2048
  unsigned short* efb = rwp + 2048;              // 32768 (hi 16384 + lo 16384)
  float* smf = (float*)(efb + 32768);
  float* abo = smf;                              // 32*64*8 = 16384 f32
  float2* Xm = (float2*)(abo + 16384);           // 2048 float2
  float2* xmix = Xm + TN * 64;
  float2* fsb = xmix + TN * 64;

  float* out = (float*)d_out;
  unsigned short* xnb = (unsigned short*)d_out;        // bf16, dead after k_conv
  unsigned short* xfb = xnb + 16777216;                // bf16 raw x, dead after k_conv

  hipLaunchKernelGGL(k_repc, dim3(576), dim3(256), 0, stream, cw, wcv);
  hipLaunchKernelGGL(k_repw, dim3(1033), dim3(256), 0, stream, w1, w2, rw, w1tp, w2p32, rwp);
  hipLaunchKernelGGL(k_repEF, dim3(128), dim3(256), 0, stream, Ere, Eim, Fre, Fim, efb);
  hipLaunchKernelGGL(k_ln_in, dim3(TN * 64), dim3(256), 0, stream, xre, xim, nsg, nsb, xnb, xfb);
  hipLaunchKernelGGL(k_conv, dim3(TN * 64), dim3(256), 0, stream, xnb, wcv, cb, xfb, XSf, XSl);
  hipLaunchKernelGGL(k_xmean, dim3(TN * 64), dim3(256), 0, stream, XSf, XSl, Xm);
  hipLaunchKernelGGL(k_chainA, dim3(TN), dim3(128), 0, stream, Xm, Ere, Eim, mixw, mixb, xmix);
  hipLaunchKernelGGL(k_chainB, dim3(1), dim3(128), 0, stream, xmix, nu, th, fre, fim, fsb);
  hipLaunchKernelGGL(k_chainC, dim3(TN), dim3(128), 0, stream, fsb, srcw, srcb, gw, gbv, la, lb,
                     dt, abo);
  hipLaunchKernelGGL(k_state, dim3(512), dim3(128), 0, stream, XSf, XSl, efb, abo, hre, him,
                     ntg, ntb, onb16);
  hipLaunchKernelGGL(k_moe2, dim3(TN * 64), dim3(256), 0, stream, onb16, w1tp, w2p32, rwp, rb,
                     b1, b2, XSf, XSl, out);
  (void)in_sizes; (void)n_in; (void)out_size; (void)ws_size;
}